// Round 1
// baseline (2564.811 us; speedup 1.0000x reference)
//
#include <hip/hip_runtime.h>
#include <math.h>

#define B_ 8192
#define K_ 32
#define D_ 768
#define H_ 256
#define T_ 16
#define S_ 2

// ---------- wave (64-lane) reductions ----------
__device__ __forceinline__ float wsum(float v) {
  v += __shfl_xor(v, 32); v += __shfl_xor(v, 16); v += __shfl_xor(v, 8);
  v += __shfl_xor(v, 4);  v += __shfl_xor(v, 2);  v += __shfl_xor(v, 1);
  return v;
}
__device__ __forceinline__ float wmaxr(float v) {
  v = fmaxf(v, __shfl_xor(v, 32)); v = fmaxf(v, __shfl_xor(v, 16));
  v = fmaxf(v, __shfl_xor(v, 8));  v = fmaxf(v, __shfl_xor(v, 4));
  v = fmaxf(v, __shfl_xor(v, 2));  v = fmaxf(v, __shfl_xor(v, 1));
  return v;
}

// ---------- weight folding: Wk_in^T = (Wk_a@W_in)^T, Wv_in = Wv_a@W_in, Wc_in = Wc@W_in ----------
__global__ __launch_bounds__(256)
void fold_kernel(const float* __restrict__ Wk_a, const float* __restrict__ Wv_a,
                 const float* __restrict__ Wc,  const float* __restrict__ W_in,
                 float* __restrict__ WkinT, float* __restrict__ Wv_in, float* __restrict__ Wc_in)
{
  const int i = blockIdx.x;   // output row 0..255
  const int m = blockIdx.y;   // which matrix
  const float* Wx = (m == 0) ? Wk_a : ((m == 1) ? Wv_a : Wc);
  const int t = threadIdx.x;
  float a0 = 0.f, a1 = 0.f, a2 = 0.f;
  for (int k = 0; k < H_; k++) {
    const float wv = Wx[i * H_ + k];
    const float* row = W_in + (size_t)k * D_;
    a0 = fmaf(wv, row[t], a0);
    a1 = fmaf(wv, row[t + 256], a1);
    a2 = fmaf(wv, row[t + 512], a2);
  }
  if (m == 0) {  // store transposed [D,H] so qk_vec GEMM is NT
    WkinT[(size_t)t * H_ + i] = a0;
    WkinT[(size_t)(t + 256) * H_ + i] = a1;
    WkinT[(size_t)(t + 512) * H_ + i] = a2;
  } else {
    float* o = ((m == 1) ? Wv_in : Wc_in) + (size_t)i * D_;
    o[t] = a0; o[t + 256] = a1; o[t + 512] = a2;
  }
}

// ---------- l2-normalize topic prototypes ----------
__global__ __launch_bounds__(256)
void proto_kernel(const float* __restrict__ tpro, float* __restrict__ pro)
{
  const int w = threadIdx.x >> 6, l = threadIdx.x & 63;
  for (int r = w; r < T_; r += 4) {
    const float4 v = *(const float4*)(tpro + (size_t)r * H_ + l * 4);
    const float n = fmaxf(sqrtf(wsum(v.x * v.x + v.y * v.y + v.z * v.z + v.w * v.w)), 1e-12f);
    float4 o; o.x = v.x / n; o.y = v.y / n; o.z = v.z / n; o.w = v.w / n;
    *(float4*)(pro + (size_t)r * H_ + l * 4) = o;
  }
}

// ---------- fp32 NT GEMM: C[M,N] = A[M,K]*B[N,K]^T (+bias). 128x128x8, 256 thr, 8x8/thr ----------
template<bool BIAS>
__global__ __launch_bounds__(256)
void gemm_nt(const float* __restrict__ A, const float* __restrict__ Bm,
             const float* __restrict__ bias, float* __restrict__ C,
             int M, int N, int Kd)
{
  __shared__ float As[8][132];
  __shared__ float Bs[8][132];
  const int t = threadIdx.x;
  const int tx = t & 15, ty = t >> 4;
  const int lr = t >> 1, lc = (t & 1) * 4;
  const float* Ab = A + ((size_t)blockIdx.y * 128 + lr) * Kd + lc;
  const float* Bb = Bm + ((size_t)blockIdx.x * 128 + lr) * Kd + lc;
  float acc[8][8];
#pragma unroll
  for (int i = 0; i < 8; i++)
#pragma unroll
    for (int j = 0; j < 8; j++) acc[i][j] = 0.f;

  for (int k0 = 0; k0 < Kd; k0 += 8) {
    const float4 av = *(const float4*)(Ab + k0);
    const float4 bv = *(const float4*)(Bb + k0);
    __syncthreads();  // previous tile fully consumed
    As[lc + 0][lr] = av.x; As[lc + 1][lr] = av.y; As[lc + 2][lr] = av.z; As[lc + 3][lr] = av.w;
    Bs[lc + 0][lr] = bv.x; Bs[lc + 1][lr] = bv.y; Bs[lc + 2][lr] = bv.z; Bs[lc + 3][lr] = bv.w;
    __syncthreads();
#pragma unroll
    for (int kk = 0; kk < 8; kk++) {
      float a[8], b[8];
#pragma unroll
      for (int i = 0; i < 8; i++) a[i] = As[kk][ty * 8 + i];
#pragma unroll
      for (int j = 0; j < 8; j++) b[j] = Bs[kk][tx * 8 + j];
#pragma unroll
      for (int i = 0; i < 8; i++)
#pragma unroll
        for (int j = 0; j < 8; j++) acc[i][j] = fmaf(a[i], b[j], acc[i][j]);
    }
  }
  const int col = blockIdx.x * 128 + tx * 8;
  float bb[8];
#pragma unroll
  for (int j = 0; j < 8; j++) bb[j] = BIAS ? bias[col + j] : 0.f;
#pragma unroll
  for (int i = 0; i < 8; i++) {
    const size_t row = (size_t)blockIdx.y * 128 + ty * 8 + i;
    float4 v0, v1;
    v0.x = acc[i][0] + bb[0]; v0.y = acc[i][1] + bb[1]; v0.z = acc[i][2] + bb[2]; v0.w = acc[i][3] + bb[3];
    v1.x = acc[i][4] + bb[4]; v1.y = acc[i][5] + bb[5]; v1.z = acc[i][6] + bb[6]; v1.w = acc[i][7] + bb[7];
    *(float4*)(C + row * N + col) = v0;
    *(float4*)(C + row * N + col + 4) = v1;
  }
}

// ---------- fused single-head cross-attention (folded): scores via qk_vec, outputs wce ----------
__global__ __launch_bounds__(512)
void attn_kernel(const float* __restrict__ ce, const float* __restrict__ qkv,
                 const float* __restrict__ q, const float* __restrict__ bk,
                 float* __restrict__ wce)
{
  extern __shared__ float sm[];
  float* ce_s = sm;               // K_*D_
  float* qk_s = ce_s + K_ * D_;   // D_
  float* sc_s = qk_s + D_;        // K_
  float* at_s = sc_s + K_;        // K_
  float* rd_s = at_s + K_;        // 8
  const int b = blockIdx.x, t = threadIdx.x;
  const int w = t >> 6, l = t & 63;

  float p = 0.f;
  if (t < H_) p = q[(size_t)b * H_ + t] * bk[t];
  p = wsum(p);
  if (l == 0) rd_s[w] = p;
  for (int i = t; i < D_; i += 512) qk_s[i] = qkv[(size_t)b * D_ + i];
  const float4* cg = (const float4*)(ce + (size_t)b * K_ * D_);
  float4* cs = (float4*)ce_s;
#pragma unroll
  for (int i = 0; i < 12; i++) cs[t + i * 512] = cg[t + i * 512];
  __syncthreads();
  const float qbk = rd_s[0] + rd_s[1] + rd_s[2] + rd_s[3] + rd_s[4] + rd_s[5] + rd_s[6] + rd_s[7];

  // scores: wave w handles candidates 4w..4w+3
#pragma unroll
  for (int cc = 0; cc < 4; cc++) {
    const int c = w * 4 + cc;
    float s = 0.f;
#pragma unroll
    for (int j = 0; j < 12; j++) s = fmaf(ce_s[c * D_ + l + j * 64], qk_s[l + j * 64], s);
    s = wsum(s);
    if (l == 0) sc_s[c] = s + qbk;
  }
  __syncthreads();
  if (w == 0) {
    float s = (l < K_) ? sc_s[l] * (1.f / 16.f) : -1e30f;  // /sqrt(H)
    const float m = wmaxr(s);
    float e = (l < K_) ? expf(s - m) : 0.f;
    const float su = wsum(e);
    if (l < K_) at_s[l] = e / su;
  }
  __syncthreads();
  for (int j = t; j < D_; j += 512) {
    float acc = 0.f;
#pragma unroll
    for (int c = 0; c < K_; c++) acc = fmaf(at_s[c], ce_s[c * D_ + j], acc);
    wce[(size_t)b * D_ + j] = acc;
  }
}

// ---------- residual + LayerNorm (4 rows/block, wave per row) ----------
__global__ __launch_bounds__(256)
void ln_kernel(const float* __restrict__ xin, const float* __restrict__ res,
               const float* __restrict__ lw, const float* __restrict__ lb,
               float* __restrict__ qe)
{
  const int w = threadIdx.x >> 6, l = threadIdx.x & 63;
  const size_t r = (size_t)blockIdx.x * 4 + w;
  const float4 a = *(const float4*)(xin + r * H_ + l * 4);
  const float4 b = *(const float4*)(res + r * H_ + l * 4);
  const float x0 = a.x + b.x, x1 = a.y + b.y, x2 = a.z + b.z, x3 = a.w + b.w;
  const float mu = wsum(x0 + x1 + x2 + x3) * (1.f / H_);
  const float d0 = x0 - mu, d1 = x1 - mu, d2 = x2 - mu, d3 = x3 - mu;
  const float var = wsum(d0 * d0 + d1 * d1 + d2 * d2 + d3 * d3) * (1.f / H_);
  const float sd = sqrtf(var + 1e-5f);
  const float4 w4 = *(const float4*)(lw + l * 4);
  const float4 b4 = *(const float4*)(lb + l * 4);
  float4 o;
  o.x = d0 / sd * w4.x + b4.x; o.y = d1 / sd * w4.y + b4.y;
  o.z = d2 / sd * w4.z + b4.z; o.w = d3 / sd * w4.w + b4.w;
  *(float4*)(qe + r * H_ + l * 4) = o;
}

// ---------- h = l2n(hraw); need = softmax(h@Wqt^T + bqt) ----------
__global__ __launch_bounds__(256)
void h_post(const float* __restrict__ hraw, const float* __restrict__ Wqt,
            const float* __restrict__ bqt, float* __restrict__ h, float* __restrict__ need)
{
  __shared__ float wq_s[T_ * H_];
  for (int i = threadIdx.x; i < T_ * H_; i += 256) wq_s[i] = Wqt[i];
  const int w = threadIdx.x >> 6, l = threadIdx.x & 63;
  const size_t r = (size_t)blockIdx.x * 4 + w;
  const float4 v = *(const float4*)(hraw + r * H_ + l * 4);
  const float n = fmaxf(sqrtf(wsum(v.x * v.x + v.y * v.y + v.z * v.z + v.w * v.w)), 1e-12f);
  float4 hn; hn.x = v.x / n; hn.y = v.y / n; hn.z = v.z / n; hn.w = v.w / n;
  *(float4*)(h + r * H_ + l * 4) = hn;
  __syncthreads();
  float mine = 0.f;
  for (int tt = 0; tt < T_; tt++) {
    const float4 p4 = *(const float4*)(wq_s + tt * H_ + l * 4);
    float p = hn.x * p4.x + hn.y * p4.y + hn.z * p4.z + hn.w * p4.w;
    p = wsum(p);
    if (l == tt) mine = p + bqt[l];
  }
  float s = (l < T_) ? mine : -1e30f;
  const float m = wmaxr(s);
  const float e = (l < T_) ? expf(s - m) : 0.f;
  const float su = wsum(e);
  if (l < T_) need[r * T_ + l] = e / su;
}

// ---------- cn = l2n(cn_raw) in place; tp = softmax(cn @ proto_n^T) ----------
__global__ __launch_bounds__(256)
void cn_post(float* __restrict__ cn, const float* __restrict__ pro, float* __restrict__ tp)
{
  __shared__ float pr_s[T_ * H_];
  for (int i = threadIdx.x; i < T_ * H_; i += 256) pr_s[i] = pro[i];
  const int w = threadIdx.x >> 6, l = threadIdx.x & 63;
  const size_t r = (size_t)blockIdx.x * 4 + w;
  const float4 v = *(const float4*)(cn + r * H_ + l * 4);
  const float n = fmaxf(sqrtf(wsum(v.x * v.x + v.y * v.y + v.z * v.z + v.w * v.w)), 1e-12f);
  float4 cv; cv.x = v.x / n; cv.y = v.y / n; cv.z = v.z / n; cv.w = v.w / n;
  *(float4*)(cn + r * H_ + l * 4) = cv;
  __syncthreads();
  float mine = 0.f;
  for (int tt = 0; tt < T_; tt++) {
    const float4 p4 = *(const float4*)(pr_s + tt * H_ + l * 4);
    float p = cv.x * p4.x + cv.y * p4.y + cv.z * p4.z + cv.w * p4.w;
    p = wsum(p);
    if (l == tt) mine = p;
  }
  float s = (l < T_) ? mine : -1e30f;
  const float m = wmaxr(s);
  const float e = (l < T_) ? expf(s - m) : 0.f;
  const float su = wsum(e);
  if (l < T_) tp[r * T_ + l] = e / su;
}

// ---------- selection step: scores, argmax, logits/preds, state updates ----------
template<int STEP>
__global__ __launch_bounds__(256)
void score_kernel(const float* __restrict__ h, const float* __restrict__ se,
                  const float* __restrict__ cn, const float* __restrict__ tp,
                  const float* __restrict__ need, const float* __restrict__ clam,
                  float* __restrict__ covered, int* __restrict__ sel,
                  float* __restrict__ chosen, float* __restrict__ logits,
                  float* __restrict__ preds)
{
  __shared__ __align__(16) float hs_s[H_];
  __shared__ float nu_s[T_];
  __shared__ float sc_s[K_];
  __shared__ float rd_s[4];
  __shared__ int idx_s;
  const int b = blockIdx.x, t = threadIdx.x;
  const int w = t >> 6, l = t & 63;

  const float hv = h[(size_t)b * H_ + t] + se[STEP * H_ + t];
  const float ss = wsum(hv * hv);
  if (l == 0) rd_s[w] = ss;
  if (STEP == 1 && t < T_)
    nu_s[t] = need[(size_t)b * T_ + t] * fminf(fmaxf(1.f - covered[(size_t)b * T_ + t], 0.f), 1.f);
  __syncthreads();
  const float n = fmaxf(sqrtf(rd_s[0] + rd_s[1] + rd_s[2] + rd_s[3]), 1e-12f);
  hs_s[t] = hv / n;
  __syncthreads();

  const float lam = log1pf(expf(clam[0]));  // softplus
  const float4 hf = *(const float4*)(hs_s + l * 4);
#pragma unroll
  for (int cc = 0; cc < 8; cc++) {
    const int c = w * 8 + cc;
    const float4 cv = *(const float4*)(cn + ((size_t)b * K_ + c) * H_ + l * 4);
    float p = cv.x * hf.x + cv.y * hf.y + cv.z * hf.z + cv.w * hf.w;
    p = wsum(p);
    float s = p / 0.1f;  // / TEMP
    if (STEP == 1) {
      float g = (l < T_) ? nu_s[l] * tp[((size_t)b * K_ + c) * T_ + l] : 0.f;
      g = wsum(g);
      s += lam * g;
      if (sel[(size_t)b * K_ + c]) s = -100.f;
    }
    if (l == 0) sc_s[c] = s;
  }
  __syncthreads();
  if (w == 0) {  // argmax, first-index tie-break
    float s = (l < K_) ? sc_s[l] : -1e30f;
    int bi = (l < K_) ? l : K_;
#pragma unroll
    for (int o = 32; o; o >>= 1) {
      const float s2 = __shfl_xor(s, o);
      const int i2 = __shfl_xor(bi, o);
      if (s2 > s || (s2 == s && i2 < bi)) { s = s2; bi = i2; }
    }
    if (l == 0) idx_s = bi;
  }
  __syncthreads();
  const int idx = idx_s;
  if (t < K_) logits[(size_t)b * (S_ * K_) + STEP * K_ + t] = sc_s[t];
  if (t == 0) preds[(size_t)b * S_ + STEP] = (float)idx;
  if (STEP == 0) {
    if (t < K_) sel[(size_t)b * K_ + t] = (t == idx) ? 1 : 0;
    if (t < T_) covered[(size_t)b * T_ + t] = fminf(tp[((size_t)b * K_ + idx) * T_ + t], 1.f);
    chosen[(size_t)b * H_ + t] = cn[((size_t)b * K_ + idx) * H_ + t];
  }
}

// ---------- GRU gate fusion + l2n, h updated in place ----------
__global__ __launch_bounds__(256)
void gru_kernel(const float* __restrict__ gi, const float* __restrict__ gh, float* __restrict__ h)
{
  __shared__ float rd_s[4];
  const int b = blockIdx.x, t = threadIdx.x, w = t >> 6, l = t & 63;
  const size_t o = (size_t)b * (3 * H_);
  const float ir = gi[o + t], iz = gi[o + 256 + t], ig = gi[o + 512 + t];
  const float hr = gh[o + t], hz = gh[o + 256 + t], hg = gh[o + 512 + t];
  const float hv = h[(size_t)b * H_ + t];
  const float r = 1.f / (1.f + expf(-(ir + hr)));
  const float z = 1.f / (1.f + expf(-(iz + hz)));
  const float nn = tanhf(ig + r * hg);
  const float x = (1.f - z) * nn + z * hv;
  const float ss = wsum(x * x);
  if (l == 0) rd_s[w] = ss;
  __syncthreads();
  const float n = fmaxf(sqrtf(rd_s[0] + rd_s[1] + rd_s[2] + rd_s[3]), 1e-12f);
  h[(size_t)b * H_ + t] = x / n;
}

extern "C" void kernel_launch(void* const* d_in, const int* in_sizes, int n_in,
                              void* d_out, int out_size, void* d_ws, size_t ws_size,
                              hipStream_t stream)
{
  const float* query_emb = (const float*)d_in[0];
  const float* cand_emb  = (const float*)d_in[1];
  const float* W_in = (const float*)d_in[2];
  const float* Wq_a = (const float*)d_in[3];
  const float* Wk_a = (const float*)d_in[4];
  const float* Wv_a = (const float*)d_in[5];
  const float* bq_a = (const float*)d_in[6];
  const float* bk_a = (const float*)d_in[7];
  const float* bv_a = (const float*)d_in[8];
  const float* Wo_a = (const float*)d_in[9];
  const float* bo_a = (const float*)d_in[10];
  const float* ln_w = (const float*)d_in[11];
  const float* ln_b = (const float*)d_in[12];
  const float* Wq   = (const float*)d_in[13];
  const float* Wc   = (const float*)d_in[14];
  const float* W_ih = (const float*)d_in[15];
  const float* W_hh = (const float*)d_in[16];
  const float* b_ih = (const float*)d_in[17];
  const float* b_hh = (const float*)d_in[18];
  const float* step_emb = (const float*)d_in[19];
  const float* tpro = (const float*)d_in[20];
  const float* Wqt  = (const float*)d_in[21];
  const float* bqt  = (const float*)d_in[22];
  const float* clam = (const float*)d_in[23];

  // workspace layout (floats); aliases: qr->qe, q->ctx, qkv->gi, wce->gh, ctxv->hraw. ~382 MB total.
  float* ws = (float*)d_ws;
  size_t o = 0;
  float* WkinT = ws + o; o += (size_t)D_ * H_;
  float* Wv_in = ws + o; o += (size_t)H_ * D_;
  float* Wc_in = ws + o; o += (size_t)H_ * D_;
  float* pro   = ws + o; o += (size_t)T_ * H_;
  float* qr    = ws + o; o += (size_t)B_ * H_;   // later: qe (in-place)
  float* q     = ws + o; o += (size_t)B_ * H_;   // later: ctx
  float* qkv   = ws + o; o += (size_t)B_ * D_;   // later: gi
  float* wce   = ws + o; o += (size_t)B_ * D_;   // later: gh
  float* ctxv  = ws + o; o += (size_t)B_ * H_;   // later: hraw
  float* h     = ws + o; o += (size_t)B_ * H_;
  float* need  = ws + o; o += (size_t)B_ * T_;
  float* cn    = ws + o; o += (size_t)B_ * K_ * H_;
  float* tp    = ws + o; o += (size_t)B_ * K_ * T_;
  int*   sel   = (int*)(ws + o); o += (size_t)B_ * K_;
  float* cov   = ws + o; o += (size_t)B_ * T_;
  float* chosen= ws + o; o += (size_t)B_ * H_;

  float* out_logits = (float*)d_out;
  float* out_preds  = (float*)d_out + (size_t)B_ * S_ * K_;

  const int attn_lds = (K_ * D_ + D_ + K_ + K_ + 8) * 4;  // 101664 B

  fold_kernel<<<dim3(H_, 3), 256, 0, stream>>>(Wk_a, Wv_a, Wc, W_in, WkinT, Wv_in, Wc_in);
  proto_kernel<<<1, 256, 0, stream>>>(tpro, pro);

  // query path
  gemm_nt<false><<<dim3(H_ / 128, B_ / 128), 256, 0, stream>>>(query_emb, W_in, nullptr, qr, B_, H_, D_);
  gemm_nt<true ><<<dim3(H_ / 128, B_ / 128), 256, 0, stream>>>(qr, Wq_a, bq_a, q, B_, H_, H_);
  gemm_nt<false><<<dim3(D_ / 128, B_ / 128), 256, 0, stream>>>(q, WkinT, nullptr, qkv, B_, D_, H_);
  attn_kernel<<<B_, 512, attn_lds, stream>>>(cand_emb, qkv, q, bk_a, wce);
  gemm_nt<true ><<<dim3(H_ / 128, B_ / 128), 256, 0, stream>>>(wce, Wv_in, bv_a, ctxv, B_, H_, D_);
  gemm_nt<true ><<<dim3(H_ / 128, B_ / 128), 256, 0, stream>>>(ctxv, Wo_a, bo_a, q, B_, H_, H_);  // q := ctx
  ln_kernel<<<B_ / 4, 256, 0, stream>>>(q, qr, ln_w, ln_b, qr);                                   // qr := qe
  gemm_nt<false><<<dim3(H_ / 128, B_ / 128), 256, 0, stream>>>(qr, Wq, nullptr, ctxv, B_, H_, H_); // ctxv := hraw
  h_post<<<B_ / 4, 256, 0, stream>>>(ctxv, Wqt, bqt, h, need);

  // candidate path (the big GEMM)
  gemm_nt<false><<<dim3(H_ / 128, (B_ * K_) / 128), 256, 0, stream>>>(cand_emb, Wc_in, nullptr, cn, B_ * K_, H_, D_);
  cn_post<<<(B_ * K_) / 4, 256, 0, stream>>>(cn, pro, tp);

  // step 0
  score_kernel<0><<<B_, 256, 0, stream>>>(h, step_emb, cn, tp, need, clam, cov, sel, chosen, out_logits, out_preds);
  // GRU update
  gemm_nt<true ><<<dim3((3 * H_) / 128, B_ / 128), 256, 0, stream>>>(chosen, W_ih, b_ih, qkv, B_, 3 * H_, H_);  // qkv := gi
  gemm_nt<true ><<<dim3((3 * H_) / 128, B_ / 128), 256, 0, stream>>>(h, W_hh, b_hh, wce, B_, 3 * H_, H_);       // wce := gh
  gru_kernel<<<B_, 256, 0, stream>>>(qkv, wce, h);
  // step 1
  score_kernel<1><<<B_, 256, 0, stream>>>(h, step_emb, cn, tp, need, clam, cov, sel, chosen, out_logits, out_preds);
}

// Round 2
// 1767.475 us; speedup vs baseline: 1.4511x; 1.4511x over previous
//
#include <hip/hip_runtime.h>
#include <math.h>

#define B_ 8192
#define K_ 32
#define D_ 768
#define H_ 256
#define T_ 16
#define S_ 2

typedef unsigned int uint;
typedef unsigned short ushort;
typedef __attribute__((ext_vector_type(8))) short bf16x8;
typedef __attribute__((ext_vector_type(4))) float f32x4;

// ---------- wave (64-lane) reductions ----------
__device__ __forceinline__ float wsum(float v) {
  v += __shfl_xor(v, 32); v += __shfl_xor(v, 16); v += __shfl_xor(v, 8);
  v += __shfl_xor(v, 4);  v += __shfl_xor(v, 2);  v += __shfl_xor(v, 1);
  return v;
}
__device__ __forceinline__ float wmaxr(float v) {
  v = fmaxf(v, __shfl_xor(v, 32)); v = fmaxf(v, __shfl_xor(v, 16));
  v = fmaxf(v, __shfl_xor(v, 8));  v = fmaxf(v, __shfl_xor(v, 4));
  v = fmaxf(v, __shfl_xor(v, 2));  v = fmaxf(v, __shfl_xor(v, 1));
  return v;
}

// split fp32 -> (hi bf16 trunc, lo bf16 trunc of exact remainder), packed 2/uint
__device__ __forceinline__ void split4(const float4 f, uint2& h, uint2& lo) {
  const uint ux = __float_as_uint(f.x), uy = __float_as_uint(f.y);
  const uint uz = __float_as_uint(f.z), uw = __float_as_uint(f.w);
  h.x = (uy & 0xFFFF0000u) | (ux >> 16);
  h.y = (uw & 0xFFFF0000u) | (uz >> 16);
  const float rx = f.x - __uint_as_float(ux & 0xFFFF0000u);
  const float ry = f.y - __uint_as_float(uy & 0xFFFF0000u);
  const float rz = f.z - __uint_as_float(uz & 0xFFFF0000u);
  const float rw = f.w - __uint_as_float(uw & 0xFFFF0000u);
  lo.x = (__float_as_uint(ry) & 0xFFFF0000u) | (__float_as_uint(rx) >> 16);
  lo.y = (__float_as_uint(rw) & 0xFFFF0000u) | (__float_as_uint(rz) >> 16);
}

// ---------- weight folding: WkinT=(Wk_a@W_in)^T fp32, Wv_in fp32, Wc_in -> hi/lo bf16 frag-tiled ----------
__global__ __launch_bounds__(256)
void fold_kernel(const float* __restrict__ Wk_a, const float* __restrict__ Wv_a,
                 const float* __restrict__ Wc,  const float* __restrict__ W_in,
                 float* __restrict__ WkinT, float* __restrict__ Wv_in,
                 ushort* __restrict__ Bh, ushort* __restrict__ Bl)
{
  const int i = blockIdx.x;   // output row 0..255
  const int m = blockIdx.y;   // which matrix
  const float* Wx = (m == 0) ? Wk_a : ((m == 1) ? Wv_a : Wc);
  const int t = threadIdx.x;
  float a0 = 0.f, a1 = 0.f, a2 = 0.f;
  for (int k = 0; k < H_; k++) {
    const float wv = Wx[i * H_ + k];
    const float* row = W_in + (size_t)k * D_;
    a0 = fmaf(wv, row[t], a0);
    a1 = fmaf(wv, row[t + 256], a1);
    a2 = fmaf(wv, row[t + 512], a2);
  }
  if (m == 0) {  // store transposed [D,H] so qk_vec GEMM is NT
    WkinT[(size_t)t * H_ + i] = a0;
    WkinT[(size_t)(t + 256) * H_ + i] = a1;
    WkinT[(size_t)(t + 512) * H_ + i] = a2;
  } else if (m == 1) {
    float* o = Wv_in + (size_t)i * D_;
    o[t] = a0; o[t + 256] = a1; o[t + 512] = a2;
  } else {
    // fragment-tiled hi/lo for MFMA: elem = ((ks*16+nb)*64 + (nl|(kc<<4)))*8 + kb
    const float vals[3] = {a0, a1, a2};
#pragma unroll
    for (int j = 0; j < 3; j++) {
      const int k = t + j * 256;
      const float v = vals[j];
      const int idx = (((k >> 5) * 16 + (i >> 4)) * 64 + ((i & 15) | (((k >> 3) & 3) << 4))) * 8 + (k & 7);
      const uint u = __float_as_uint(v);
      Bh[idx] = (ushort)(u >> 16);
      const float rr = v - __uint_as_float(u & 0xFFFF0000u);
      Bl[idx] = (ushort)(__float_as_uint(rr) >> 16);
    }
  }
}

// ---------- l2-normalize topic prototypes ----------
__global__ __launch_bounds__(256)
void proto_kernel(const float* __restrict__ tpro, float* __restrict__ pro)
{
  const int w = threadIdx.x >> 6, l = threadIdx.x & 63;
  for (int r = w; r < T_; r += 4) {
    const float4 v = *(const float4*)(tpro + (size_t)r * H_ + l * 4);
    const float n = fmaxf(sqrtf(wsum(v.x * v.x + v.y * v.y + v.z * v.z + v.w * v.w)), 1e-12f);
    float4 o; o.x = v.x / n; o.y = v.y / n; o.z = v.z / n; o.w = v.w / n;
    *(float4*)(pro + (size_t)r * H_ + l * 4) = o;
  }
}

// ---------- split-bf16 MFMA GEMM: C[M,256] = A[M,768] * B^T, 3-term hi/lo ----------
// grid (M/128, 2), 256 threads, BK=32. B pre-tiled in fragment order by fold_kernel.
__global__ __launch_bounds__(256)
void gemm_cn(const float* __restrict__ A, const ushort* __restrict__ Bh,
             const ushort* __restrict__ Bl, float* __restrict__ C)
{
  __shared__ __align__(16) ushort AhS[4096], AlS[4096], BhS[4096], BlS[4096];
  const int t = threadIdx.x;
  const int l = t & 63, w = t >> 6;
  const int wr = w >> 1, wc = w & 1;
  const int cb = blockIdx.y;

  // staging map: thread -> (row r, k-chunk pair kc0..kc0+1)
  const int r = t >> 1;
  const int kc0 = (t & 1) * 2;
  const float* Ag = A + ((size_t)blockIdx.x * 128 + r) * 768 + kc0 * 8;
  const ushort* Bhg = Bh + (size_t)cb * 4096 + t * 8;
  const ushort* Blg = Bl + (size_t)cb * 4096 + t * 8;
  const int aslot0 = ((r >> 4) * 64 + ((r & 15) | (kc0 << 4))) * 8;
  const int aslot1 = ((r >> 4) * 64 + ((r & 15) | ((kc0 + 1) << 4))) * 8;

  f32x4 acc[4][4];
#pragma unroll
  for (int i = 0; i < 4; i++)
#pragma unroll
    for (int j = 0; j < 4; j++) acc[i][j] = (f32x4)0.f;

  // preload ks=0
  float4 f0 = *(const float4*)(Ag + 0);
  float4 f1 = *(const float4*)(Ag + 4);
  float4 f2 = *(const float4*)(Ag + 8);
  float4 f3 = *(const float4*)(Ag + 12);
  uint4 vbh0 = *(const uint4*)(Bhg + 0);
  uint4 vbh1 = *(const uint4*)(Bhg + 2048);
  uint4 vbl0 = *(const uint4*)(Blg + 0);
  uint4 vbl1 = *(const uint4*)(Blg + 2048);

  for (int ks = 0; ks < 24; ks++) {
    __syncthreads();  // previous tile fully consumed
    // stage B (plain copy, already bf16 hi/lo in fragment order)
    *(uint4*)&BhS[t * 8] = vbh0;  *(uint4*)&BhS[2048 + t * 8] = vbh1;
    *(uint4*)&BlS[t * 8] = vbl0;  *(uint4*)&BlS[2048 + t * 8] = vbl1;
    // stage A: convert fp32 -> hi/lo, write full 16B fragment slots
    {
      uint2 ha, la, hb, lb;
      split4(f0, ha, la); split4(f1, hb, lb);
      *(uint4*)&AhS[aslot0] = make_uint4(ha.x, ha.y, hb.x, hb.y);
      *(uint4*)&AlS[aslot0] = make_uint4(la.x, la.y, lb.x, lb.y);
      split4(f2, ha, la); split4(f3, hb, lb);
      *(uint4*)&AhS[aslot1] = make_uint4(ha.x, ha.y, hb.x, hb.y);
      *(uint4*)&AlS[aslot1] = make_uint4(la.x, la.y, lb.x, lb.y);
    }
    __syncthreads();
    // issue next tile's globals (latency hides under MFMA)
    if (ks < 23) {
      const int o4 = (ks + 1) * 32;
      f0 = *(const float4*)(Ag + o4);
      f1 = *(const float4*)(Ag + o4 + 4);
      f2 = *(const float4*)(Ag + o4 + 8);
      f3 = *(const float4*)(Ag + o4 + 12);
      const int ob = (ks + 1) * 8192;
      vbh0 = *(const uint4*)(Bhg + ob);
      vbh1 = *(const uint4*)(Bhg + ob + 2048);
      vbl0 = *(const uint4*)(Blg + ob);
      vbl1 = *(const uint4*)(Blg + ob + 2048);
    }
    // compute
    bf16x8 ah[4], al[4];
#pragma unroll
    for (int mi = 0; mi < 4; mi++) {
      ah[mi] = *(const bf16x8*)&AhS[((wr * 4 + mi) * 64 + l) * 8];
      al[mi] = *(const bf16x8*)&AlS[((wr * 4 + mi) * 64 + l) * 8];
    }
#pragma unroll
    for (int ni = 0; ni < 4; ni++) {
      const bf16x8 bhf = *(const bf16x8*)&BhS[((wc * 4 + ni) * 64 + l) * 8];
      const bf16x8 blf = *(const bf16x8*)&BlS[((wc * 4 + ni) * 64 + l) * 8];
#pragma unroll
      for (int mi = 0; mi < 4; mi++) {
        acc[mi][ni] = __builtin_amdgcn_mfma_f32_16x16x32_bf16(ah[mi], bhf, acc[mi][ni], 0, 0, 0);
        acc[mi][ni] = __builtin_amdgcn_mfma_f32_16x16x32_bf16(al[mi], bhf, acc[mi][ni], 0, 0, 0);
        acc[mi][ni] = __builtin_amdgcn_mfma_f32_16x16x32_bf16(ah[mi], blf, acc[mi][ni], 0, 0, 0);
      }
    }
  }

  // epilogue: C/D frag col=lane&15, row=(lane>>4)*4+reg
  const size_t crow0 = (size_t)blockIdx.x * 128;
  const int ccol0 = cb * 128 + wc * 64;
#pragma unroll
  for (int mi = 0; mi < 4; mi++)
#pragma unroll
    for (int ni = 0; ni < 4; ni++)
#pragma unroll
      for (int rg = 0; rg < 4; rg++) {
        const int rloc = wr * 64 + mi * 16 + (l >> 4) * 4 + rg;
        const int col = ccol0 + ni * 16 + (l & 15);
        C[(crow0 + rloc) * H_ + col] = acc[mi][ni][rg];
      }
}

// ---------- fp32 NT GEMM: C[M,N] = A[M,K]*B[N,K]^T (+bias). 128x128x8, 256 thr, 8x8/thr ----------
template<bool BIAS>
__global__ __launch_bounds__(256)
void gemm_nt(const float* __restrict__ A, const float* __restrict__ Bm,
             const float* __restrict__ bias, float* __restrict__ C,
             int M, int N, int Kd)
{
  __shared__ float As[8][132];
  __shared__ float Bs[8][132];
  const int t = threadIdx.x;
  const int tx = t & 15, ty = t >> 4;
  const int lr = t >> 1, lc = (t & 1) * 4;
  const float* Ab = A + ((size_t)blockIdx.y * 128 + lr) * Kd + lc;
  const float* Bb = Bm + ((size_t)blockIdx.x * 128 + lr) * Kd + lc;
  float acc[8][8];
#pragma unroll
  for (int i = 0; i < 8; i++)
#pragma unroll
    for (int j = 0; j < 8; j++) acc[i][j] = 0.f;

  for (int k0 = 0; k0 < Kd; k0 += 8) {
    const float4 av = *(const float4*)(Ab + k0);
    const float4 bv = *(const float4*)(Bb + k0);
    __syncthreads();
    As[lc + 0][lr] = av.x; As[lc + 1][lr] = av.y; As[lc + 2][lr] = av.z; As[lc + 3][lr] = av.w;
    Bs[lc + 0][lr] = bv.x; Bs[lc + 1][lr] = bv.y; Bs[lc + 2][lr] = bv.z; Bs[lc + 3][lr] = bv.w;
    __syncthreads();
#pragma unroll
    for (int kk = 0; kk < 8; kk++) {
      float a[8], b[8];
#pragma unroll
      for (int i = 0; i < 8; i++) a[i] = As[kk][ty * 8 + i];
#pragma unroll
      for (int j = 0; j < 8; j++) b[j] = Bs[kk][tx * 8 + j];
#pragma unroll
      for (int i = 0; i < 8; i++)
#pragma unroll
        for (int j = 0; j < 8; j++) acc[i][j] = fmaf(a[i], b[j], acc[i][j]);
    }
  }
  const int col = blockIdx.x * 128 + tx * 8;
  float bb[8];
#pragma unroll
  for (int j = 0; j < 8; j++) bb[j] = BIAS ? bias[col + j] : 0.f;
#pragma unroll
  for (int i = 0; i < 8; i++) {
    const size_t row = (size_t)blockIdx.y * 128 + ty * 8 + i;
    float4 v0, v1;
    v0.x = acc[i][0] + bb[0]; v0.y = acc[i][1] + bb[1]; v0.z = acc[i][2] + bb[2]; v0.w = acc[i][3] + bb[3];
    v1.x = acc[i][4] + bb[4]; v1.y = acc[i][5] + bb[5]; v1.z = acc[i][6] + bb[6]; v1.w = acc[i][7] + bb[7];
    *(float4*)(C + row * N + col) = v0;
    *(float4*)(C + row * N + col + 4) = v1;
  }
}

// ---------- fused single-head cross-attention (folded): scores via qk_vec, outputs wce ----------
__global__ __launch_bounds__(512)
void attn_kernel(const float* __restrict__ ce, const float* __restrict__ qkv,
                 const float* __restrict__ q, const float* __restrict__ bk,
                 float* __restrict__ wce)
{
  extern __shared__ float sm[];
  float* ce_s = sm;               // K_*D_
  float* qk_s = ce_s + K_ * D_;   // D_
  float* sc_s = qk_s + D_;        // K_
  float* at_s = sc_s + K_;        // K_
  float* rd_s = at_s + K_;        // 8
  const int b = blockIdx.x, t = threadIdx.x;
  const int w = t >> 6, l = t & 63;

  float p = 0.f;
  if (t < H_) p = q[(size_t)b * H_ + t] * bk[t];
  p = wsum(p);
  if (l == 0) rd_s[w] = p;
  for (int i = t; i < D_; i += 512) qk_s[i] = qkv[(size_t)b * D_ + i];
  const float4* cg = (const float4*)(ce + (size_t)b * K_ * D_);
  float4* cs = (float4*)ce_s;
#pragma unroll
  for (int i = 0; i < 12; i++) cs[t + i * 512] = cg[t + i * 512];
  __syncthreads();
  const float qbk = rd_s[0] + rd_s[1] + rd_s[2] + rd_s[3] + rd_s[4] + rd_s[5] + rd_s[6] + rd_s[7];

#pragma unroll
  for (int cc = 0; cc < 4; cc++) {
    const int c = w * 4 + cc;
    float s = 0.f;
#pragma unroll
    for (int j = 0; j < 12; j++) s = fmaf(ce_s[c * D_ + l + j * 64], qk_s[l + j * 64], s);
    s = wsum(s);
    if (l == 0) sc_s[c] = s + qbk;
  }
  __syncthreads();
  if (w == 0) {
    float s = (l < K_) ? sc_s[l] * (1.f / 16.f) : -1e30f;  // /sqrt(H)
    const float m = wmaxr(s);
    float e = (l < K_) ? expf(s - m) : 0.f;
    const float su = wsum(e);
    if (l < K_) at_s[l] = e / su;
  }
  __syncthreads();
  for (int j = t; j < D_; j += 512) {
    float acc = 0.f;
#pragma unroll
    for (int c = 0; c < K_; c++) acc = fmaf(at_s[c], ce_s[c * D_ + j], acc);
    wce[(size_t)b * D_ + j] = acc;
  }
}

// ---------- residual + LayerNorm (4 rows/block, wave per row) ----------
__global__ __launch_bounds__(256)
void ln_kernel(const float* __restrict__ xin, const float* __restrict__ res,
               const float* __restrict__ lw, const float* __restrict__ lb,
               float* __restrict__ qe)
{
  const int w = threadIdx.x >> 6, l = threadIdx.x & 63;
  const size_t r = (size_t)blockIdx.x * 4 + w;
  const float4 a = *(const float4*)(xin + r * H_ + l * 4);
  const float4 b = *(const float4*)(res + r * H_ + l * 4);
  const float x0 = a.x + b.x, x1 = a.y + b.y, x2 = a.z + b.z, x3 = a.w + b.w;
  const float mu = wsum(x0 + x1 + x2 + x3) * (1.f / H_);
  const float d0 = x0 - mu, d1 = x1 - mu, d2 = x2 - mu, d3 = x3 - mu;
  const float var = wsum(d0 * d0 + d1 * d1 + d2 * d2 + d3 * d3) * (1.f / H_);
  const float sd = sqrtf(var + 1e-5f);
  const float4 w4 = *(const float4*)(lw + l * 4);
  const float4 b4 = *(const float4*)(lb + l * 4);
  float4 o;
  o.x = d0 / sd * w4.x + b4.x; o.y = d1 / sd * w4.y + b4.y;
  o.z = d2 / sd * w4.z + b4.z; o.w = d3 / sd * w4.w + b4.w;
  *(float4*)(qe + r * H_ + l * 4) = o;
}

// ---------- h = l2n(hraw); need = softmax(h@Wqt^T + bqt) ----------
__global__ __launch_bounds__(256)
void h_post(const float* __restrict__ hraw, const float* __restrict__ Wqt,
            const float* __restrict__ bqt, float* __restrict__ h, float* __restrict__ need)
{
  __shared__ float wq_s[T_ * H_];
  for (int i = threadIdx.x; i < T_ * H_; i += 256) wq_s[i] = Wqt[i];
  const int w = threadIdx.x >> 6, l = threadIdx.x & 63;
  const size_t r = (size_t)blockIdx.x * 4 + w;
  const float4 v = *(const float4*)(hraw + r * H_ + l * 4);
  const float n = fmaxf(sqrtf(wsum(v.x * v.x + v.y * v.y + v.z * v.z + v.w * v.w)), 1e-12f);
  float4 hn; hn.x = v.x / n; hn.y = v.y / n; hn.z = v.z / n; hn.w = v.w / n;
  *(float4*)(h + r * H_ + l * 4) = hn;
  __syncthreads();
  float mine = 0.f;
  for (int tt = 0; tt < T_; tt++) {
    const float4 p4 = *(const float4*)(wq_s + tt * H_ + l * 4);
    float p = hn.x * p4.x + hn.y * p4.y + hn.z * p4.z + hn.w * p4.w;
    p = wsum(p);
    if (l == tt) mine = p + bqt[l];
  }
  float s = (l < T_) ? mine : -1e30f;
  const float m = wmaxr(s);
  const float e = (l < T_) ? expf(s - m) : 0.f;
  const float su = wsum(e);
  if (l < T_) need[r * T_ + l] = e / su;
}

// ---------- cn = l2n(cn_raw) in place; tp = softmax(cn @ proto_n^T) ----------
__global__ __launch_bounds__(256)
void cn_post(float* __restrict__ cn, const float* __restrict__ pro, float* __restrict__ tp)
{
  __shared__ float pr_s[T_ * H_];
  for (int i = threadIdx.x; i < T_ * H_; i += 256) pr_s[i] = pro[i];
  const int w = threadIdx.x >> 6, l = threadIdx.x & 63;
  const size_t r = (size_t)blockIdx.x * 4 + w;
  const float4 v = *(const float4*)(cn + r * H_ + l * 4);
  const float n = fmaxf(sqrtf(wsum(v.x * v.x + v.y * v.y + v.z * v.z + v.w * v.w)), 1e-12f);
  float4 cv; cv.x = v.x / n; cv.y = v.y / n; cv.z = v.z / n; cv.w = v.w / n;
  *(float4*)(cn + r * H_ + l * 4) = cv;
  __syncthreads();
  float mine = 0.f;
  for (int tt = 0; tt < T_; tt++) {
    const float4 p4 = *(const float4*)(pr_s + tt * H_ + l * 4);
    float p = cv.x * p4.x + cv.y * p4.y + cv.z * p4.z + cv.w * p4.w;
    p = wsum(p);
    if (l == tt) mine = p;
  }
  float s = (l < T_) ? mine : -1e30f;
  const float m = wmaxr(s);
  const float e = (l < T_) ? expf(s - m) : 0.f;
  const float su = wsum(e);
  if (l < T_) tp[r * T_ + l] = e / su;
}

// ---------- selection step: scores, argmax, logits/preds, state updates ----------
template<int STEP>
__global__ __launch_bounds__(256)
void score_kernel(const float* __restrict__ h, const float* __restrict__ se,
                  const float* __restrict__ cn, const float* __restrict__ tp,
                  const float* __restrict__ need, const float* __restrict__ clam,
                  float* __restrict__ covered, int* __restrict__ sel,
                  float* __restrict__ chosen, float* __restrict__ logits,
                  float* __restrict__ preds)
{
  __shared__ __align__(16) float hs_s[H_];
  __shared__ float nu_s[T_];
  __shared__ float sc_s[K_];
  __shared__ float rd_s[4];
  __shared__ int idx_s;
  const int b = blockIdx.x, t = threadIdx.x;
  const int w = t >> 6, l = t & 63;

  const float hv = h[(size_t)b * H_ + t] + se[STEP * H_ + t];
  const float ss = wsum(hv * hv);
  if (l == 0) rd_s[w] = ss;
  if (STEP == 1 && t < T_)
    nu_s[t] = need[(size_t)b * T_ + t] * fminf(fmaxf(1.f - covered[(size_t)b * T_ + t], 0.f), 1.f);
  __syncthreads();
  const float n = fmaxf(sqrtf(rd_s[0] + rd_s[1] + rd_s[2] + rd_s[3]), 1e-12f);
  hs_s[t] = hv / n;
  __syncthreads();

  const float lam = log1pf(expf(clam[0]));  // softplus
  const float4 hf = *(const float4*)(hs_s + l * 4);
#pragma unroll
  for (int cc = 0; cc < 8; cc++) {
    const int c = w * 8 + cc;
    const float4 cv = *(const float4*)(cn + ((size_t)b * K_ + c) * H_ + l * 4);
    float p = cv.x * hf.x + cv.y * hf.y + cv.z * hf.z + cv.w * hf.w;
    p = wsum(p);
    float s = p / 0.1f;  // / TEMP
    if (STEP == 1) {
      float g = (l < T_) ? nu_s[l] * tp[((size_t)b * K_ + c) * T_ + l] : 0.f;
      g = wsum(g);
      s += lam * g;
      if (sel[(size_t)b * K_ + c]) s = -100.f;
    }
    if (l == 0) sc_s[c] = s;
  }
  __syncthreads();
  if (w == 0) {  // argmax, first-index tie-break
    float s = (l < K_) ? sc_s[l] : -1e30f;
    int bi = (l < K_) ? l : K_;
#pragma unroll
    for (int o = 32; o; o >>= 1) {
      const float s2 = __shfl_xor(s, o);
      const int i2 = __shfl_xor(bi, o);
      if (s2 > s || (s2 == s && i2 < bi)) { s = s2; bi = i2; }
    }
    if (l == 0) idx_s = bi;
  }
  __syncthreads();
  const int idx = idx_s;
  if (t < K_) logits[(size_t)b * (S_ * K_) + STEP * K_ + t] = sc_s[t];
  if (t == 0) preds[(size_t)b * S_ + STEP] = (float)idx;
  if (STEP == 0) {
    if (t < K_) sel[(size_t)b * K_ + t] = (t == idx) ? 1 : 0;
    if (t < T_) covered[(size_t)b * T_ + t] = fminf(tp[((size_t)b * K_ + idx) * T_ + t], 1.f);
    chosen[(size_t)b * H_ + t] = cn[((size_t)b * K_ + idx) * H_ + t];
  }
}

// ---------- GRU gate fusion + l2n, h updated in place ----------
__global__ __launch_bounds__(256)
void gru_kernel(const float* __restrict__ gi, const float* __restrict__ gh, float* __restrict__ h)
{
  __shared__ float rd_s[4];
  const int b = blockIdx.x, t = threadIdx.x, w = t >> 6, l = t & 63;
  const size_t o = (size_t)b * (3 * H_);
  const float ir = gi[o + t], iz = gi[o + 256 + t], ig = gi[o + 512 + t];
  const float hr = gh[o + t], hz = gh[o + 256 + t], hg = gh[o + 512 + t];
  const float hv = h[(size_t)b * H_ + t];
  const float r = 1.f / (1.f + expf(-(ir + hr)));
  const float z = 1.f / (1.f + expf(-(iz + hz)));
  const float nn = tanhf(ig + r * hg);
  const float x = (1.f - z) * nn + z * hv;
  const float ss = wsum(x * x);
  if (l == 0) rd_s[w] = ss;
  __syncthreads();
  const float n = fmaxf(sqrtf(rd_s[0] + rd_s[1] + rd_s[2] + rd_s[3]), 1e-12f);
  h[(size_t)b * H_ + t] = x / n;
}

extern "C" void kernel_launch(void* const* d_in, const int* in_sizes, int n_in,
                              void* d_out, int out_size, void* d_ws, size_t ws_size,
                              hipStream_t stream)
{
  const float* query_emb = (const float*)d_in[0];
  const float* cand_emb  = (const float*)d_in[1];
  const float* W_in = (const float*)d_in[2];
  const float* Wq_a = (const float*)d_in[3];
  const float* Wk_a = (const float*)d_in[4];
  const float* Wv_a = (const float*)d_in[5];
  const float* bq_a = (const float*)d_in[6];
  const float* bk_a = (const float*)d_in[7];
  const float* bv_a = (const float*)d_in[8];
  const float* Wo_a = (const float*)d_in[9];
  const float* bo_a = (const float*)d_in[10];
  const float* ln_w = (const float*)d_in[11];
  const float* ln_b = (const float*)d_in[12];
  const float* Wq   = (const float*)d_in[13];
  const float* Wc   = (const float*)d_in[14];
  const float* W_ih = (const float*)d_in[15];
  const float* W_hh = (const float*)d_in[16];
  const float* b_ih = (const float*)d_in[17];
  const float* b_hh = (const float*)d_in[18];
  const float* step_emb = (const float*)d_in[19];
  const float* tpro = (const float*)d_in[20];
  const float* Wqt  = (const float*)d_in[21];
  const float* bqt  = (const float*)d_in[22];
  const float* clam = (const float*)d_in[23];

  float* ws = (float*)d_ws;
  size_t o = 0;
  float* WkinT = ws + o; o += (size_t)D_ * H_;
  float* Wv_in = ws + o; o += (size_t)H_ * D_;
  ushort* BhW  = (ushort*)(ws + o); o += (size_t)H_ * D_ / 2;
  ushort* BlW  = (ushort*)(ws + o); o += (size_t)H_ * D_ / 2;
  float* pro   = ws + o; o += (size_t)T_ * H_;
  float* qr    = ws + o; o += (size_t)B_ * H_;   // later: qe (in-place)
  float* q     = ws + o; o += (size_t)B_ * H_;   // later: ctx
  float* qkv   = ws + o; o += (size_t)B_ * D_;   // later: gi
  float* wce   = ws + o; o += (size_t)B_ * D_;   // later: gh
  float* ctxv  = ws + o; o += (size_t)B_ * H_;   // later: hraw
  float* h     = ws + o; o += (size_t)B_ * H_;
  float* need  = ws + o; o += (size_t)B_ * T_;
  float* cn    = ws + o; o += (size_t)B_ * K_ * H_;
  float* tp    = ws + o; o += (size_t)B_ * K_ * T_;
  int*   sel   = (int*)(ws + o); o += (size_t)B_ * K_;
  float* cov   = ws + o; o += (size_t)B_ * T_;
  float* chosen= ws + o; o += (size_t)B_ * H_;

  float* out_logits = (float*)d_out;
  float* out_preds  = (float*)d_out + (size_t)B_ * S_ * K_;

  const int attn_lds = (K_ * D_ + D_ + K_ + K_ + 8) * 4;

  fold_kernel<<<dim3(H_, 3), 256, 0, stream>>>(Wk_a, Wv_a, Wc, W_in, WkinT, Wv_in, BhW, BlW);
  proto_kernel<<<1, 256, 0, stream>>>(tpro, pro);

  // query path
  gemm_nt<false><<<dim3(H_ / 128, B_ / 128), 256, 0, stream>>>(query_emb, W_in, nullptr, qr, B_, H_, D_);
  gemm_nt<true ><<<dim3(H_ / 128, B_ / 128), 256, 0, stream>>>(qr, Wq_a, bq_a, q, B_, H_, H_);
  gemm_nt<false><<<dim3(D_ / 128, B_ / 128), 256, 0, stream>>>(q, WkinT, nullptr, qkv, B_, D_, H_);
  attn_kernel<<<B_, 512, attn_lds, stream>>>(cand_emb, qkv, q, bk_a, wce);
  gemm_nt<true ><<<dim3(H_ / 128, B_ / 128), 256, 0, stream>>>(wce, Wv_in, bv_a, ctxv, B_, H_, D_);
  gemm_nt<true ><<<dim3(H_ / 128, B_ / 128), 256, 0, stream>>>(ctxv, Wo_a, bo_a, q, B_, H_, H_);  // q := ctx
  ln_kernel<<<B_ / 4, 256, 0, stream>>>(q, qr, ln_w, ln_b, qr);                                   // qr := qe
  gemm_nt<false><<<dim3(H_ / 128, B_ / 128), 256, 0, stream>>>(qr, Wq, nullptr, ctxv, B_, H_, H_); // ctxv := hraw
  h_post<<<B_ / 4, 256, 0, stream>>>(ctxv, Wqt, bqt, h, need);

  // candidate path: split-bf16 MFMA GEMM
  gemm_cn<<<dim3((B_ * K_) / 128, 2), 256, 0, stream>>>(cand_emb, BhW, BlW, cn);
  cn_post<<<(B_ * K_) / 4, 256, 0, stream>>>(cn, pro, tp);

  // step 0
  score_kernel<0><<<B_, 256, 0, stream>>>(h, step_emb, cn, tp, need, clam, cov, sel, chosen, out_logits, out_preds);
  // GRU update
  gemm_nt<true ><<<dim3((3 * H_) / 128, B_ / 128), 256, 0, stream>>>(chosen, W_ih, b_ih, qkv, B_, 3 * H_, H_);  // qkv := gi
  gemm_nt<true ><<<dim3((3 * H_) / 128, B_ / 128), 256, 0, stream>>>(h, W_hh, b_hh, wce, B_, 3 * H_, H_);       // wce := gh
  gru_kernel<<<B_, 256, 0, stream>>>(qkv, wce, h);
  // step 1
  score_kernel<1><<<B_, 256, 0, stream>>>(h, step_emb, cn, tp, need, clam, cov, sel, chosen, out_logits, out_preds);
}

// Round 3
// 1476.942 us; speedup vs baseline: 1.7366x; 1.1967x over previous
//
#include <hip/hip_runtime.h>
#include <math.h>

#define B_ 8192
#define K_ 32
#define D_ 768
#define H_ 256
#define T_ 16
#define S_ 2

typedef unsigned int uint;
typedef unsigned short ushort;
typedef __attribute__((ext_vector_type(8))) short bf16x8;
typedef __attribute__((ext_vector_type(4))) float f32x4;

// ---------- wave (64-lane) reductions ----------
__device__ __forceinline__ float wsum(float v) {
  v += __shfl_xor(v, 32); v += __shfl_xor(v, 16); v += __shfl_xor(v, 8);
  v += __shfl_xor(v, 4);  v += __shfl_xor(v, 2);  v += __shfl_xor(v, 1);
  return v;
}
__device__ __forceinline__ float wmaxr(float v) {
  v = fmaxf(v, __shfl_xor(v, 32)); v = fmaxf(v, __shfl_xor(v, 16));
  v = fmaxf(v, __shfl_xor(v, 8));  v = fmaxf(v, __shfl_xor(v, 4));
  v = fmaxf(v, __shfl_xor(v, 2));  v = fmaxf(v, __shfl_xor(v, 1));
  return v;
}

// split fp32 -> (hi bf16 trunc, lo bf16 trunc of exact remainder), packed 2/uint
__device__ __forceinline__ void split4(const float4 f, uint2& h, uint2& lo) {
  const uint ux = __float_as_uint(f.x), uy = __float_as_uint(f.y);
  const uint uz = __float_as_uint(f.z), uw = __float_as_uint(f.w);
  h.x = (uy & 0xFFFF0000u) | (ux >> 16);
  h.y = (uw & 0xFFFF0000u) | (uz >> 16);
  const float rx = f.x - __uint_as_float(ux & 0xFFFF0000u);
  const float ry = f.y - __uint_as_float(uy & 0xFFFF0000u);
  const float rz = f.z - __uint_as_float(uz & 0xFFFF0000u);
  const float rw = f.w - __uint_as_float(uw & 0xFFFF0000u);
  lo.x = (__float_as_uint(ry) & 0xFFFF0000u) | (__float_as_uint(rx) >> 16);
  lo.y = (__float_as_uint(rw) & 0xFFFF0000u) | (__float_as_uint(rz) >> 16);
}

// ---------- fold stage 1: WkinT=(Wk_a@W_in)^T fp32, Wv_in fp32, Wc@W_in -> hi/lo bf16 frag-tiled ----------
__global__ __launch_bounds__(256)
void fold_kernel(const float* __restrict__ Wk_a, const float* __restrict__ Wv_a,
                 const float* __restrict__ Wc,  const float* __restrict__ W_in,
                 float* __restrict__ WkinT, float* __restrict__ Wv_in,
                 ushort* __restrict__ Bh, ushort* __restrict__ Bl)
{
  const int i = blockIdx.x;   // output row 0..255
  const int m = blockIdx.y;   // which matrix
  const float* Wx = (m == 0) ? Wk_a : ((m == 1) ? Wv_a : Wc);
  const int t = threadIdx.x;
  float a0 = 0.f, a1 = 0.f, a2 = 0.f;
  for (int k = 0; k < H_; k++) {
    const float wv = Wx[i * H_ + k];
    const float* row = W_in + (size_t)k * D_;
    a0 = fmaf(wv, row[t], a0);
    a1 = fmaf(wv, row[t + 256], a1);
    a2 = fmaf(wv, row[t + 512], a2);
  }
  if (m == 0) {
    WkinT[(size_t)t * H_ + i] = a0;
    WkinT[(size_t)(t + 256) * H_ + i] = a1;
    WkinT[(size_t)(t + 512) * H_ + i] = a2;
  } else if (m == 1) {
    float* o = Wv_in + (size_t)i * D_;
    o[t] = a0; o[t + 256] = a1; o[t + 512] = a2;
  } else {
    // fragment-tiled hi/lo for MFMA: elem = ((ks*16+nb)*64 + (nl|(kc<<4)))*8 + kb
    const float vals[3] = {a0, a1, a2};
#pragma unroll
    for (int j = 0; j < 3; j++) {
      const int k = t + j * 256;
      const float v = vals[j];
      const int idx = (((k >> 5) * 16 + (i >> 4)) * 64 + ((i & 15) | (((k >> 3) & 3) << 4))) * 8 + (k & 7);
      const uint u = __float_as_uint(v);
      Bh[idx] = (ushort)(u >> 16);
      const float rr = v - __uint_as_float(u & 0xFFFF0000u);
      Bl[idx] = (ushort)(__float_as_uint(rr) >> 16);
    }
  }
}

// ---------- fold stage 2: Bqk=(Wq_a^T Wk_in)^T-as-[768,256], Wvo=Wo_a@Wv_in, LN fold, bias folds ----------
__global__ __launch_bounds__(256)
void fold2_kernel(const float* __restrict__ Wq_a, const float* __restrict__ bq_a,
                  const float* __restrict__ bk_a, const float* __restrict__ Wo_a,
                  const float* __restrict__ bo_a, const float* __restrict__ bv_a,
                  const float* __restrict__ Wq,   const float* __restrict__ ln_w,
                  const float* __restrict__ ln_b, const float* __restrict__ WkinT,
                  const float* __restrict__ Wv_in,
                  float* __restrict__ Bqk, float* __restrict__ bqk,
                  float* __restrict__ Wvo, float* __restrict__ bvo,
                  float* __restrict__ Wqp, float* __restrict__ bqp,
                  float* __restrict__ vqbk, float* __restrict__ qcst)
{
  __shared__ float rd_s[4];
  const int n = blockIdx.x, t = threadIdx.x, w = t >> 6, l = t & 63;
  // Bqk[n][k] = sum_h Wq_a[h,k] * Wk_in[h,n]   (WkinT[n,h] = Wk_in[h,n])
  float s = 0.f;
  for (int hh = 0; hh < H_; hh++)
    s = fmaf(Wq_a[hh * H_ + t], WkinT[(size_t)n * H_ + hh], s);
  Bqk[(size_t)n * H_ + t] = s;
  // bqk[n] = sum_h bq[h] * Wk_in[h,n]
  float p = bq_a[t] * WkinT[(size_t)n * H_ + t];
  p = wsum(p);
  if (l == 0) rd_s[w] = p;
  __syncthreads();
  if (t == 0) bqk[n] = rd_s[0] + rd_s[1] + rd_s[2] + rd_s[3];
  if (n < H_) {
    // Wvo[n][d] = sum_h Wo_a[n,h] * Wv_in[h,d]
    float a0 = 0.f, a1 = 0.f, a2 = 0.f;
    for (int hh = 0; hh < H_; hh++) {
      const float wo = Wo_a[n * H_ + hh];
      const float* rowv = Wv_in + (size_t)hh * D_;
      a0 = fmaf(wo, rowv[t], a0);
      a1 = fmaf(wo, rowv[t + 256], a1);
      a2 = fmaf(wo, rowv[t + 512], a2);
    }
    Wvo[(size_t)n * D_ + t] = a0;
    Wvo[(size_t)n * D_ + t + 256] = a1;
    Wvo[(size_t)n * D_ + t + 512] = a2;
    // bvo[n] = sum_h Wo_a[n,h]*bv[h] + bo[n]
    float pb = Wo_a[n * H_ + t] * bv_a[t];
    pb = wsum(pb);
    __syncthreads();
    if (l == 0) rd_s[w] = pb;
    __syncthreads();
    if (t == 0) bvo[n] = rd_s[0] + rd_s[1] + rd_s[2] + rd_s[3] + bo_a[n];
    // LN fold into Wq
    Wqp[n * H_ + t] = Wq[n * H_ + t] * ln_w[t];
    float pq = Wq[n * H_ + t] * ln_b[t];
    pq = wsum(pq);
    __syncthreads();
    if (l == 0) rd_s[w] = pq;
    __syncthreads();
    if (t == 0) bqp[n] = rd_s[0] + rd_s[1] + rd_s[2] + rd_s[3];
  }
  if (n == 0) {
    // vqbk[k] = sum_h bk[h]*Wq_a[h,k];  qcst = bq.bk
    float sv = 0.f;
    for (int hh = 0; hh < H_; hh++) sv = fmaf(bk_a[hh], Wq_a[hh * H_ + t], sv);
    vqbk[t] = sv;
    float pc = bq_a[t] * bk_a[t];
    pc = wsum(pc);
    __syncthreads();
    if (l == 0) rd_s[w] = pc;
    __syncthreads();
    if (t == 0) qcst[0] = rd_s[0] + rd_s[1] + rd_s[2] + rd_s[3];
  }
}

// ---------- l2-normalize topic prototypes ----------
__global__ __launch_bounds__(256)
void proto_kernel(const float* __restrict__ tpro, float* __restrict__ pro)
{
  const int w = threadIdx.x >> 6, l = threadIdx.x & 63;
  for (int r = w; r < T_; r += 4) {
    const float4 v = *(const float4*)(tpro + (size_t)r * H_ + l * 4);
    const float n = fmaxf(sqrtf(wsum(v.x * v.x + v.y * v.y + v.z * v.z + v.w * v.w)), 1e-12f);
    float4 o; o.x = v.x / n; o.y = v.y / n; o.z = v.z / n; o.w = v.w / n;
    *(float4*)(pro + (size_t)r * H_ + l * 4) = o;
  }
}

// ---------- split-bf16 MFMA GEMM, full N=256 per block, fused l2n + topic softmax ----------
// grid (B*K/128), 512 threads (8 waves, 2x4), BK=32. Writes normalized cn + tp.
__global__ __launch_bounds__(512, 4)
void gemm_cn(const float* __restrict__ A, const ushort* __restrict__ Bh,
             const ushort* __restrict__ Bl, const float* __restrict__ pro,
             float* __restrict__ C, float* __restrict__ tp)
{
  __shared__ __align__(16) char smem[51200];
  ushort* AhS = (ushort*)smem;          // [0,4096) ushorts
  ushort* AlS = AhS + 4096;             // [4096,8192)
  ushort* BhS = AhS + 8192;             // [8192,16384)
  ushort* BlS = AhS + 16384;            // [16384,24576)
  float* pro_s = (float*)smem;          // epilogue alias: [0,4096) floats
  float* rsq   = (float*)smem + 4096;   // [4096,4608): [128][4]
  float* tdot  = (float*)smem + 4608;   // [4608,12800): [128][16][4]

  const int t = threadIdx.x;
  const int l = t & 63, w = t >> 6;
  const int wr = w >> 2, wc = w & 3;

  // staging map: A: thread -> (row r, k-chunk kc); B: contiguous copy
  const int r = t >> 2;
  const int kc = t & 3;
  const float* Ag = A + ((size_t)blockIdx.x * 128 + r) * 768 + kc * 8;
  const ushort* Bhg = Bh + t * 8;
  const ushort* Blg = Bl + t * 8;
  const int aslot = ((r >> 4) * 64 + ((r & 15) | (kc << 4))) * 8;

  f32x4 acc[4][4];
#pragma unroll
  for (int i = 0; i < 4; i++)
#pragma unroll
    for (int j = 0; j < 4; j++) acc[i][j] = (f32x4)0.f;

  // preload A ks=0 (register prefetch; B is L2-resident, load in-loop)
  float4 f0 = *(const float4*)(Ag + 0);
  float4 f1 = *(const float4*)(Ag + 4);

  for (int ks = 0; ks < 24; ks++) {
    __syncthreads();  // previous tile fully consumed
    // stage B (already bf16 hi/lo in fragment order)
    *(uint4*)&BhS[t * 8]        = *(const uint4*)(Bhg + ks * 8192);
    *(uint4*)&BhS[4096 + t * 8] = *(const uint4*)(Bhg + ks * 8192 + 4096);
    *(uint4*)&BlS[t * 8]        = *(const uint4*)(Blg + ks * 8192);
    *(uint4*)&BlS[4096 + t * 8] = *(const uint4*)(Blg + ks * 8192 + 4096);
    // stage A: fp32 -> hi/lo split, full 16B fragment slots
    {
      uint2 ha, la, hb, lb;
      split4(f0, ha, la); split4(f1, hb, lb);
      *(uint4*)&AhS[aslot] = make_uint4(ha.x, ha.y, hb.x, hb.y);
      *(uint4*)&AlS[aslot] = make_uint4(la.x, la.y, lb.x, lb.y);
    }
    __syncthreads();
    if (ks < 23) {
      const int o4 = (ks + 1) * 32;
      f0 = *(const float4*)(Ag + o4);
      f1 = *(const float4*)(Ag + o4 + 4);
    }
    bf16x8 ah[4], al[4];
#pragma unroll
    for (int mi = 0; mi < 4; mi++) {
      ah[mi] = *(const bf16x8*)&AhS[((wr * 4 + mi) * 64 + l) * 8];
      al[mi] = *(const bf16x8*)&AlS[((wr * 4 + mi) * 64 + l) * 8];
    }
#pragma unroll
    for (int ni = 0; ni < 4; ni++) {
      const bf16x8 bhf = *(const bf16x8*)&BhS[((wc * 4 + ni) * 64 + l) * 8];
      const bf16x8 blf = *(const bf16x8*)&BlS[((wc * 4 + ni) * 64 + l) * 8];
#pragma unroll
      for (int mi = 0; mi < 4; mi++) {
        acc[mi][ni] = __builtin_amdgcn_mfma_f32_16x16x32_bf16(ah[mi], bhf, acc[mi][ni], 0, 0, 0);
        acc[mi][ni] = __builtin_amdgcn_mfma_f32_16x16x32_bf16(al[mi], bhf, acc[mi][ni], 0, 0, 0);
        acc[mi][ni] = __builtin_amdgcn_mfma_f32_16x16x32_bf16(ah[mi], blf, acc[mi][ni], 0, 0, 0);
      }
    }
  }

  // ---- fused epilogue: l2n + cn write + tp = softmax(cn . proto^T) ----
  __syncthreads();  // staging LDS now dead
  // stage normalized protos [16][256] fp32
  {
    const float4* pg = (const float4*)pro;
    float4* ps = (float4*)pro_s;
    ps[t] = pg[t]; ps[t + 512] = pg[t + 512];
  }
  // per-row sum of squares: lane partial over its 4 cols, reduce over 16 lanes, 4 wc waves via LDS
#pragma unroll
  for (int mi = 0; mi < 4; mi++)
#pragma unroll
    for (int rg = 0; rg < 4; rg++) {
      float p = 0.f;
#pragma unroll
      for (int ni = 0; ni < 4; ni++) { const float v = acc[mi][ni][rg]; p = fmaf(v, v, p); }
      p += __shfl_xor(p, 1); p += __shfl_xor(p, 2); p += __shfl_xor(p, 4); p += __shfl_xor(p, 8);
      if ((l & 15) == 0) rsq[(wr * 64 + mi * 16 + (l >> 4) * 4 + rg) * 4 + wc] = p;
    }
  __syncthreads();
  // normalize in place + write cn (fp32)
  const size_t row0 = (size_t)blockIdx.x * 128;
#pragma unroll
  for (int mi = 0; mi < 4; mi++)
#pragma unroll
    for (int rg = 0; rg < 4; rg++) {
      const int rl = wr * 64 + mi * 16 + (l >> 4) * 4 + rg;
      const float ssum = rsq[rl * 4 + 0] + rsq[rl * 4 + 1] + rsq[rl * 4 + 2] + rsq[rl * 4 + 3];
      const float inv = 1.f / fmaxf(sqrtf(ssum), 1e-12f);
#pragma unroll
      for (int ni = 0; ni < 4; ni++) {
        const float v = acc[mi][ni][rg] * inv;
        acc[mi][ni][rg] = v;
        C[(row0 + rl) * H_ + wc * 64 + ni * 16 + (l & 15)] = v;
      }
    }
  // topic dots: per proto tt, per row: partial over lane's 4 cols, reduce 16 lanes -> tdot[row][tt][wc]
#pragma unroll
  for (int tt = 0; tt < T_; tt++) {
    const float p0 = pro_s[tt * H_ + wc * 64 + 0 * 16 + (l & 15)];
    const float p1 = pro_s[tt * H_ + wc * 64 + 1 * 16 + (l & 15)];
    const float p2 = pro_s[tt * H_ + wc * 64 + 2 * 16 + (l & 15)];
    const float p3 = pro_s[tt * H_ + wc * 64 + 3 * 16 + (l & 15)];
#pragma unroll
    for (int mi = 0; mi < 4; mi++)
#pragma unroll
      for (int rg = 0; rg < 4; rg++) {
        const int rl = wr * 64 + mi * 16 + (l >> 4) * 4 + rg;
        float p = acc[mi][0][rg] * p0 + acc[mi][1][rg] * p1 + acc[mi][2][rg] * p2 + acc[mi][3][rg] * p3;
        p += __shfl_xor(p, 1); p += __shfl_xor(p, 2); p += __shfl_xor(p, 4); p += __shfl_xor(p, 8);
        if ((l & 15) == 0) tdot[(rl * 16 + tt) * 4 + wc] = p;
      }
  }
  __syncthreads();
  if (t < 128) {
    float v[16];
    float mx = -1e30f;
#pragma unroll
    for (int tt = 0; tt < T_; tt++) {
      v[tt] = tdot[(t * 16 + tt) * 4 + 0] + tdot[(t * 16 + tt) * 4 + 1] +
              tdot[(t * 16 + tt) * 4 + 2] + tdot[(t * 16 + tt) * 4 + 3];
      mx = fmaxf(mx, v[tt]);
    }
    float se = 0.f;
#pragma unroll
    for (int tt = 0; tt < T_; tt++) { v[tt] = expf(v[tt] - mx); se += v[tt]; }
    const float is = 1.f / se;
#pragma unroll
    for (int tt = 0; tt < T_; tt++) tp[(row0 + t) * T_ + tt] = v[tt] * is;
  }
}

// ---------- fp32 NT GEMM: C[M,N] = A[M,K]*B[N,K]^T (+bias). 128x128x8, 256 thr, 8x8/thr ----------
template<bool BIAS>
__global__ __launch_bounds__(256)
void gemm_nt(const float* __restrict__ A, const float* __restrict__ Bm,
             const float* __restrict__ bias, float* __restrict__ C,
             int M, int N, int Kd)
{
  __shared__ float As[8][132];
  __shared__ float Bs[8][132];
  const int t = threadIdx.x;
  const int tx = t & 15, ty = t >> 4;
  const int lr = t >> 1, lc = (t & 1) * 4;
  const float* Ab = A + ((size_t)blockIdx.y * 128 + lr) * Kd + lc;
  const float* Bb = Bm + ((size_t)blockIdx.x * 128 + lr) * Kd + lc;
  float acc[8][8];
#pragma unroll
  for (int i = 0; i < 8; i++)
#pragma unroll
    for (int j = 0; j < 8; j++) acc[i][j] = 0.f;

  for (int k0 = 0; k0 < Kd; k0 += 8) {
    const float4 av = *(const float4*)(Ab + k0);
    const float4 bv = *(const float4*)(Bb + k0);
    __syncthreads();
    As[lc + 0][lr] = av.x; As[lc + 1][lr] = av.y; As[lc + 2][lr] = av.z; As[lc + 3][lr] = av.w;
    Bs[lc + 0][lr] = bv.x; Bs[lc + 1][lr] = bv.y; Bs[lc + 2][lr] = bv.z; Bs[lc + 3][lr] = bv.w;
    __syncthreads();
#pragma unroll
    for (int kk = 0; kk < 8; kk++) {
      float a[8], b[8];
#pragma unroll
      for (int i = 0; i < 8; i++) a[i] = As[kk][ty * 8 + i];
#pragma unroll
      for (int j = 0; j < 8; j++) b[j] = Bs[kk][tx * 8 + j];
#pragma unroll
      for (int i = 0; i < 8; i++)
#pragma unroll
        for (int j = 0; j < 8; j++) acc[i][j] = fmaf(a[i], b[j], acc[i][j]);
    }
  }
  const int col = blockIdx.x * 128 + tx * 8;
  float bb[8];
#pragma unroll
  for (int j = 0; j < 8; j++) bb[j] = BIAS ? bias[col + j] : 0.f;
#pragma unroll
  for (int i = 0; i < 8; i++) {
    const size_t row = (size_t)blockIdx.y * 128 + ty * 8 + i;
    float4 v0, v1;
    v0.x = acc[i][0] + bb[0]; v0.y = acc[i][1] + bb[1]; v0.z = acc[i][2] + bb[2]; v0.w = acc[i][3] + bb[3];
    v1.x = acc[i][4] + bb[4]; v1.y = acc[i][5] + bb[5]; v1.z = acc[i][6] + bb[6]; v1.w = acc[i][7] + bb[7];
    *(float4*)(C + row * N + col) = v0;
    *(float4*)(C + row * N + col + 4) = v1;
  }
}

// ---------- fused cross-attention, no LDS staging of ce (L2/L3 serves PV re-read) ----------
__global__ __launch_bounds__(256)
void attn_kernel(const float* __restrict__ ce, const float* __restrict__ qkv,
                 const float* __restrict__ qr, const float* __restrict__ vqbk,
                 const float* __restrict__ qcst, float* __restrict__ wce)
{
  __shared__ float4 qk_s[192];
  __shared__ float sc_s[K_];
  __shared__ float at_s[K_];
  __shared__ float rd_s[4];
  const int b = blockIdx.x, t = threadIdx.x;
  const int w = t >> 6, l = t & 63;

  // qbk = qr . vqbk + bq.bk
  float p = qr[(size_t)b * H_ + t] * vqbk[t];
  p = wsum(p);
  if (l == 0) rd_s[w] = p;
  if (t < 192) qk_s[t] = ((const float4*)qkv)[(size_t)b * 192 + t];
  __syncthreads();
  const float qbk = rd_s[0] + rd_s[1] + rd_s[2] + rd_s[3] + qcst[0];

  const float4* ceb = (const float4*)(ce + (size_t)b * K_ * D_);
  // scores: wave w handles candidates w*8 .. w*8+7
#pragma unroll
  for (int cc = 0; cc < 8; cc++) {
    const int c = w * 8 + cc;
    const float4* cr = ceb + c * 192;
    float s = 0.f;
#pragma unroll
    for (int j = 0; j < 3; j++) {
      const float4 f = cr[l + j * 64];
      const float4 q4 = qk_s[l + j * 64];
      s = fmaf(f.x, q4.x, s); s = fmaf(f.y, q4.y, s);
      s = fmaf(f.z, q4.z, s); s = fmaf(f.w, q4.w, s);
    }
    s = wsum(s);
    if (l == 0) sc_s[c] = s + qbk;
  }
  __syncthreads();
  if (w == 0) {
    float s = (l < K_) ? sc_s[l] * (1.f / 16.f) : -1e30f;  // /sqrt(H)
    const float m = wmaxr(s);
    float e = (l < K_) ? expf(s - m) : 0.f;
    const float su = wsum(e);
    if (l < K_) at_s[l] = e / su;
  }
  __syncthreads();
  if (t < 192) {
    float4 a = make_float4(0.f, 0.f, 0.f, 0.f);
#pragma unroll
    for (int c = 0; c < K_; c++) {
      const float4 f = ceb[c * 192 + t];
      const float av = at_s[c];
      a.x = fmaf(av, f.x, a.x); a.y = fmaf(av, f.y, a.y);
      a.z = fmaf(av, f.z, a.z); a.w = fmaf(av, f.w, a.w);
    }
    ((float4*)wce)[(size_t)b * 192 + t] = a;
  }
}

// ---------- residual + LayerNorm -> xhat (scale/bias folded into Wq') ----------
__global__ __launch_bounds__(256)
void ln_kernel(const float* __restrict__ xin, const float* __restrict__ res,
               float* __restrict__ xhat)
{
  const int w = threadIdx.x >> 6, l = threadIdx.x & 63;
  const size_t r = (size_t)blockIdx.x * 4 + w;
  const float4 a = *(const float4*)(xin + r * H_ + l * 4);
  const float4 b = *(const float4*)(res + r * H_ + l * 4);
  const float x0 = a.x + b.x, x1 = a.y + b.y, x2 = a.z + b.z, x3 = a.w + b.w;
  const float mu = wsum(x0 + x1 + x2 + x3) * (1.f / H_);
  const float d0 = x0 - mu, d1 = x1 - mu, d2 = x2 - mu, d3 = x3 - mu;
  const float var = wsum(d0 * d0 + d1 * d1 + d2 * d2 + d3 * d3) * (1.f / H_);
  const float isd = 1.f / sqrtf(var + 1e-5f);
  float4 o;
  o.x = d0 * isd; o.y = d1 * isd; o.z = d2 * isd; o.w = d3 * isd;
  *(float4*)(xhat + r * H_ + l * 4) = o;
}

// ---------- h = l2n(hraw); need = softmax(h@Wqt^T + bqt) ----------
__global__ __launch_bounds__(256)
void h_post(const float* __restrict__ hraw, const float* __restrict__ Wqt,
            const float* __restrict__ bqt, float* __restrict__ h, float* __restrict__ need)
{
  __shared__ float wq_s[T_ * H_];
  for (int i = threadIdx.x; i < T_ * H_; i += 256) wq_s[i] = Wqt[i];
  const int w = threadIdx.x >> 6, l = threadIdx.x & 63;
  const size_t r = (size_t)blockIdx.x * 4 + w;
  const float4 v = *(const float4*)(hraw + r * H_ + l * 4);
  const float n = fmaxf(sqrtf(wsum(v.x * v.x + v.y * v.y + v.z * v.z + v.w * v.w)), 1e-12f);
  float4 hn; hn.x = v.x / n; hn.y = v.y / n; hn.z = v.z / n; hn.w = v.w / n;
  *(float4*)(h + r * H_ + l * 4) = hn;
  __syncthreads();
  float mine = 0.f;
  for (int tt = 0; tt < T_; tt++) {
    const float4 p4 = *(const float4*)(wq_s + tt * H_ + l * 4);
    float p = hn.x * p4.x + hn.y * p4.y + hn.z * p4.z + hn.w * p4.w;
    p = wsum(p);
    if (l == tt) mine = p + bqt[l];
  }
  float s = (l < T_) ? mine : -1e30f;
  const float m = wmaxr(s);
  const float e = (l < T_) ? expf(s - m) : 0.f;
  const float su = wsum(e);
  if (l < T_) need[r * T_ + l] = e / su;
}

// ---------- selection step ----------
template<int STEP>
__global__ __launch_bounds__(256)
void score_kernel(const float* __restrict__ h, const float* __restrict__ se,
                  const float* __restrict__ cn, const float* __restrict__ tp,
                  const float* __restrict__ need, const float* __restrict__ clam,
                  float* __restrict__ covered, int* __restrict__ sel,
                  float* __restrict__ chosen, float* __restrict__ logits,
                  float* __restrict__ preds)
{
  __shared__ __align__(16) float hs_s[H_];
  __shared__ float nu_s[T_];
  __shared__ float sc_s[K_];
  __shared__ float rd_s[4];
  __shared__ int idx_s;
  const int b = blockIdx.x, t = threadIdx.x;
  const int w = t >> 6, l = t & 63;

  const float hv = h[(size_t)b * H_ + t] + se[STEP * H_ + t];
  const float ss = wsum(hv * hv);
  if (l == 0) rd_s[w] = ss;
  if (STEP == 1 && t < T_)
    nu_s[t] = need[(size_t)b * T_ + t] * fminf(fmaxf(1.f - covered[(size_t)b * T_ + t], 0.f), 1.f);
  __syncthreads();
  const float n = fmaxf(sqrtf(rd_s[0] + rd_s[1] + rd_s[2] + rd_s[3]), 1e-12f);
  hs_s[t] = hv / n;
  __syncthreads();

  const float lam = log1pf(expf(clam[0]));  // softplus
  const float4 hf = *(const float4*)(hs_s + l * 4);
#pragma unroll
  for (int cc = 0; cc < 8; cc++) {
    const int c = w * 8 + cc;
    const float4 cv = *(const float4*)(cn + ((size_t)b * K_ + c) * H_ + l * 4);
    float p = cv.x * hf.x + cv.y * hf.y + cv.z * hf.z + cv.w * hf.w;
    p = wsum(p);
    float s = p / 0.1f;  // / TEMP
    if (STEP == 1) {
      float g = (l < T_) ? nu_s[l] * tp[((size_t)b * K_ + c) * T_ + l] : 0.f;
      g = wsum(g);
      s += lam * g;
      if (sel[(size_t)b * K_ + c]) s = -100.f;
    }
    if (l == 0) sc_s[c] = s;
  }
  __syncthreads();
  if (w == 0) {  // argmax, first-index tie-break
    float s = (l < K_) ? sc_s[l] : -1e30f;
    int bi = (l < K_) ? l : K_;
#pragma unroll
    for (int o = 32; o; o >>= 1) {
      const float s2 = __shfl_xor(s, o);
      const int i2 = __shfl_xor(bi, o);
      if (s2 > s || (s2 == s && i2 < bi)) { s = s2; bi = i2; }
    }
    if (l == 0) idx_s = bi;
  }
  __syncthreads();
  const int idx = idx_s;
  if (t < K_) logits[(size_t)b * (S_ * K_) + STEP * K_ + t] = sc_s[t];
  if (t == 0) preds[(size_t)b * S_ + STEP] = (float)idx;
  if (STEP == 0) {
    if (t < K_) sel[(size_t)b * K_ + t] = (t == idx) ? 1 : 0;
    if (t < T_) covered[(size_t)b * T_ + t] = fminf(tp[((size_t)b * K_ + idx) * T_ + t], 1.f);
    chosen[(size_t)b * H_ + t] = cn[((size_t)b * K_ + idx) * H_ + t];
  }
}

// ---------- GRU gate fusion + l2n, h updated in place ----------
__global__ __launch_bounds__(256)
void gru_kernel(const float* __restrict__ gi, const float* __restrict__ gh, float* __restrict__ h)
{
  __shared__ float rd_s[4];
  const int b = blockIdx.x, t = threadIdx.x, w = t >> 6, l = t & 63;
  const size_t o = (size_t)b * (3 * H_);
  const float ir = gi[o + t], iz = gi[o + 256 + t], ig = gi[o + 512 + t];
  const float hr = gh[o + t], hz = gh[o + 256 + t], hg = gh[o + 512 + t];
  const float hv = h[(size_t)b * H_ + t];
  const float r = 1.f / (1.f + expf(-(ir + hr)));
  const float z = 1.f / (1.f + expf(-(iz + hz)));
  const float nn = tanhf(ig + r * hg);
  const float x = (1.f - z) * nn + z * hv;
  const float ss = wsum(x * x);
  if (l == 0) rd_s[w] = ss;
  __syncthreads();
  const float n = fmaxf(sqrtf(rd_s[0] + rd_s[1] + rd_s[2] + rd_s[3]), 1e-12f);
  h[(size_t)b * H_ + t] = x / n;
}

extern "C" void kernel_launch(void* const* d_in, const int* in_sizes, int n_in,
                              void* d_out, int out_size, void* d_ws, size_t ws_size,
                              hipStream_t stream)
{
  const float* query_emb = (const float*)d_in[0];
  const float* cand_emb  = (const float*)d_in[1];
  const float* W_in = (const float*)d_in[2];
  const float* Wq_a = (const float*)d_in[3];
  const float* Wk_a = (const float*)d_in[4];
  const float* Wv_a = (const float*)d_in[5];
  const float* bq_a = (const float*)d_in[6];
  const float* bk_a = (const float*)d_in[7];
  const float* bv_a = (const float*)d_in[8];
  const float* Wo_a = (const float*)d_in[9];
  const float* bo_a = (const float*)d_in[10];
  const float* ln_w = (const float*)d_in[11];
  const float* ln_b = (const float*)d_in[12];
  const float* Wq   = (const float*)d_in[13];
  const float* Wc   = (const float*)d_in[14];
  const float* W_ih = (const float*)d_in[15];
  const float* W_hh = (const float*)d_in[16];
  const float* b_ih = (const float*)d_in[17];
  const float* b_hh = (const float*)d_in[18];
  const float* step_emb = (const float*)d_in[19];
  const float* tpro = (const float*)d_in[20];
  const float* Wqt  = (const float*)d_in[21];
  const float* bqt  = (const float*)d_in[22];
  const float* clam = (const float*)d_in[23];

  float* ws = (float*)d_ws;
  size_t o = 0;
  float* WkinT = ws + o; o += (size_t)D_ * H_;
  float* Wv_in = ws + o; o += (size_t)H_ * D_;
  ushort* BhW  = (ushort*)(ws + o); o += (size_t)H_ * D_ / 2;
  ushort* BlW  = (ushort*)(ws + o); o += (size_t)H_ * D_ / 2;
  float* pro   = ws + o; o += (size_t)T_ * H_;
  float* Bqk   = ws + o; o += (size_t)D_ * H_;
  float* bqk   = ws + o; o += 1024;
  float* Wvo   = ws + o; o += (size_t)H_ * D_;
  float* bvo   = ws + o; o += 256;
  float* Wqp   = ws + o; o += (size_t)H_ * H_;
  float* bqp   = ws + o; o += 256;
  float* vqbk  = ws + o; o += 256;
  float* qcst  = ws + o; o += 4;
  float* qr    = ws + o; o += (size_t)B_ * H_;
  float* qkv   = ws + o; o += (size_t)B_ * D_;   // later: gi
  float* wce   = ws + o; o += (size_t)B_ * D_;   // later: gh
  float* ctxb  = ws + o; o += (size_t)B_ * H_;   // ctx, later hraw
  float* xhat  = ws + o; o += (size_t)B_ * H_;
  float* h     = ws + o; o += (size_t)B_ * H_;
  float* need  = ws + o; o += (size_t)B_ * T_;
  float* cn    = ws + o; o += (size_t)B_ * K_ * H_;
  float* tp    = ws + o; o += (size_t)B_ * K_ * T_;
  int*   sel   = (int*)(ws + o); o += (size_t)B_ * K_;
  float* cov   = ws + o; o += (size_t)B_ * T_;
  float* chosen= ws + o; o += (size_t)B_ * H_;

  float* out_logits = (float*)d_out;
  float* out_preds  = (float*)d_out + (size_t)B_ * S_ * K_;

  // weight folding
  fold_kernel<<<dim3(H_, 3), 256, 0, stream>>>(Wk_a, Wv_a, Wc, W_in, WkinT, Wv_in, BhW, BlW);
  proto_kernel<<<1, 256, 0, stream>>>(tpro, pro);
  fold2_kernel<<<D_, 256, 0, stream>>>(Wq_a, bq_a, bk_a, Wo_a, bo_a, bv_a, Wq, ln_w, ln_b,
                                       WkinT, Wv_in, Bqk, bqk, Wvo, bvo, Wqp, bqp, vqbk, qcst);

  // query path
  gemm_nt<false><<<dim3(H_ / 128, B_ / 128), 256, 0, stream>>>(query_emb, W_in, nullptr, qr, B_, H_, D_);
  gemm_nt<true ><<<dim3(D_ / 128, B_ / 128), 256, 0, stream>>>(qr, Bqk, bqk, qkv, B_, D_, H_);
  attn_kernel<<<B_, 256, 0, stream>>>(cand_emb, qkv, qr, vqbk, qcst, wce);
  gemm_nt<true ><<<dim3(H_ / 128, B_ / 128), 256, 0, stream>>>(wce, Wvo, bvo, ctxb, B_, H_, D_);
  ln_kernel<<<B_ / 4, 256, 0, stream>>>(ctxb, qr, xhat);
  gemm_nt<true ><<<dim3(H_ / 128, B_ / 128), 256, 0, stream>>>(xhat, Wqp, bqp, ctxb, B_, H_, H_);  // ctxb := hraw
  h_post<<<B_ / 4, 256, 0, stream>>>(ctxb, Wqt, bqt, h, need);

  // candidate path: split-bf16 MFMA GEMM with fused l2n + topic softmax
  gemm_cn<<<(B_ * K_) / 128, 512, 0, stream>>>(cand_emb, BhW, BlW, pro, cn, tp);

  // step 0
  score_kernel<0><<<B_, 256, 0, stream>>>(h, step_emb, cn, tp, need, clam, cov, sel, chosen, out_logits, out_preds);
  // GRU update
  gemm_nt<true ><<<dim3((3 * H_) / 128, B_ / 128), 256, 0, stream>>>(chosen, W_ih, b_ih, qkv, B_, 3 * H_, H_);  // qkv := gi
  gemm_nt<true ><<<dim3((3 * H_) / 128, B_ / 128), 256, 0, stream>>>(h, W_hh, b_hh, wce, B_, 3 * H_, H_);       // wce := gh
  gru_kernel<<<B_, 256, 0, stream>>>(qkv, wce, h);
  // step 1
  score_kernel<1><<<B_, 256, 0, stream>>>(h, step_emb, cn, tp, need, clam, cov, sel, chosen, out_logits, out_preds);
}

// Round 4
// 1268.211 us; speedup vs baseline: 2.0224x; 1.1646x over previous
//
#include <hip/hip_runtime.h>
#include <math.h>

#define B_ 8192
#define K_ 32
#define D_ 768
#define H_ 256
#define T_ 16
#define S_ 2

typedef unsigned int uint;
typedef unsigned short ushort;
typedef __attribute__((ext_vector_type(8))) short bf16x8;
typedef __attribute__((ext_vector_type(4))) float f32x4;

// ---------- wave (64-lane) reductions ----------
__device__ __forceinline__ float wsum(float v) {
  v += __shfl_xor(v, 32); v += __shfl_xor(v, 16); v += __shfl_xor(v, 8);
  v += __shfl_xor(v, 4);  v += __shfl_xor(v, 2);  v += __shfl_xor(v, 1);
  return v;
}
__device__ __forceinline__ float wmaxr(float v) {
  v = fmaxf(v, __shfl_xor(v, 32)); v = fmaxf(v, __shfl_xor(v, 16));
  v = fmaxf(v, __shfl_xor(v, 8));  v = fmaxf(v, __shfl_xor(v, 4));
  v = fmaxf(v, __shfl_xor(v, 2));  v = fmaxf(v, __shfl_xor(v, 1));
  return v;
}

// async global->LDS, 16B per lane; gptr is per-lane, lds dest = uniform base + lane*16
__device__ __forceinline__ void glds16(const ushort* g, ushort* l) {
  __builtin_amdgcn_global_load_lds(
      (const __attribute__((address_space(1))) void*)g,
      (__attribute__((address_space(3))) void*)l, 16, 0, 0);
}

// split fp32 -> (hi bf16 trunc, lo bf16 trunc of exact remainder), packed 2/uint
__device__ __forceinline__ void split4(const float4 f, uint2& h, uint2& lo) {
  const uint ux = __float_as_uint(f.x), uy = __float_as_uint(f.y);
  const uint uz = __float_as_uint(f.z), uw = __float_as_uint(f.w);
  h.x = (uy & 0xFFFF0000u) | (ux >> 16);
  h.y = (uw & 0xFFFF0000u) | (uz >> 16);
  const float rx = f.x - __uint_as_float(ux & 0xFFFF0000u);
  const float ry = f.y - __uint_as_float(uy & 0xFFFF0000u);
  const float rz = f.z - __uint_as_float(uz & 0xFFFF0000u);
  const float rw = f.w - __uint_as_float(uw & 0xFFFF0000u);
  lo.x = (__float_as_uint(ry) & 0xFFFF0000u) | (__float_as_uint(rx) >> 16);
  lo.y = (__float_as_uint(rw) & 0xFFFF0000u) | (__float_as_uint(rz) >> 16);
}

// B frag tiling: NB=17 tiles of 16 cols (0..15 = Wc_in cols, 16 = folded protos)
// elem(ks, nb, col_in_tile i, k) = ((ks*17 + nb)*64 + (i | (kc<<4)))*8 + kb ; kc=(k>>3)&3, kb=k&7

// ---------- fold stage 1: WkinT fp32, Wv_in fp32, Wc_in fp32 + hi/lo bf16 frag-tiled ----------
__global__ __launch_bounds__(256)
void fold_kernel(const float* __restrict__ Wk_a, const float* __restrict__ Wv_a,
                 const float* __restrict__ Wc,  const float* __restrict__ W_in,
                 float* __restrict__ WkinT, float* __restrict__ Wv_in,
                 float* __restrict__ Wc_f,
                 ushort* __restrict__ Bh, ushort* __restrict__ Bl)
{
  const int i = blockIdx.x;   // output row 0..255
  const int m = blockIdx.y;   // which matrix
  const float* Wx = (m == 0) ? Wk_a : ((m == 1) ? Wv_a : Wc);
  const int t = threadIdx.x;
  float a0 = 0.f, a1 = 0.f, a2 = 0.f;
  for (int k = 0; k < H_; k++) {
    const float wv = Wx[i * H_ + k];
    const float* row = W_in + (size_t)k * D_;
    a0 = fmaf(wv, row[t], a0);
    a1 = fmaf(wv, row[t + 256], a1);
    a2 = fmaf(wv, row[t + 512], a2);
  }
  if (m == 0) {
    WkinT[(size_t)t * H_ + i] = a0;
    WkinT[(size_t)(t + 256) * H_ + i] = a1;
    WkinT[(size_t)(t + 512) * H_ + i] = a2;
  } else if (m == 1) {
    float* o = Wv_in + (size_t)i * D_;
    o[t] = a0; o[t + 256] = a1; o[t + 512] = a2;
  } else {
    float* o = Wc_f + (size_t)i * D_;
    o[t] = a0; o[t + 256] = a1; o[t + 512] = a2;
    const float vals[3] = {a0, a1, a2};
#pragma unroll
    for (int j = 0; j < 3; j++) {
      const int k = t + j * 256;
      const float v = vals[j];
      const int idx = (((k >> 5) * 17 + (i >> 4)) * 64 + ((i & 15) | (((k >> 3) & 3) << 4))) * 8 + (k & 7);
      const uint u = __float_as_uint(v);
      Bh[idx] = (ushort)(u >> 16);
      const float rr = v - __uint_as_float(u & 0xFFFF0000u);
      Bl[idx] = (ushort)(__float_as_uint(rr) >> 16);
    }
  }
}

// ---------- l2-normalize topic prototypes ----------
__global__ __launch_bounds__(256)
void proto_kernel(const float* __restrict__ tpro, float* __restrict__ pro)
{
  const int w = threadIdx.x >> 6, l = threadIdx.x & 63;
  for (int r = w; r < T_; r += 4) {
    const float4 v = *(const float4*)(tpro + (size_t)r * H_ + l * 4);
    const float n = fmaxf(sqrtf(wsum(v.x * v.x + v.y * v.y + v.z * v.z + v.w * v.w)), 1e-12f);
    float4 o; o.x = v.x / n; o.y = v.y / n; o.z = v.z / n; o.w = v.w / n;
    *(float4*)(pro + (size_t)r * H_ + l * 4) = o;
  }
}

// ---------- fold stage 3: Pfold[t][d] = sum_h pro_n[t][h]*Wc_in[h][d] -> frag tile nb=16 ----------
__global__ __launch_bounds__(256)
void fold3_kernel(const float* __restrict__ pro, const float* __restrict__ Wc_f,
                  ushort* __restrict__ Bh, ushort* __restrict__ Bl)
{
  const int tt = blockIdx.x;  // topic 0..15
  const int t = threadIdx.x;
  float a0 = 0.f, a1 = 0.f, a2 = 0.f;
  for (int h = 0; h < H_; h++) {
    const float pv = pro[tt * H_ + h];
    const float* row = Wc_f + (size_t)h * D_;
    a0 = fmaf(pv, row[t], a0);
    a1 = fmaf(pv, row[t + 256], a1);
    a2 = fmaf(pv, row[t + 512], a2);
  }
  const float vals[3] = {a0, a1, a2};
#pragma unroll
  for (int j = 0; j < 3; j++) {
    const int k = t + j * 256;
    const float v = vals[j];
    const int idx = (((k >> 5) * 17 + 16) * 64 + (tt | (((k >> 3) & 3) << 4))) * 8 + (k & 7);
    const uint u = __float_as_uint(v);
    Bh[idx] = (ushort)(u >> 16);
    const float rr = v - __uint_as_float(u & 0xFFFF0000u);
    Bl[idx] = (ushort)(__float_as_uint(rr) >> 16);
  }
}

// ---------- fold stage 2: attention/query-path weight folds ----------
__global__ __launch_bounds__(256)
void fold2_kernel(const float* __restrict__ Wq_a, const float* __restrict__ bq_a,
                  const float* __restrict__ bk_a, const float* __restrict__ Wo_a,
                  const float* __restrict__ bo_a, const float* __restrict__ bv_a,
                  const float* __restrict__ Wq,   const float* __restrict__ ln_w,
                  const float* __restrict__ ln_b, const float* __restrict__ WkinT,
                  const float* __restrict__ Wv_in,
                  float* __restrict__ Bqk, float* __restrict__ bqk,
                  float* __restrict__ Wvo, float* __restrict__ bvo,
                  float* __restrict__ Wqp, float* __restrict__ bqp,
                  float* __restrict__ vqbk, float* __restrict__ qcst)
{
  __shared__ float rd_s[4];
  const int n = blockIdx.x, t = threadIdx.x, w = t >> 6, l = t & 63;
  float s = 0.f;
  for (int hh = 0; hh < H_; hh++)
    s = fmaf(Wq_a[hh * H_ + t], WkinT[(size_t)n * H_ + hh], s);
  Bqk[(size_t)n * H_ + t] = s;
  float p = bq_a[t] * WkinT[(size_t)n * H_ + t];
  p = wsum(p);
  if (l == 0) rd_s[w] = p;
  __syncthreads();
  if (t == 0) bqk[n] = rd_s[0] + rd_s[1] + rd_s[2] + rd_s[3];
  if (n < H_) {
    float a0 = 0.f, a1 = 0.f, a2 = 0.f;
    for (int hh = 0; hh < H_; hh++) {
      const float wo = Wo_a[n * H_ + hh];
      const float* rowv = Wv_in + (size_t)hh * D_;
      a0 = fmaf(wo, rowv[t], a0);
      a1 = fmaf(wo, rowv[t + 256], a1);
      a2 = fmaf(wo, rowv[t + 512], a2);
    }
    Wvo[(size_t)n * D_ + t] = a0;
    Wvo[(size_t)n * D_ + t + 256] = a1;
    Wvo[(size_t)n * D_ + t + 512] = a2;
    float pb = Wo_a[n * H_ + t] * bv_a[t];
    pb = wsum(pb);
    __syncthreads();
    if (l == 0) rd_s[w] = pb;
    __syncthreads();
    if (t == 0) bvo[n] = rd_s[0] + rd_s[1] + rd_s[2] + rd_s[3] + bo_a[n];
    Wqp[n * H_ + t] = Wq[n * H_ + t] * ln_w[t];
    float pq = Wq[n * H_ + t] * ln_b[t];
    pq = wsum(pq);
    __syncthreads();
    if (l == 0) rd_s[w] = pq;
    __syncthreads();
    if (t == 0) bqp[n] = rd_s[0] + rd_s[1] + rd_s[2] + rd_s[3];
  }
  if (n == 0) {
    float sv = 0.f;
    for (int hh = 0; hh < H_; hh++) sv = fmaf(bk_a[hh], Wq_a[hh * H_ + t], sv);
    vqbk[t] = sv;
    float pc = bq_a[t] * bk_a[t];
    pc = wsum(pc);
    __syncthreads();
    if (l == 0) rd_s[w] = pc;
    __syncthreads();
    if (t == 0) qcst[0] = rd_s[0] + rd_s[1] + rd_s[2] + rd_s[3];
  }
}

// ---------- split-bf16 MFMA GEMM + fused l2n + MFMA topic softmax ----------
// grid (B*K/128), 512 threads (8 waves 2x4), BK=32. B frag-tiled [24ks][17nb][64][8].
__global__ __launch_bounds__(512, 4)
void gemm_cn(const float* __restrict__ A, const ushort* __restrict__ Bh,
             const ushort* __restrict__ Bl, float* __restrict__ C,
             float* __restrict__ tp)
{
  __shared__ __align__(16) ushort AhS[4096], AlS[4096], BhS[8704], BlS[8704];
  const int t = threadIdx.x;
  const int l = t & 63, w = t >> 6;
  const int wr = w >> 2, wc = w & 3;
  const int wu = __builtin_amdgcn_readfirstlane(w);
  const bool protoW = (w == 3) || (w == 4);  // SIMD3 / SIMD0, rows wr*64..+64

  const int r = t >> 2;
  const int kc = t & 3;
  const float* Ag = A + ((size_t)blockIdx.x * 128 + r) * 768 + kc * 8;
  const int aslot = ((r >> 4) * 64 + ((r & 15) | (kc << 4))) * 8;

  f32x4 acc[4][4];
  f32x4 accp[4];
#pragma unroll
  for (int i = 0; i < 4; i++) {
    accp[i] = (f32x4)0.f;
#pragma unroll
    for (int j = 0; j < 4; j++) acc[i][j] = (f32x4)0.f;
  }

  float4 f0 = *(const float4*)(Ag + 0);
  float4 f1 = *(const float4*)(Ag + 4);

  for (int ks = 0; ks < 24; ks++) {
    __syncthreads();  // previous tile fully consumed
    // B staging via async global->LDS (17 hi + 17 lo 1KB chunks, spread over waves)
    for (int idx = wu; idx < 34; idx += 8) {
      const bool hi_ = idx < 17;
      const int c = hi_ ? idx : idx - 17;
      const ushort* g = (hi_ ? Bh : Bl) + (size_t)ks * 8704 + c * 512 + l * 8;
      ushort* dst = (hi_ ? BhS : BlS) + c * 512;
      glds16(g, dst);
    }
    // A staging: fp32 -> hi/lo split into fragment slots
    {
      uint2 ha, la, hb, lb;
      split4(f0, ha, la); split4(f1, hb, lb);
      *(uint4*)&AhS[aslot] = make_uint4(ha.x, ha.y, hb.x, hb.y);
      *(uint4*)&AlS[aslot] = make_uint4(la.x, la.y, lb.x, lb.y);
    }
    __syncthreads();  // vmcnt+lgkm drained here by compiler
    if (ks < 23) {
      const int o4 = (ks + 1) * 32;
      f0 = *(const float4*)(Ag + o4);
      f1 = *(const float4*)(Ag + o4 + 4);
    }
    bf16x8 ah[4], al[4];
#pragma unroll
    for (int mi = 0; mi < 4; mi++) {
      ah[mi] = *(const bf16x8*)&AhS[((wr * 4 + mi) * 64 + l) * 8];
      al[mi] = *(const bf16x8*)&AlS[((wr * 4 + mi) * 64 + l) * 8];
    }
#pragma unroll
    for (int ni = 0; ni < 4; ni++) {
      const bf16x8 bhf = *(const bf16x8*)&BhS[((wc * 4 + ni) * 64 + l) * 8];
      const bf16x8 blf = *(const bf16x8*)&BlS[((wc * 4 + ni) * 64 + l) * 8];
#pragma unroll
      for (int mi = 0; mi < 4; mi++) {
        acc[mi][ni] = __builtin_amdgcn_mfma_f32_16x16x32_bf16(ah[mi], bhf, acc[mi][ni], 0, 0, 0);
        acc[mi][ni] = __builtin_amdgcn_mfma_f32_16x16x32_bf16(al[mi], bhf, acc[mi][ni], 0, 0, 0);
        acc[mi][ni] = __builtin_amdgcn_mfma_f32_16x16x32_bf16(ah[mi], blf, acc[mi][ni], 0, 0, 0);
      }
    }
    if (protoW) {  // folded-proto tile (nb=16)
      const bf16x8 bph = *(const bf16x8*)&BhS[(16 * 64 + l) * 8];
      const bf16x8 bpl = *(const bf16x8*)&BlS[(16 * 64 + l) * 8];
#pragma unroll
      for (int mi = 0; mi < 4; mi++) {
        accp[mi] = __builtin_amdgcn_mfma_f32_16x16x32_bf16(ah[mi], bph, accp[mi], 0, 0, 0);
        accp[mi] = __builtin_amdgcn_mfma_f32_16x16x32_bf16(al[mi], bph, accp[mi], 0, 0, 0);
        accp[mi] = __builtin_amdgcn_mfma_f32_16x16x32_bf16(ah[mi], bpl, accp[mi], 0, 0, 0);
      }
    }
  }

  // ---- epilogue ----
  __syncthreads();  // staging LDS dead; alias for rsq
  float* rsq = (float*)AhS;  // [128][4]
#pragma unroll
  for (int mi = 0; mi < 4; mi++)
#pragma unroll
    for (int rg = 0; rg < 4; rg++) {
      float p = 0.f;
#pragma unroll
      for (int ni = 0; ni < 4; ni++) { const float v = acc[mi][ni][rg]; p = fmaf(v, v, p); }
      p += __shfl_xor(p, 1); p += __shfl_xor(p, 2); p += __shfl_xor(p, 4); p += __shfl_xor(p, 8);
      if ((l & 15) == 0) rsq[(wr * 64 + mi * 16 + (l >> 4) * 4 + rg) * 4 + wc] = p;
    }
  __syncthreads();
  const size_t row0 = (size_t)blockIdx.x * 128;
#pragma unroll
  for (int mi = 0; mi < 4; mi++)
#pragma unroll
    for (int rg = 0; rg < 4; rg++) {
      const int rl = wr * 64 + mi * 16 + (l >> 4) * 4 + rg;
      const float ssum = rsq[rl * 4 + 0] + rsq[rl * 4 + 1] + rsq[rl * 4 + 2] + rsq[rl * 4 + 3];
      const float inv = 1.f / fmaxf(sqrtf(ssum), 1e-12f);
#pragma unroll
      for (int ni = 0; ni < 4; ni++)
        C[(row0 + rl) * H_ + wc * 64 + ni * 16 + (l & 15)] = acc[mi][ni][rg] * inv;
    }
  if (protoW) {  // lane-local topic softmax: topic = l&15, reduce across 16-lane group
#pragma unroll
    for (int mi = 0; mi < 4; mi++)
#pragma unroll
      for (int rg = 0; rg < 4; rg++) {
        const int rl = wr * 64 + mi * 16 + (l >> 4) * 4 + rg;
        const float ssum = rsq[rl * 4 + 0] + rsq[rl * 4 + 1] + rsq[rl * 4 + 2] + rsq[rl * 4 + 3];
        const float inv = 1.f / fmaxf(sqrtf(ssum), 1e-12f);
        const float v = accp[mi][rg] * inv;
        float m = v;
        m = fmaxf(m, __shfl_xor(m, 1)); m = fmaxf(m, __shfl_xor(m, 2));
        m = fmaxf(m, __shfl_xor(m, 4)); m = fmaxf(m, __shfl_xor(m, 8));
        const float e = expf(v - m);
        float su = e;
        su += __shfl_xor(su, 1); su += __shfl_xor(su, 2); su += __shfl_xor(su, 4); su += __shfl_xor(su, 8);
        tp[(row0 + rl) * T_ + (l & 15)] = e / su;
      }
  }
}

// ---------- fp32 NT GEMM: C[M,N] = A[M,K]*B[N,K]^T (+bias). 64x64x8, 256 thr, 4x4/thr ----------
template<bool BIAS>
__global__ __launch_bounds__(256)
void gemm_nt(const float* __restrict__ A, const float* __restrict__ Bm,
             const float* __restrict__ bias, float* __restrict__ C,
             int M, int N, int Kd)
{
  __shared__ float As[8][72];
  __shared__ float Bs[8][72];
  const int t = threadIdx.x;
  const int tx = t & 15, ty = t >> 4;
  const int t2 = t & 127;
  const int lr = t2 >> 1, lc = (t2 & 1) * 4;
  const float* Sb = (t < 128)
      ? (A  + ((size_t)blockIdx.y * 64 + lr) * Kd + lc)
      : (Bm + ((size_t)blockIdx.x * 64 + lr) * Kd + lc);
  float (*Ss)[72] = (t < 128) ? As : Bs;
  float acc[4][4];
#pragma unroll
  for (int i = 0; i < 4; i++)
#pragma unroll
    for (int j = 0; j < 4; j++) acc[i][j] = 0.f;

  for (int k0 = 0; k0 < Kd; k0 += 8) {
    const float4 v = *(const float4*)(Sb + k0);
    __syncthreads();
    Ss[lc + 0][lr] = v.x; Ss[lc + 1][lr] = v.y; Ss[lc + 2][lr] = v.z; Ss[lc + 3][lr] = v.w;
    __syncthreads();
#pragma unroll
    for (int kk = 0; kk < 8; kk++) {
      const float4 a4 = *(const float4*)&As[kk][ty * 4];
      const float4 b4 = *(const float4*)&Bs[kk][tx * 4];
      acc[0][0] = fmaf(a4.x, b4.x, acc[0][0]); acc[0][1] = fmaf(a4.x, b4.y, acc[0][1]);
      acc[0][2] = fmaf(a4.x, b4.z, acc[0][2]); acc[0][3] = fmaf(a4.x, b4.w, acc[0][3]);
      acc[1][0] = fmaf(a4.y, b4.x, acc[1][0]); acc[1][1] = fmaf(a4.y, b4.y, acc[1][1]);
      acc[1][2] = fmaf(a4.y, b4.z, acc[1][2]); acc[1][3] = fmaf(a4.y, b4.w, acc[1][3]);
      acc[2][0] = fmaf(a4.z, b4.x, acc[2][0]); acc[2][1] = fmaf(a4.z, b4.y, acc[2][1]);
      acc[2][2] = fmaf(a4.z, b4.z, acc[2][2]); acc[2][3] = fmaf(a4.z, b4.w, acc[2][3]);
      acc[3][0] = fmaf(a4.w, b4.x, acc[3][0]); acc[3][1] = fmaf(a4.w, b4.y, acc[3][1]);
      acc[3][2] = fmaf(a4.w, b4.z, acc[3][2]); acc[3][3] = fmaf(a4.w, b4.w, acc[3][3]);
    }
  }
  const int col = blockIdx.x * 64 + tx * 4;
  float bb[4];
#pragma unroll
  for (int j = 0; j < 4; j++) bb[j] = BIAS ? bias[col + j] : 0.f;
#pragma unroll
  for (int i = 0; i < 4; i++) {
    const size_t row = (size_t)blockIdx.y * 64 + ty * 4 + i;
    float4 v;
    v.x = acc[i][0] + bb[0]; v.y = acc[i][1] + bb[1];
    v.z = acc[i][2] + bb[2]; v.w = acc[i][3] + bb[3];
    *(float4*)(C + row * N + col) = v;
  }
}

// ---------- fused cross-attention (scores + softmax + PV; PV re-read L2-served) ----------
__global__ __launch_bounds__(256)
void attn_kernel(const float* __restrict__ ce, const float* __restrict__ qkv,
                 const float* __restrict__ qr, const float* __restrict__ vqbk,
                 const float* __restrict__ qcst, float* __restrict__ wce)
{
  __shared__ float4 qk_s[192];
  __shared__ float sc_s[K_];
  __shared__ float at_s[K_];
  __shared__ float rd_s[4];
  const int b = blockIdx.x, t = threadIdx.x;
  const int w = t >> 6, l = t & 63;

  float p = qr[(size_t)b * H_ + t] * vqbk[t];
  p = wsum(p);
  if (l == 0) rd_s[w] = p;
  if (t < 192) qk_s[t] = ((const float4*)qkv)[(size_t)b * 192 + t];
  __syncthreads();
  const float qbk = rd_s[0] + rd_s[1] + rd_s[2] + rd_s[3] + qcst[0];

  const float4* ceb = (const float4*)(ce + (size_t)b * K_ * D_);
#pragma unroll
  for (int cc = 0; cc < 8; cc++) {
    const int c = w * 8 + cc;
    const float4* cr = ceb + c * 192;
    float s = 0.f;
#pragma unroll
    for (int j = 0; j < 3; j++) {
      const float4 f = cr[l + j * 64];
      const float4 q4 = qk_s[l + j * 64];
      s = fmaf(f.x, q4.x, s); s = fmaf(f.y, q4.y, s);
      s = fmaf(f.z, q4.z, s); s = fmaf(f.w, q4.w, s);
    }
    s = wsum(s);
    if (l == 0) sc_s[c] = s + qbk;
  }
  __syncthreads();
  if (w == 0) {
    float s = (l < K_) ? sc_s[l] * (1.f / 16.f) : -1e30f;
    const float m = wmaxr(s);
    float e = (l < K_) ? expf(s - m) : 0.f;
    const float su = wsum(e);
    if (l < K_) at_s[l] = e / su;
  }
  __syncthreads();
  if (t < 192) {
    float4 a = make_float4(0.f, 0.f, 0.f, 0.f);
#pragma unroll
    for (int c = 0; c < K_; c++) {
      const float4 f = ceb[c * 192 + t];
      const float av = at_s[c];
      a.x = fmaf(av, f.x, a.x); a.y = fmaf(av, f.y, a.y);
      a.z = fmaf(av, f.z, a.z); a.w = fmaf(av, f.w, a.w);
    }
    ((float4*)wce)[(size_t)b * 192 + t] = a;
  }
}

// ---------- residual + LayerNorm -> xhat (scale/bias folded into Wq') ----------
__global__ __launch_bounds__(256)
void ln_kernel(const float* __restrict__ xin, const float* __restrict__ res,
               float* __restrict__ xhat)
{
  const int w = threadIdx.x >> 6, l = threadIdx.x & 63;
  const size_t r = (size_t)blockIdx.x * 4 + w;
  const float4 a = *(const float4*)(xin + r * H_ + l * 4);
  const float4 b = *(const float4*)(res + r * H_ + l * 4);
  const float x0 = a.x + b.x, x1 = a.y + b.y, x2 = a.z + b.z, x3 = a.w + b.w;
  const float mu = wsum(x0 + x1 + x2 + x3) * (1.f / H_);
  const float d0 = x0 - mu, d1 = x1 - mu, d2 = x2 - mu, d3 = x3 - mu;
  const float var = wsum(d0 * d0 + d1 * d1 + d2 * d2 + d3 * d3) * (1.f / H_);
  const float isd = 1.f / sqrtf(var + 1e-5f);
  float4 o;
  o.x = d0 * isd; o.y = d1 * isd; o.z = d2 * isd; o.w = d3 * isd;
  *(float4*)(xhat + r * H_ + l * 4) = o;
}

// ---------- h = l2n(hraw); need = softmax(h@Wqt^T + bqt) ----------
__global__ __launch_bounds__(256)
void h_post(const float* __restrict__ hraw, const float* __restrict__ Wqt,
            const float* __restrict__ bqt, float* __restrict__ h, float* __restrict__ need)
{
  __shared__ float wq_s[T_ * H_];
  for (int i = threadIdx.x; i < T_ * H_; i += 256) wq_s[i] = Wqt[i];
  const int w = threadIdx.x >> 6, l = threadIdx.x & 63;
  const size_t r = (size_t)blockIdx.x * 4 + w;
  const float4 v = *(const float4*)(hraw + r * H_ + l * 4);
  const float n = fmaxf(sqrtf(wsum(v.x * v.x + v.y * v.y + v.z * v.z + v.w * v.w)), 1e-12f);
  float4 hn; hn.x = v.x / n; hn.y = v.y / n; hn.z = v.z / n; hn.w = v.w / n;
  *(float4*)(h + r * H_ + l * 4) = hn;
  __syncthreads();
  float mine = 0.f;
  for (int tt = 0; tt < T_; tt++) {
    const float4 p4 = *(const float4*)(wq_s + tt * H_ + l * 4);
    float p = hn.x * p4.x + hn.y * p4.y + hn.z * p4.z + hn.w * p4.w;
    p = wsum(p);
    if (l == tt) mine = p + bqt[l];
  }
  float s = (l < T_) ? mine : -1e30f;
  const float m = wmaxr(s);
  const float e = (l < T_) ? expf(s - m) : 0.f;
  const float su = wsum(e);
  if (l < T_) need[r * T_ + l] = e / su;
}

// ---------- selection step ----------
template<int STEP>
__global__ __launch_bounds__(256)
void score_kernel(const float* __restrict__ h, const float* __restrict__ se,
                  const float* __restrict__ cn, const float* __restrict__ tp,
                  const float* __restrict__ need, const float* __restrict__ clam,
                  float* __restrict__ covered, int* __restrict__ sel,
                  float* __restrict__ chosen, float* __restrict__ logits,
                  float* __restrict__ preds)
{
  __shared__ __align__(16) float hs_s[H_];
  __shared__ float nu_s[T_];
  __shared__ float sc_s[K_];
  __shared__ float rd_s[4];
  __shared__ int idx_s;
  const int b = blockIdx.x, t = threadIdx.x;
  const int w = t >> 6, l = t & 63;

  const float hv = h[(size_t)b * H_ + t] + se[STEP * H_ + t];
  const float ss = wsum(hv * hv);
  if (l == 0) rd_s[w] = ss;
  if (STEP == 1 && t < T_)
    nu_s[t] = need[(size_t)b * T_ + t] * fminf(fmaxf(1.f - covered[(size_t)b * T_ + t], 0.f), 1.f);
  __syncthreads();
  const float n = fmaxf(sqrtf(rd_s[0] + rd_s[1] + rd_s[2] + rd_s[3]), 1e-12f);
  hs_s[t] = hv / n;
  __syncthreads();

  const float lam = log1pf(expf(clam[0]));
  const float4 hf = *(const float4*)(hs_s + l * 4);
#pragma unroll
  for (int cc = 0; cc < 8; cc++) {
    const int c = w * 8 + cc;
    const float4 cv = *(const float4*)(cn + ((size_t)b * K_ + c) * H_ + l * 4);
    float p = cv.x * hf.x + cv.y * hf.y + cv.z * hf.z + cv.w * hf.w;
    p = wsum(p);
    float s = p / 0.1f;
    if (STEP == 1) {
      float g = (l < T_) ? nu_s[l] * tp[((size_t)b * K_ + c) * T_ + l] : 0.f;
      g = wsum(g);
      s += lam * g;
      if (sel[(size_t)b * K_ + c]) s = -100.f;
    }
    if (l == 0) sc_s[c] = s;
  }
  __syncthreads();
  if (w == 0) {
    float s = (l < K_) ? sc_s[l] : -1e30f;
    int bi = (l < K_) ? l : K_;
#pragma unroll
    for (int o = 32; o; o >>= 1) {
      const float s2 = __shfl_xor(s, o);
      const int i2 = __shfl_xor(bi, o);
      if (s2 > s || (s2 == s && i2 < bi)) { s = s2; bi = i2; }
    }
    if (l == 0) idx_s = bi;
  }
  __syncthreads();
  const int idx = idx_s;
  if (t < K_) logits[(size_t)b * (S_ * K_) + STEP * K_ + t] = sc_s[t];
  if (t == 0) preds[(size_t)b * S_ + STEP] = (float)idx;
  if (STEP == 0) {
    if (t < K_) sel[(size_t)b * K_ + t] = (t == idx) ? 1 : 0;
    if (t < T_) covered[(size_t)b * T_ + t] = fminf(tp[((size_t)b * K_ + idx) * T_ + t], 1.f);
    chosen[(size_t)b * H_ + t] = cn[((size_t)b * K_ + idx) * H_ + t];
  }
}

// ---------- GRU gate fusion + l2n, h updated in place ----------
__global__ __launch_bounds__(256)
void gru_kernel(const float* __restrict__ gi, const float* __restrict__ gh, float* __restrict__ h)
{
  __shared__ float rd_s[4];
  const int b = blockIdx.x, t = threadIdx.x, w = t >> 6, l = t & 63;
  const size_t o = (size_t)b * (3 * H_);
  const float ir = gi[o + t], iz = gi[o + 256 + t], ig = gi[o + 512 + t];
  const float hr = gh[o + t], hz = gh[o + 256 + t], hg = gh[o + 512 + t];
  const float hv = h[(size_t)b * H_ + t];
  const float r = 1.f / (1.f + expf(-(ir + hr)));
  const float z = 1.f / (1.f + expf(-(iz + hz)));
  const float nn = tanhf(ig + r * hg);
  const float x = (1.f - z) * nn + z * hv;
  const float ss = wsum(x * x);
  if (l == 0) rd_s[w] = ss;
  __syncthreads();
  const float n = fmaxf(sqrtf(rd_s[0] + rd_s[1] + rd_s[2] + rd_s[3]), 1e-12f);
  h[(size_t)b * H_ + t] = x / n;
}

extern "C" void kernel_launch(void* const* d_in, const int* in_sizes, int n_in,
                              void* d_out, int out_size, void* d_ws, size_t ws_size,
                              hipStream_t stream)
{
  const float* query_emb = (const float*)d_in[0];
  const float* cand_emb  = (const float*)d_in[1];
  const float* W_in = (const float*)d_in[2];
  const float* Wq_a = (const float*)d_in[3];
  const float* Wk_a = (const float*)d_in[4];
  const float* Wv_a = (const float*)d_in[5];
  const float* bq_a = (const float*)d_in[6];
  const float* bk_a = (const float*)d_in[7];
  const float* bv_a = (const float*)d_in[8];
  const float* Wo_a = (const float*)d_in[9];
  const float* bo_a = (const float*)d_in[10];
  const float* ln_w = (const float*)d_in[11];
  const float* ln_b = (const float*)d_in[12];
  const float* Wq   = (const float*)d_in[13];
  const float* Wc   = (const float*)d_in[14];
  const float* W_ih = (const float*)d_in[15];
  const float* W_hh = (const float*)d_in[16];
  const float* b_ih = (const float*)d_in[17];
  const float* b_hh = (const float*)d_in[18];
  const float* step_emb = (const float*)d_in[19];
  const float* tpro = (const float*)d_in[20];
  const float* Wqt  = (const float*)d_in[21];
  const float* bqt  = (const float*)d_in[22];
  const float* clam = (const float*)d_in[23];

  float* ws = (float*)d_ws;
  size_t o = 0;
  float* WkinT = ws + o; o += (size_t)D_ * H_;
  float* Wv_in = ws + o; o += (size_t)H_ * D_;
  float* Wc_f  = ws + o; o += (size_t)H_ * D_;
  ushort* BhW  = (ushort*)(ws + o); o += 104448;   // 24*17*64*8 ushorts
  ushort* BlW  = (ushort*)(ws + o); o += 104448;
  float* pro   = ws + o; o += (size_t)T_ * H_;
  float* Bqk   = ws + o; o += (size_t)D_ * H_;
  float* bqk   = ws + o; o += 1024;
  float* Wvo   = ws + o; o += (size_t)H_ * D_;
  float* bvo   = ws + o; o += 256;
  float* Wqp   = ws + o; o += (size_t)H_ * H_;
  float* bqp   = ws + o; o += 256;
  float* vqbk  = ws + o; o += 256;
  float* qcst  = ws + o; o += 4;
  float* qr    = ws + o; o += (size_t)B_ * H_;
  float* qkv   = ws + o; o += (size_t)B_ * D_;   // later: gi
  float* wce   = ws + o; o += (size_t)B_ * D_;   // later: gh
  float* ctxb  = ws + o; o += (size_t)B_ * H_;   // ctx, later hraw
  float* xhat  = ws + o; o += (size_t)B_ * H_;
  float* h     = ws + o; o += (size_t)B_ * H_;
  float* need  = ws + o; o += (size_t)B_ * T_;
  float* cn    = ws + o; o += (size_t)B_ * K_ * H_;
  float* tp    = ws + o; o += (size_t)B_ * K_ * T_;
  int*   sel   = (int*)(ws + o); o += (size_t)B_ * K_;
  float* cov   = ws + o; o += (size_t)B_ * T_;
  float* chosen= ws + o; o += (size_t)B_ * H_;

  float* out_logits = (float*)d_out;
  float* out_preds  = (float*)d_out + (size_t)B_ * S_ * K_;

  // weight folding
  fold_kernel<<<dim3(H_, 3), 256, 0, stream>>>(Wk_a, Wv_a, Wc, W_in, WkinT, Wv_in, Wc_f, BhW, BlW);
  proto_kernel<<<1, 256, 0, stream>>>(tpro, pro);
  fold3_kernel<<<T_, 256, 0, stream>>>(pro, Wc_f, BhW, BlW);
  fold2_kernel<<<D_, 256, 0, stream>>>(Wq_a, bq_a, bk_a, Wo_a, bo_a, bv_a, Wq, ln_w, ln_b,
                                       WkinT, Wv_in, Bqk, bqk, Wvo, bvo, Wqp, bqp, vqbk, qcst);

  // query path
  gemm_nt<false><<<dim3(H_ / 64, B_ / 64), 256, 0, stream>>>(query_emb, W_in, nullptr, qr, B_, H_, D_);
  gemm_nt<true ><<<dim3(D_ / 64, B_ / 64), 256, 0, stream>>>(qr, Bqk, bqk, qkv, B_, D_, H_);
  attn_kernel<<<B_, 256, 0, stream>>>(cand_emb, qkv, qr, vqbk, qcst, wce);
  gemm_nt<true ><<<dim3(H_ / 64, B_ / 64), 256, 0, stream>>>(wce, Wvo, bvo, ctxb, B_, H_, D_);
  ln_kernel<<<B_ / 4, 256, 0, stream>>>(ctxb, qr, xhat);
  gemm_nt<true ><<<dim3(H_ / 64, B_ / 64), 256, 0, stream>>>(xhat, Wqp, bqp, ctxb, B_, H_, H_);  // ctxb := hraw
  h_post<<<B_ / 4, 256, 0, stream>>>(ctxb, Wqt, bqt, h, need);

  // candidate path: split-bf16 MFMA GEMM, fused l2n + MFMA topic softmax
  gemm_cn<<<(B_ * K_) / 128, 512, 0, stream>>>(cand_emb, BhW, BlW, cn, tp);

  // step 0
  score_kernel<0><<<B_, 256, 0, stream>>>(h, step_emb, cn, tp, need, clam, cov, sel, chosen, out_logits, out_preds);
  // GRU update
  gemm_nt<true ><<<dim3((3 * H_) / 64, B_ / 64), 256, 0, stream>>>(chosen, W_ih, b_ih, qkv, B_, 3 * H_, H_);  // qkv := gi
  gemm_nt<true ><<<dim3((3 * H_) / 64, B_ / 64), 256, 0, stream>>>(h, W_hh, b_hh, wce, B_, 3 * H_, H_);       // wce := gh
  gru_kernel<<<B_, 256, 0, stream>>>(qkv, wce, h);
  // step 1
  score_kernel<1><<<B_, 256, 0, stream>>>(h, step_emb, cn, tp, need, clam, cov, sel, chosen, out_logits, out_preds);
}

// Round 5
// 1036.194 us; speedup vs baseline: 2.4752x; 1.2239x over previous
//
#include <hip/hip_runtime.h>
#include <math.h>

#define B_ 8192
#define K_ 32
#define D_ 768
#define H_ 256
#define T_ 16
#define S_ 2

typedef unsigned int uint;
typedef unsigned short ushort;
typedef __attribute__((ext_vector_type(8))) short bf16x8;
typedef __attribute__((ext_vector_type(4))) float f32x4;

// ---------- wave (64-lane) reductions ----------
__device__ __forceinline__ float wsum(float v) {
  v += __shfl_xor(v, 32); v += __shfl_xor(v, 16); v += __shfl_xor(v, 8);
  v += __shfl_xor(v, 4);  v += __shfl_xor(v, 2);  v += __shfl_xor(v, 1);
  return v;
}
__device__ __forceinline__ float wmaxr(float v) {
  v = fmaxf(v, __shfl_xor(v, 32)); v = fmaxf(v, __shfl_xor(v, 16));
  v = fmaxf(v, __shfl_xor(v, 8));  v = fmaxf(v, __shfl_xor(v, 4));
  v = fmaxf(v, __shfl_xor(v, 2));  v = fmaxf(v, __shfl_xor(v, 1));
  return v;
}

// split fp32 -> (hi bf16 trunc, lo bf16 trunc of exact remainder), packed 2/uint
__device__ __forceinline__ void split4(const float4 f, uint2& h, uint2& lo) {
  const uint ux = __float_as_uint(f.x), uy = __float_as_uint(f.y);
  const uint uz = __float_as_uint(f.z), uw = __float_as_uint(f.w);
  h.x = (uy & 0xFFFF0000u) | (ux >> 16);
  h.y = (uw & 0xFFFF0000u) | (uz >> 16);
  const float rx = f.x - __uint_as_float(ux & 0xFFFF0000u);
  const float ry = f.y - __uint_as_float(uy & 0xFFFF0000u);
  const float rz = f.z - __uint_as_float(uz & 0xFFFF0000u);
  const float rw = f.w - __uint_as_float(uw & 0xFFFF0000u);
  lo.x = (__float_as_uint(ry) & 0xFFFF0000u) | (__float_as_uint(rx) >> 16);
  lo.y = (__float_as_uint(rw) & 0xFFFF0000u) | (__float_as_uint(rz) >> 16);
}

// B frag tiling (NB = N/16): elem(n,k) -> ((ks*NB + nb)*64 + (nl | kc<<4))*8 + kb
// ks=k>>5, kc=(k>>3)&3, kb=k&7, nb=n>>4, nl=n&15

// ---------- fold stage 1: WkinT fp32, Wv_in fp32, Wc_in -> hi/lo bf16 frag-tiled (NB=16) ----------
__global__ __launch_bounds__(256)
void fold_kernel(const float* __restrict__ Wk_a, const float* __restrict__ Wv_a,
                 const float* __restrict__ Wc,  const float* __restrict__ W_in,
                 float* __restrict__ WkinT, float* __restrict__ Wv_in,
                 ushort* __restrict__ Bh, ushort* __restrict__ Bl)
{
  const int i = blockIdx.x;   // output row 0..255
  const int m = blockIdx.y;   // which matrix
  const float* Wx = (m == 0) ? Wk_a : ((m == 1) ? Wv_a : Wc);
  const int t = threadIdx.x;
  float a0 = 0.f, a1 = 0.f, a2 = 0.f;
  for (int k = 0; k < H_; k++) {
    const float wv = Wx[i * H_ + k];
    const float* row = W_in + (size_t)k * D_;
    a0 = fmaf(wv, row[t], a0);
    a1 = fmaf(wv, row[t + 256], a1);
    a2 = fmaf(wv, row[t + 512], a2);
  }
  if (m == 0) {
    WkinT[(size_t)t * H_ + i] = a0;
    WkinT[(size_t)(t + 256) * H_ + i] = a1;
    WkinT[(size_t)(t + 512) * H_ + i] = a2;
  } else if (m == 1) {
    float* o = Wv_in + (size_t)i * D_;
    o[t] = a0; o[t + 256] = a1; o[t + 512] = a2;
  } else {
    const float vals[3] = {a0, a1, a2};
#pragma unroll
    for (int j = 0; j < 3; j++) {
      const int k = t + j * 256;
      const float v = vals[j];
      const int idx = (((k >> 5) * 16 + (i >> 4)) * 64 + ((i & 15) | (((k >> 3) & 3) << 4))) * 8 + (k & 7);
      const uint u = __float_as_uint(v);
      Bh[idx] = (ushort)(u >> 16);
      const float rr = v - __uint_as_float(u & 0xFFFF0000u);
      Bl[idx] = (ushort)(__float_as_uint(rr) >> 16);
    }
  }
}

// ---------- generic fp32 [N][K] -> frag-tiled hi/lo bf16 ----------
__global__ __launch_bounds__(256)
void tile_kernel(const float* __restrict__ W, int NB, int K,
                 ushort* __restrict__ Bh, ushort* __restrict__ Bl)
{
  const int n = blockIdx.x, t = threadIdx.x;
  for (int k = t; k < K; k += 256) {
    const float v = W[(size_t)n * K + k];
    const int idx = (((k >> 5) * NB + (n >> 4)) * 64 + ((n & 15) | (((k >> 3) & 3) << 4))) * 8 + (k & 7);
    const uint u = __float_as_uint(v);
    Bh[idx] = (ushort)(u >> 16);
    const float rr = v - __uint_as_float(u & 0xFFFF0000u);
    Bl[idx] = (ushort)(__float_as_uint(rr) >> 16);
  }
}

// ---------- l2-normalize topic prototypes ----------
__global__ __launch_bounds__(256)
void proto_kernel(const float* __restrict__ tpro, float* __restrict__ pro)
{
  const int w = threadIdx.x >> 6, l = threadIdx.x & 63;
  for (int r = w; r < T_; r += 4) {
    const float4 v = *(const float4*)(tpro + (size_t)r * H_ + l * 4);
    const float n = fmaxf(sqrtf(wsum(v.x * v.x + v.y * v.y + v.z * v.z + v.w * v.w)), 1e-12f);
    float4 o; o.x = v.x / n; o.y = v.y / n; o.z = v.z / n; o.w = v.w / n;
    *(float4*)(pro + (size_t)r * H_ + l * 4) = o;
  }
}

// ---------- fold stage 2: attention/query-path weight folds ----------
__global__ __launch_bounds__(256)
void fold2_kernel(const float* __restrict__ Wq_a, const float* __restrict__ bq_a,
                  const float* __restrict__ bk_a, const float* __restrict__ Wo_a,
                  const float* __restrict__ bo_a, const float* __restrict__ bv_a,
                  const float* __restrict__ Wq,   const float* __restrict__ ln_w,
                  const float* __restrict__ ln_b, const float* __restrict__ WkinT,
                  const float* __restrict__ Wv_in,
                  float* __restrict__ Bqk, float* __restrict__ bqk,
                  float* __restrict__ Wvo, float* __restrict__ bvo,
                  float* __restrict__ Wqp, float* __restrict__ bqp,
                  float* __restrict__ vqbk, float* __restrict__ qcst)
{
  __shared__ float rd_s[4];
  const int n = blockIdx.x, t = threadIdx.x, w = t >> 6, l = t & 63;
  float s = 0.f;
  for (int hh = 0; hh < H_; hh++)
    s = fmaf(Wq_a[hh * H_ + t], WkinT[(size_t)n * H_ + hh], s);
  Bqk[(size_t)n * H_ + t] = s;
  float p = bq_a[t] * WkinT[(size_t)n * H_ + t];
  p = wsum(p);
  if (l == 0) rd_s[w] = p;
  __syncthreads();
  if (t == 0) bqk[n] = rd_s[0] + rd_s[1] + rd_s[2] + rd_s[3];
  if (n < H_) {
    float a0 = 0.f, a1 = 0.f, a2 = 0.f;
    for (int hh = 0; hh < H_; hh++) {
      const float wo = Wo_a[n * H_ + hh];
      const float* rowv = Wv_in + (size_t)hh * D_;
      a0 = fmaf(wo, rowv[t], a0);
      a1 = fmaf(wo, rowv[t + 256], a1);
      a2 = fmaf(wo, rowv[t + 512], a2);
    }
    Wvo[(size_t)n * D_ + t] = a0;
    Wvo[(size_t)n * D_ + t + 256] = a1;
    Wvo[(size_t)n * D_ + t + 512] = a2;
    float pb = Wo_a[n * H_ + t] * bv_a[t];
    pb = wsum(pb);
    __syncthreads();
    if (l == 0) rd_s[w] = pb;
    __syncthreads();
    if (t == 0) bvo[n] = rd_s[0] + rd_s[1] + rd_s[2] + rd_s[3] + bo_a[n];
    Wqp[n * H_ + t] = Wq[n * H_ + t] * ln_w[t];
    float pq = Wq[n * H_ + t] * ln_b[t];
    pq = wsum(pq);
    __syncthreads();
    if (l == 0) rd_s[w] = pq;
    __syncthreads();
    if (t == 0) bqp[n] = rd_s[0] + rd_s[1] + rd_s[2] + rd_s[3];
  }
  if (n == 0) {
    float sv = 0.f;
    for (int hh = 0; hh < H_; hh++) sv = fmaf(bk_a[hh], Wq_a[hh * H_ + t], sv);
    vqbk[t] = sv;
    float pc = bq_a[t] * bk_a[t];
    pc = wsum(pc);
    __syncthreads();
    if (l == 0) rd_s[w] = pc;
    __syncthreads();
    if (t == 0) qcst[0] = rd_s[0] + rd_s[1] + rd_s[2] + rd_s[3];
  }
}

// ---------- gemm_cn v3: split-bf16 MFMA, BM=64, full N=256, B from L2 regs, A LDS-dbuf ----------
// grid (B*K/64), 256 threads (4 waves, one per 64-col group), fused l2n epilogue.
__global__ __launch_bounds__(256)
void gemm_cn(const float* __restrict__ A, const ushort* __restrict__ Bh,
             const ushort* __restrict__ Bl, float* __restrict__ C)
{
  __shared__ __align__(16) ushort AhS[2][2048], AlS[2][2048];
  __shared__ float rsq[64][4];
  const int t = threadIdx.x, l = t & 63, w = t >> 6;   // w = column-group wave
  const int r = t >> 2, kc = t & 3;                    // A staging map: 64 rows x 4 chunks
  const float* Ag = A + ((size_t)blockIdx.x * 64 + r) * 768 + kc * 8;
  const int aslot = ((r >> 4) * 64 + ((r & 15) | (kc << 4))) * 8;
  const ushort* Bhb = Bh + ((w * 4) * 64 + l) * 8;     // + ks*8192 + ni*512
  const ushort* Blb = Bl + ((w * 4) * 64 + l) * 8;

  f32x4 acc[4][4];
#pragma unroll
  for (int i = 0; i < 4; i++)
#pragma unroll
    for (int j = 0; j < 4; j++) acc[i][j] = (f32x4)0.f;

  // prologue: stage A(0) -> buf0, prefetch A(1)
  float4 f0 = *(const float4*)(Ag);
  float4 f1 = *(const float4*)(Ag + 4);
  {
    uint2 ha, la, hb, lb;
    split4(f0, ha, la); split4(f1, hb, lb);
    *(uint4*)&AhS[0][aslot] = make_uint4(ha.x, ha.y, hb.x, hb.y);
    *(uint4*)&AlS[0][aslot] = make_uint4(la.x, la.y, lb.x, lb.y);
  }
  f0 = *(const float4*)(Ag + 32);
  f1 = *(const float4*)(Ag + 36);
  __syncthreads();

#pragma unroll 2
  for (int ks = 0; ks < 24; ks++) {
    const int cur = ks & 1;
    // B fragments for this ks straight from L2 into regs
    uint4 bhv[4], blv[4];
#pragma unroll
    for (int ni = 0; ni < 4; ni++) {
      bhv[ni] = *(const uint4*)(Bhb + ks * 8192 + ni * 512);
      blv[ni] = *(const uint4*)(Blb + ks * 8192 + ni * 512);
    }
    // stage A(ks+1) into the other buffer; prefetch A(ks+2)
    if (ks < 23) {
      uint2 ha, la, hb, lb;
      split4(f0, ha, la); split4(f1, hb, lb);
      *(uint4*)&AhS[cur ^ 1][aslot] = make_uint4(ha.x, ha.y, hb.x, hb.y);
      *(uint4*)&AlS[cur ^ 1][aslot] = make_uint4(la.x, la.y, lb.x, lb.y);
      if (ks < 22) {
        f0 = *(const float4*)(Ag + (ks + 2) * 32);
        f1 = *(const float4*)(Ag + (ks + 2) * 32 + 4);
      }
    }
    // MFMA: 4 row-frags x 4 col-frags x 3 terms
#pragma unroll
    for (int mi = 0; mi < 4; mi++) {
      const bf16x8 ah = *(const bf16x8*)&AhS[cur][(mi * 64 + l) * 8];
      const bf16x8 al = *(const bf16x8*)&AlS[cur][(mi * 64 + l) * 8];
#pragma unroll
      for (int ni = 0; ni < 4; ni++) {
        const bf16x8 bhf = *(const bf16x8*)&bhv[ni];
        const bf16x8 blf = *(const bf16x8*)&blv[ni];
        acc[mi][ni] = __builtin_amdgcn_mfma_f32_16x16x32_bf16(ah, bhf, acc[mi][ni], 0, 0, 0);
        acc[mi][ni] = __builtin_amdgcn_mfma_f32_16x16x32_bf16(al, bhf, acc[mi][ni], 0, 0, 0);
        acc[mi][ni] = __builtin_amdgcn_mfma_f32_16x16x32_bf16(ah, blf, acc[mi][ni], 0, 0, 0);
      }
    }
    __syncthreads();  // ds ordering only; A/B global loads stay in flight
  }

  // ---- fused epilogue: l2n + write ----
#pragma unroll
  for (int mi = 0; mi < 4; mi++)
#pragma unroll
    for (int rg = 0; rg < 4; rg++) {
      float p = 0.f;
#pragma unroll
      for (int ni = 0; ni < 4; ni++) { const float v = acc[mi][ni][rg]; p = fmaf(v, v, p); }
      p += __shfl_xor(p, 1); p += __shfl_xor(p, 2); p += __shfl_xor(p, 4); p += __shfl_xor(p, 8);
      if ((l & 15) == 0) rsq[mi * 16 + (l >> 4) * 4 + rg][w] = p;
    }
  __syncthreads();
  const size_t row0 = (size_t)blockIdx.x * 64;
#pragma unroll
  for (int mi = 0; mi < 4; mi++)
#pragma unroll
    for (int rg = 0; rg < 4; rg++) {
      const int rl = mi * 16 + (l >> 4) * 4 + rg;
      const float ssum = rsq[rl][0] + rsq[rl][1] + rsq[rl][2] + rsq[rl][3];
      const float inv = 1.f / fmaxf(sqrtf(ssum), 1e-12f);
#pragma unroll
      for (int ni = 0; ni < 4; ni++)
        C[(row0 + rl) * H_ + w * 64 + ni * 16 + (l & 15)] = acc[mi][ni][rg] * inv;
    }
}

// ---------- tp = softmax(cn . pro^T) over topics ----------
__global__ __launch_bounds__(256)
void tp_kernel(const float* __restrict__ cn, const float* __restrict__ pro,
               float* __restrict__ tp)
{
  __shared__ float cn_s[16][260];
  __shared__ float pro_s[16][260];
  const int t = threadIdx.x;
  const size_t row0 = (size_t)blockIdx.x * 16;
  const int sr = t >> 4;
#pragma unroll
  for (int j = 0; j < 4; j++) {
    const int c = (t & 15) * 4 + j * 64;
    *(float4*)&cn_s[sr][c] = *(const float4*)(cn + (row0 + sr) * H_ + c);
    *(float4*)&pro_s[sr][c] = *(const float4*)(pro + sr * H_ + c);
  }
  __syncthreads();
  const int r = t >> 4, tt = t & 15;
  float d = 0.f;
#pragma unroll 8
  for (int j = 0; j < 64; j++) {
    const float4 a = *(const float4*)&cn_s[r][j * 4];
    const float4 p = *(const float4*)&pro_s[tt][j * 4];
    d = fmaf(a.x, p.x, d); d = fmaf(a.y, p.y, d);
    d = fmaf(a.z, p.z, d); d = fmaf(a.w, p.w, d);
  }
  float m = d;
  m = fmaxf(m, __shfl_xor(m, 1)); m = fmaxf(m, __shfl_xor(m, 2));
  m = fmaxf(m, __shfl_xor(m, 4)); m = fmaxf(m, __shfl_xor(m, 8));
  const float e = expf(d - m);
  float su = e;
  su += __shfl_xor(su, 1); su += __shfl_xor(su, 2);
  su += __shfl_xor(su, 4); su += __shfl_xor(su, 8);
  tp[(row0 + r) * T_ + tt] = e / su;
}

// ---------- generic split-bf16 MFMA GEMM: C[M,N] = A[M,K]*B^T (+bias), B pre-tiled ----------
// BM=128, BN=64, 256 thr (2x2 waves), A LDS-dbuf reg-staged, B from L2 regs.
template<int NKS, int NB, bool BIAS>
__global__ __launch_bounds__(256)
void gemm_bf(const float* __restrict__ A, const ushort* __restrict__ Bh,
             const ushort* __restrict__ Bl, const float* __restrict__ bias,
             float* __restrict__ C)
{
  __shared__ __align__(16) ushort AhS[2][4096], AlS[2][4096];
  const int t = threadIdx.x, l = t & 63, w = t >> 6;
  const int wr = w >> 1, wc = w & 1;
  const int Kd = NKS * 32, N = NB * 16;
  const int r = t >> 1, kc0 = (t & 1) * 2;            // 128 rows x 2 chunk-pairs
  const float* Ag = A + ((size_t)blockIdx.x * 128 + r) * Kd + kc0 * 8;
  const int aslot0 = ((r >> 4) * 64 + ((r & 15) | (kc0 << 4))) * 8;
  const int aslot1 = aslot0 + 128;
  const int nb0 = blockIdx.y * 4 + wc * 2;
  const ushort* Bhb = Bh + (nb0 * 64 + l) * 8;        // + ks*NB*512 + ni*512
  const ushort* Blb = Bl + (nb0 * 64 + l) * 8;

  f32x4 acc[4][2];
#pragma unroll
  for (int i = 0; i < 4; i++)
#pragma unroll
    for (int j = 0; j < 2; j++) acc[i][j] = (f32x4)0.f;

  float4 f0 = *(const float4*)(Ag);
  float4 f1 = *(const float4*)(Ag + 4);
  float4 f2 = *(const float4*)(Ag + 8);
  float4 f3 = *(const float4*)(Ag + 12);
  {
    uint2 ha, la, hb, lb;
    split4(f0, ha, la); split4(f1, hb, lb);
    *(uint4*)&AhS[0][aslot0] = make_uint4(ha.x, ha.y, hb.x, hb.y);
    *(uint4*)&AlS[0][aslot0] = make_uint4(la.x, la.y, lb.x, lb.y);
    split4(f2, ha, la); split4(f3, hb, lb);
    *(uint4*)&AhS[0][aslot1] = make_uint4(ha.x, ha.y, hb.x, hb.y);
    *(uint4*)&AlS[0][aslot1] = make_uint4(la.x, la.y, lb.x, lb.y);
  }
  f0 = *(const float4*)(Ag + 32); f1 = *(const float4*)(Ag + 36);
  f2 = *(const float4*)(Ag + 40); f3 = *(const float4*)(Ag + 44);
  __syncthreads();

#pragma unroll 2
  for (int ks = 0; ks < NKS; ks++) {
    const int cur = ks & 1;
    uint4 bhv[2], blv[2];
#pragma unroll
    for (int ni = 0; ni < 2; ni++) {
      bhv[ni] = *(const uint4*)(Bhb + ks * (NB * 512) + ni * 512);
      blv[ni] = *(const uint4*)(Blb + ks * (NB * 512) + ni * 512);
    }
    if (ks < NKS - 1) {
      uint2 ha, la, hb, lb;
      split4(f0, ha, la); split4(f1, hb, lb);
      *(uint4*)&AhS[cur ^ 1][aslot0] = make_uint4(ha.x, ha.y, hb.x, hb.y);
      *(uint4*)&AlS[cur ^ 1][aslot0] = make_uint4(la.x, la.y, lb.x, lb.y);
      split4(f2, ha, la); split4(f3, hb, lb);
      *(uint4*)&AhS[cur ^ 1][aslot1] = make_uint4(ha.x, ha.y, hb.x, hb.y);
      *(uint4*)&AlS[cur ^ 1][aslot1] = make_uint4(la.x, la.y, lb.x, lb.y);
      if (ks < NKS - 2) {
        f0 = *(const float4*)(Ag + (ks + 2) * 32);
        f1 = *(const float4*)(Ag + (ks + 2) * 32 + 4);
        f2 = *(const float4*)(Ag + (ks + 2) * 32 + 8);
        f3 = *(const float4*)(Ag + (ks + 2) * 32 + 12);
      }
    }
#pragma unroll
    for (int mi = 0; mi < 4; mi++) {
      const bf16x8 ah = *(const bf16x8*)&AhS[cur][((wr * 4 + mi) * 64 + l) * 8];
      const bf16x8 al = *(const bf16x8*)&AlS[cur][((wr * 4 + mi) * 64 + l) * 8];
#pragma unroll
      for (int ni = 0; ni < 2; ni++) {
        const bf16x8 bhf = *(const bf16x8*)&bhv[ni];
        const bf16x8 blf = *(const bf16x8*)&blv[ni];
        acc[mi][ni] = __builtin_amdgcn_mfma_f32_16x16x32_bf16(ah, bhf, acc[mi][ni], 0, 0, 0);
        acc[mi][ni] = __builtin_amdgcn_mfma_f32_16x16x32_bf16(al, bhf, acc[mi][ni], 0, 0, 0);
        acc[mi][ni] = __builtin_amdgcn_mfma_f32_16x16x32_bf16(ah, blf, acc[mi][ni], 0, 0, 0);
      }
    }
    __syncthreads();
  }

  const size_t row0 = (size_t)blockIdx.x * 128 + wr * 64;
  const int col0 = blockIdx.y * 64 + wc * 32;
#pragma unroll
  for (int mi = 0; mi < 4; mi++)
#pragma unroll
    for (int ni = 0; ni < 2; ni++) {
      const int col = col0 + ni * 16 + (l & 15);
      const float bb = BIAS ? bias[col] : 0.f;
#pragma unroll
      for (int rg = 0; rg < 4; rg++) {
        const size_t row = row0 + mi * 16 + (l >> 4) * 4 + rg;
        C[row * N + col] = acc[mi][ni][rg] + bb;
      }
    }
}

// ---------- fused cross-attention (scores + softmax + PV; PV re-read L2-served) ----------
__global__ __launch_bounds__(256)
void attn_kernel(const float* __restrict__ ce, const float* __restrict__ qkv,
                 const float* __restrict__ qr, const float* __restrict__ vqbk,
                 const float* __restrict__ qcst, float* __restrict__ wce)
{
  __shared__ float4 qk_s[192];
  __shared__ float sc_s[K_];
  __shared__ float at_s[K_];
  __shared__ float rd_s[4];
  const int b = blockIdx.x, t = threadIdx.x;
  const int w = t >> 6, l = t & 63;

  float p = qr[(size_t)b * H_ + t] * vqbk[t];
  p = wsum(p);
  if (l == 0) rd_s[w] = p;
  if (t < 192) qk_s[t] = ((const float4*)qkv)[(size_t)b * 192 + t];
  __syncthreads();
  const float qbk = rd_s[0] + rd_s[1] + rd_s[2] + rd_s[3] + qcst[0];

  const float4* ceb = (const float4*)(ce + (size_t)b * K_ * D_);
#pragma unroll
  for (int cc = 0; cc < 8; cc++) {
    const int c = w * 8 + cc;
    const float4* cr = ceb + c * 192;
    float s = 0.f;
#pragma unroll
    for (int j = 0; j < 3; j++) {
      const float4 f = cr[l + j * 64];
      const float4 q4 = qk_s[l + j * 64];
      s = fmaf(f.x, q4.x, s); s = fmaf(f.y, q4.y, s);
      s = fmaf(f.z, q4.z, s); s = fmaf(f.w, q4.w, s);
    }
    s = wsum(s);
    if (l == 0) sc_s[c] = s + qbk;
  }
  __syncthreads();
  if (w == 0) {
    float s = (l < K_) ? sc_s[l] * (1.f / 16.f) : -1e30f;
    const float m = wmaxr(s);
    float e = (l < K_) ? expf(s - m) : 0.f;
    const float su = wsum(e);
    if (l < K_) at_s[l] = e / su;
  }
  __syncthreads();
  if (t < 192) {
    float4 a = make_float4(0.f, 0.f, 0.f, 0.f);
#pragma unroll
    for (int c = 0; c < K_; c++) {
      const float4 f = ceb[c * 192 + t];
      const float av = at_s[c];
      a.x = fmaf(av, f.x, a.x); a.y = fmaf(av, f.y, a.y);
      a.z = fmaf(av, f.z, a.z); a.w = fmaf(av, f.w, a.w);
    }
    ((float4*)wce)[(size_t)b * 192 + t] = a;
  }
}

// ---------- residual + LayerNorm -> xhat (scale/bias folded into Wq') ----------
__global__ __launch_bounds__(256)
void ln_kernel(const float* __restrict__ xin, const float* __restrict__ res,
               float* __restrict__ xhat)
{
  const int w = threadIdx.x >> 6, l = threadIdx.x & 63;
  const size_t r = (size_t)blockIdx.x * 4 + w;
  const float4 a = *(const float4*)(xin + r * H_ + l * 4);
  const float4 b = *(const float4*)(res + r * H_ + l * 4);
  const float x0 = a.x + b.x, x1 = a.y + b.y, x2 = a.z + b.z, x3 = a.w + b.w;
  const float mu = wsum(x0 + x1 + x2 + x3) * (1.f / H_);
  const float d0 = x0 - mu, d1 = x1 - mu, d2 = x2 - mu, d3 = x3 - mu;
  const float var = wsum(d0 * d0 + d1 * d1 + d2 * d2 + d3 * d3) * (1.f / H_);
  const float isd = 1.f / sqrtf(var + 1e-5f);
  float4 o;
  o.x = d0 * isd; o.y = d1 * isd; o.z = d2 * isd; o.w = d3 * isd;
  *(float4*)(xhat + r * H_ + l * 4) = o;
}

// ---------- h = l2n(hraw); need = softmax(h@Wqt^T + bqt) ----------
__global__ __launch_bounds__(256)
void h_post(const float* __restrict__ hraw, const float* __restrict__ Wqt,
            const float* __restrict__ bqt, float* __restrict__ h, float* __restrict__ need)
{
  __shared__ float wq_s[T_ * H_];
  for (int i = threadIdx.x; i < T_ * H_; i += 256) wq_s[i] = Wqt[i];
  const int w = threadIdx.x >> 6, l = threadIdx.x & 63;
  const size_t r = (size_t)blockIdx.x * 4 + w;
  const float4 v = *(const float4*)(hraw + r * H_ + l * 4);
  const float n = fmaxf(sqrtf(wsum(v.x * v.x + v.y * v.y + v.z * v.z + v.w * v.w)), 1e-12f);
  float4 hn; hn.x = v.x / n; hn.y = v.y / n; hn.z = v.z / n; hn.w = v.w / n;
  *(float4*)(h + r * H_ + l * 4) = hn;
  __syncthreads();
  float mine = 0.f;
  for (int tt = 0; tt < T_; tt++) {
    const float4 p4 = *(const float4*)(wq_s + tt * H_ + l * 4);
    float p = hn.x * p4.x + hn.y * p4.y + hn.z * p4.z + hn.w * p4.w;
    p = wsum(p);
    if (l == tt) mine = p + bqt[l];
  }
  float s = (l < T_) ? mine : -1e30f;
  const float m = wmaxr(s);
  const float e = (l < T_) ? expf(s - m) : 0.f;
  const float su = wsum(e);
  if (l < T_) need[r * T_ + l] = e / su;
}

// ---------- selection step ----------
template<int STEP>
__global__ __launch_bounds__(256)
void score_kernel(const float* __restrict__ h, const float* __restrict__ se,
                  const float* __restrict__ cn, const float* __restrict__ tp,
                  const float* __restrict__ need, const float* __restrict__ clam,
                  float* __restrict__ covered, int* __restrict__ sel,
                  float* __restrict__ chosen, float* __restrict__ logits,
                  float* __restrict__ preds)
{
  __shared__ __align__(16) float hs_s[H_];
  __shared__ float nu_s[T_];
  __shared__ float sc_s[K_];
  __shared__ float rd_s[4];
  __shared__ int idx_s;
  const int b = blockIdx.x, t = threadIdx.x;
  const int w = t >> 6, l = t & 63;

  const float hv = h[(size_t)b * H_ + t] + se[STEP * H_ + t];
  const float ss = wsum(hv * hv);
  if (l == 0) rd_s[w] = ss;
  if (STEP == 1 && t < T_)
    nu_s[t] = need[(size_t)b * T_ + t] * fminf(fmaxf(1.f - covered[(size_t)b * T_ + t], 0.f), 1.f);
  __syncthreads();
  const float n = fmaxf(sqrtf(rd_s[0] + rd_s[1] + rd_s[2] + rd_s[3]), 1e-12f);
  hs_s[t] = hv / n;
  __syncthreads();

  const float lam = log1pf(expf(clam[0]));
  const float4 hf = *(const float4*)(hs_s + l * 4);
#pragma unroll
  for (int cc = 0; cc < 8; cc++) {
    const int c = w * 8 + cc;
    const float4 cv = *(const float4*)(cn + ((size_t)b * K_ + c) * H_ + l * 4);
    float p = cv.x * hf.x + cv.y * hf.y + cv.z * hf.z + cv.w * hf.w;
    p = wsum(p);
    float s = p / 0.1f;
    if (STEP == 1) {
      float g = (l < T_) ? nu_s[l] * tp[((size_t)b * K_ + c) * T_ + l] : 0.f;
      g = wsum(g);
      s += lam * g;
      if (sel[(size_t)b * K_ + c]) s = -100.f;
    }
    if (l == 0) sc_s[c] = s;
  }
  __syncthreads();
  if (w == 0) {
    float s = (l < K_) ? sc_s[l] : -1e30f;
    int bi = (l < K_) ? l : K_;
#pragma unroll
    for (int o = 32; o; o >>= 1) {
      const float s2 = __shfl_xor(s, o);
      const int i2 = __shfl_xor(bi, o);
      if (s2 > s || (s2 == s && i2 < bi)) { s = s2; bi = i2; }
    }
    if (l == 0) idx_s = bi;
  }
  __syncthreads();
  const int idx = idx_s;
  if (t < K_) logits[(size_t)b * (S_ * K_) + STEP * K_ + t] = sc_s[t];
  if (t == 0) preds[(size_t)b * S_ + STEP] = (float)idx;
  if (STEP == 0) {
    if (t < K_) sel[(size_t)b * K_ + t] = (t == idx) ? 1 : 0;
    if (t < T_) covered[(size_t)b * T_ + t] = fminf(tp[((size_t)b * K_ + idx) * T_ + t], 1.f);
    chosen[(size_t)b * H_ + t] = cn[((size_t)b * K_ + idx) * H_ + t];
  }
}

// ---------- GRU gate fusion + l2n, h updated in place ----------
__global__ __launch_bounds__(256)
void gru_kernel(const float* __restrict__ gi, const float* __restrict__ gh, float* __restrict__ h)
{
  __shared__ float rd_s[4];
  const int b = blockIdx.x, t = threadIdx.x, w = t >> 6, l = t & 63;
  const size_t o = (size_t)b * (3 * H_);
  const float ir = gi[o + t], iz = gi[o + 256 + t], ig = gi[o + 512 + t];
  const float hr = gh[o + t], hz = gh[o + 256 + t], hg = gh[o + 512 + t];
  const float hv = h[(size_t)b * H_ + t];
  const float r = 1.f / (1.f + expf(-(ir + hr)));
  const float z = 1.f / (1.f + expf(-(iz + hz)));
  const float nn = tanhf(ig + r * hg);
  const float x = (1.f - z) * nn + z * hv;
  const float ss = wsum(x * x);
  if (l == 0) rd_s[w] = ss;
  __syncthreads();
  const float n = fmaxf(sqrtf(rd_s[0] + rd_s[1] + rd_s[2] + rd_s[3]), 1e-12f);
  h[(size_t)b * H_ + t] = x / n;
}

extern "C" void kernel_launch(void* const* d_in, const int* in_sizes, int n_in,
                              void* d_out, int out_size, void* d_ws, size_t ws_size,
                              hipStream_t stream)
{
  const float* query_emb = (const float*)d_in[0];
  const float* cand_emb  = (const float*)d_in[1];
  const float* W_in = (const float*)d_in[2];
  const float* Wq_a = (const float*)d_in[3];
  const float* Wk_a = (const float*)d_in[4];
  const float* Wv_a = (const float*)d_in[5];
  const float* bq_a = (const float*)d_in[6];
  const float* bk_a = (const float*)d_in[7];
  const float* bv_a = (const float*)d_in[8];
  const float* Wo_a = (const float*)d_in[9];
  const float* bo_a = (const float*)d_in[10];
  const float* ln_w = (const float*)d_in[11];
  const float* ln_b = (const float*)d_in[12];
  const float* Wq   = (const float*)d_in[13];
  const float* Wc   = (const float*)d_in[14];
  const float* W_ih = (const float*)d_in[15];
  const float* W_hh = (const float*)d_in[16];
  const float* b_ih = (const float*)d_in[17];
  const float* b_hh = (const float*)d_in[18];
  const float* step_emb = (const float*)d_in[19];
  const float* tpro = (const float*)d_in[20];
  const float* Wqt  = (const float*)d_in[21];
  const float* bqt  = (const float*)d_in[22];
  const float* clam = (const float*)d_in[23];

  float* ws = (float*)d_ws;
  size_t o = 0;
  float* WkinT = ws + o; o += (size_t)D_ * H_;
  float* Wv_in = ws + o; o += (size_t)H_ * D_;
  ushort* BhW  = (ushort*)(ws + o); o += 98304;   // 24*16*64*8 ushorts
  ushort* BlW  = (ushort*)(ws + o); o += 98304;
  float* pro   = ws + o; o += (size_t)T_ * H_;
  float* Bqk   = ws + o; o += (size_t)D_ * H_;
  float* bqk   = ws + o; o += 1024;
  float* Wvo   = ws + o; o += (size_t)H_ * D_;
  float* bvo   = ws + o; o += 256;
  float* Wqp   = ws + o; o += (size_t)H_ * H_;
  float* bqp   = ws + o; o += 256;
  float* vqbk  = ws + o; o += 256;
  float* qcst  = ws + o; o += 4;
  ushort* WintH = (ushort*)(ws + o); o += 98304;  // 256x768
  ushort* WintL = (ushort*)(ws + o); o += 98304;
  ushort* BqktH = (ushort*)(ws + o); o += 98304;  // 768x256
  ushort* BqktL = (ushort*)(ws + o); o += 98304;
  ushort* WvotH = (ushort*)(ws + o); o += 98304;  // 256x768
  ushort* WvotL = (ushort*)(ws + o); o += 98304;
  ushort* WqptH = (ushort*)(ws + o); o += 32768;  // 256x256
  ushort* WqptL = (ushort*)(ws + o); o += 32768;
  ushort* WihtH = (ushort*)(ws + o); o += 98304;  // 768x256
  ushort* WihtL = (ushort*)(ws + o); o += 98304;
  ushort* WhhtH = (ushort*)(ws + o); o += 98304;  // 768x256
  ushort* WhhtL = (ushort*)(ws + o); o += 98304;
  float* qr    = ws + o; o += (size_t)B_ * H_;
  float* qkv   = ws + o; o += (size_t)B_ * D_;   // later: gi
  float* wce   = ws + o; o += (size_t)B_ * D_;   // later: gh
  float* ctxb  = ws + o; o += (size_t)B_ * H_;   // ctx, later hraw
  float* xhat  = ws + o; o += (size_t)B_ * H_;
  float* h     = ws + o; o += (size_t)B_ * H_;
  float* need  = ws + o; o += (size_t)B_ * T_;
  float* cn    = ws + o; o += (size_t)B_ * K_ * H_;
  float* tp    = ws + o; o += (size_t)B_ * K_ * T_;
  int*   sel   = (int*)(ws + o); o += (size_t)B_ * K_;
  float* cov   = ws + o; o += (size_t)B_ * T_;
  float* chosen= ws + o; o += (size_t)B_ * H_;

  float* out_logits = (float*)d_out;
  float* out_preds  = (float*)d_out + (size_t)B_ * S_ * K_;

  // weight folding + tiling
  fold_kernel<<<dim3(H_, 3), 256, 0, stream>>>(Wk_a, Wv_a, Wc, W_in, WkinT, Wv_in, BhW, BlW);
  proto_kernel<<<1, 256, 0, stream>>>(tpro, pro);
  fold2_kernel<<<D_, 256, 0, stream>>>(Wq_a, bq_a, bk_a, Wo_a, bo_a, bv_a, Wq, ln_w, ln_b,
                                       WkinT, Wv_in, Bqk, bqk, Wvo, bvo, Wqp, bqp, vqbk, qcst);
  tile_kernel<<<H_, 256, 0, stream>>>(W_in, 16, 768, WintH, WintL);
  tile_kernel<<<D_, 256, 0, stream>>>(Bqk, 48, 256, BqktH, BqktL);
  tile_kernel<<<H_, 256, 0, stream>>>(Wvo, 16, 768, WvotH, WvotL);
  tile_kernel<<<H_, 256, 0, stream>>>(Wqp, 16, 256, WqptH, WqptL);
  tile_kernel<<<D_, 256, 0, stream>>>(W_ih, 48, 256, WihtH, WihtL);
  tile_kernel<<<D_, 256, 0, stream>>>(W_hh, 48, 256, WhhtH, WhhtL);

  // query path (all MFMA)
  gemm_bf<24, 16, false><<<dim3(B_ / 128, 4), 256, 0, stream>>>(query_emb, WintH, WintL, nullptr, qr);
  gemm_bf<8, 48, true><<<dim3(B_ / 128, 12), 256, 0, stream>>>(qr, BqktH, BqktL, bqk, qkv);
  attn_kernel<<<B_, 256, 0, stream>>>(cand_emb, qkv, qr, vqbk, qcst, wce);
  gemm_bf<24, 16, true><<<dim3(B_ / 128, 4), 256, 0, stream>>>(wce, WvotH, WvotL, bvo, ctxb);
  ln_kernel<<<B_ / 4, 256, 0, stream>>>(ctxb, qr, xhat);
  gemm_bf<8, 16, true><<<dim3(B_ / 128, 4), 256, 0, stream>>>(xhat, WqptH, WqptL, bqp, ctxb);  // ctxb := hraw
  h_post<<<B_ / 4, 256, 0, stream>>>(ctxb, Wqt, bqt, h, need);

  // candidate path
  gemm_cn<<<(B_ * K_) / 64, 256, 0, stream>>>(cand_emb, BhW, BlW, cn);
  tp_kernel<<<(B_ * K_) / 16, 256, 0, stream>>>(cn, pro, tp);

  // step 0
  score_kernel<0><<<B_, 256, 0, stream>>>(h, step_emb, cn, tp, need, clam, cov, sel, chosen, out_logits, out_preds);
  // GRU update
  gemm_bf<8, 48, true><<<dim3(B_ / 128, 12), 256, 0, stream>>>(chosen, WihtH, WihtL, b_ih, qkv);  // qkv := gi
  gemm_bf<8, 48, true><<<dim3(B_ / 128, 12), 256, 0, stream>>>(h, WhhtH, WhhtL, b_hh, wce);       // wce := gh
  gru_kernel<<<B_, 256, 0, stream>>>(qkv, wce, h);
  // step 1
  score_kernel<1><<<B_, 256, 0, stream>>>(h, step_emb, cn, tp, need, clam, cov, sel, chosen, out_logits, out_preds);
}

// Round 6
// 961.130 us; speedup vs baseline: 2.6685x; 1.0781x over previous
//
#include <hip/hip_runtime.h>
#include <math.h>

#define B_ 8192
#define K_ 32
#define D_ 768
#define H_ 256
#define T_ 16
#define S_ 2

typedef unsigned int uint;
typedef unsigned short ushort;
typedef __attribute__((ext_vector_type(8))) short bf16x8;
typedef __attribute__((ext_vector_type(4))) float f32x4;

// ---------- wave (64-lane) reductions ----------
__device__ __forceinline__ float wsum(float v) {
  v += __shfl_xor(v, 32); v += __shfl_xor(v, 16); v += __shfl_xor(v, 8);
  v += __shfl_xor(v, 4);  v += __shfl_xor(v, 2);  v += __shfl_xor(v, 1);
  return v;
}
__device__ __forceinline__ float wmaxr(float v) {
  v = fmaxf(v, __shfl_xor(v, 32)); v = fmaxf(v, __shfl_xor(v, 16));
  v = fmaxf(v, __shfl_xor(v, 8));  v = fmaxf(v, __shfl_xor(v, 4));
  v = fmaxf(v, __shfl_xor(v, 2));  v = fmaxf(v, __shfl_xor(v, 1));
  return v;
}

// split fp32 -> (hi bf16 trunc, lo bf16 trunc of exact remainder), packed 2/uint
__device__ __forceinline__ void split4(const float4 f, uint2& h, uint2& lo) {
  const uint ux = __float_as_uint(f.x), uy = __float_as_uint(f.y);
  const uint uz = __float_as_uint(f.z), uw = __float_as_uint(f.w);
  h.x = (uy & 0xFFFF0000u) | (ux >> 16);
  h.y = (uw & 0xFFFF0000u) | (uz >> 16);
  const float rx = f.x - __uint_as_float(ux & 0xFFFF0000u);
  const float ry = f.y - __uint_as_float(uy & 0xFFFF0000u);
  const float rz = f.z - __uint_as_float(uz & 0xFFFF0000u);
  const float rw = f.w - __uint_as_float(uw & 0xFFFF0000u);
  lo.x = (__float_as_uint(ry) & 0xFFFF0000u) | (__float_as_uint(rx) >> 16);
  lo.y = (__float_as_uint(rw) & 0xFFFF0000u) | (__float_as_uint(rz) >> 16);
}

__device__ __forceinline__ float dot4(const float4 a, const float4 b) {
  float s = a.x * b.x;
  s = fmaf(a.y, b.y, s); s = fmaf(a.z, b.z, s); s = fmaf(a.w, b.w, s);
  return s;
}

// B frag tiling (NB = N/16): elem(n,k) -> ((ks*NB + nb)*64 + (nl | kc<<4))*8 + kb
// ks=k>>5, kc=(k>>3)&3, kb=k&7, nb=n>>4, nl=n&15

// ---------- fold stage 1: WkinT fp32, Wv_in fp32, Wc_in -> hi/lo bf16 frag-tiled (NB=16) ----------
__global__ __launch_bounds__(256)
void fold_kernel(const float* __restrict__ Wk_a, const float* __restrict__ Wv_a,
                 const float* __restrict__ Wc,  const float* __restrict__ W_in,
                 float* __restrict__ WkinT, float* __restrict__ Wv_in,
                 ushort* __restrict__ Bh, ushort* __restrict__ Bl)
{
  const int i = blockIdx.x;   // output row 0..255
  const int m = blockIdx.y;   // which matrix
  const float* Wx = (m == 0) ? Wk_a : ((m == 1) ? Wv_a : Wc);
  const int t = threadIdx.x;
  float a0 = 0.f, a1 = 0.f, a2 = 0.f;
  for (int k = 0; k < H_; k++) {
    const float wv = Wx[i * H_ + k];
    const float* row = W_in + (size_t)k * D_;
    a0 = fmaf(wv, row[t], a0);
    a1 = fmaf(wv, row[t + 256], a1);
    a2 = fmaf(wv, row[t + 512], a2);
  }
  if (m == 0) {
    WkinT[(size_t)t * H_ + i] = a0;
    WkinT[(size_t)(t + 256) * H_ + i] = a1;
    WkinT[(size_t)(t + 512) * H_ + i] = a2;
  } else if (m == 1) {
    float* o = Wv_in + (size_t)i * D_;
    o[t] = a0; o[t + 256] = a1; o[t + 512] = a2;
  } else {
    const float vals[3] = {a0, a1, a2};
#pragma unroll
    for (int j = 0; j < 3; j++) {
      const int k = t + j * 256;
      const float v = vals[j];
      const int idx = (((k >> 5) * 16 + (i >> 4)) * 64 + ((i & 15) | (((k >> 3) & 3) << 4))) * 8 + (k & 7);
      const uint u = __float_as_uint(v);
      Bh[idx] = (ushort)(u >> 16);
      const float rr = v - __uint_as_float(u & 0xFFFF0000u);
      Bl[idx] = (ushort)(__float_as_uint(rr) >> 16);
    }
  }
}

// ---------- all weight tilings in one launch ----------
struct TileJob { const float* W; ushort* Bh; ushort* Bl; int NB; int K; int rows; };
struct TileJobs { TileJob j[6]; };

__global__ __launch_bounds__(256)
void tile_all(TileJobs jobs)
{
  const TileJob J = jobs.j[blockIdx.y];
  const int n = blockIdx.x;
  if (n >= J.rows) return;
  const int t = threadIdx.x;
  for (int k = t; k < J.K; k += 256) {
    const float v = J.W[(size_t)n * J.K + k];
    const int idx = (((k >> 5) * J.NB + (n >> 4)) * 64 + ((n & 15) | (((k >> 3) & 3) << 4))) * 8 + (k & 7);
    const uint u = __float_as_uint(v);
    J.Bh[idx] = (ushort)(u >> 16);
    const float rr = v - __uint_as_float(u & 0xFFFF0000u);
    J.Bl[idx] = (ushort)(__float_as_uint(rr) >> 16);
  }
}

// ---------- l2-normalize topic prototypes ----------
__global__ __launch_bounds__(256)
void proto_kernel(const float* __restrict__ tpro, float* __restrict__ pro)
{
  const int w = threadIdx.x >> 6, l = threadIdx.x & 63;
  for (int r = w; r < T_; r += 4) {
    const float4 v = *(const float4*)(tpro + (size_t)r * H_ + l * 4);
    const float n = fmaxf(sqrtf(wsum(v.x * v.x + v.y * v.y + v.z * v.z + v.w * v.w)), 1e-12f);
    float4 o; o.x = v.x / n; o.y = v.y / n; o.z = v.z / n; o.w = v.w / n;
    *(float4*)(pro + (size_t)r * H_ + l * 4) = o;
  }
}

// ---------- fold stage 2: attention/query-path weight folds ----------
__global__ __launch_bounds__(256)
void fold2_kernel(const float* __restrict__ Wq_a, const float* __restrict__ bq_a,
                  const float* __restrict__ bk_a, const float* __restrict__ Wo_a,
                  const float* __restrict__ bo_a, const float* __restrict__ bv_a,
                  const float* __restrict__ Wq,   const float* __restrict__ ln_w,
                  const float* __restrict__ ln_b, const float* __restrict__ WkinT,
                  const float* __restrict__ Wv_in,
                  float* __restrict__ Bqk, float* __restrict__ bqk,
                  float* __restrict__ Wvo, float* __restrict__ bvo,
                  float* __restrict__ Wqp, float* __restrict__ bqp,
                  float* __restrict__ vqbk, float* __restrict__ qcst)
{
  __shared__ float rd_s[4];
  const int n = blockIdx.x, t = threadIdx.x, w = t >> 6, l = t & 63;
  float s = 0.f;
  for (int hh = 0; hh < H_; hh++)
    s = fmaf(Wq_a[hh * H_ + t], WkinT[(size_t)n * H_ + hh], s);
  Bqk[(size_t)n * H_ + t] = s;
  float p = bq_a[t] * WkinT[(size_t)n * H_ + t];
  p = wsum(p);
  if (l == 0) rd_s[w] = p;
  __syncthreads();
  if (t == 0) bqk[n] = rd_s[0] + rd_s[1] + rd_s[2] + rd_s[3];
  if (n < H_) {
    float a0 = 0.f, a1 = 0.f, a2 = 0.f;
    for (int hh = 0; hh < H_; hh++) {
      const float wo = Wo_a[n * H_ + hh];
      const float* rowv = Wv_in + (size_t)hh * D_;
      a0 = fmaf(wo, rowv[t], a0);
      a1 = fmaf(wo, rowv[t + 256], a1);
      a2 = fmaf(wo, rowv[t + 512], a2);
    }
    Wvo[(size_t)n * D_ + t] = a0;
    Wvo[(size_t)n * D_ + t + 256] = a1;
    Wvo[(size_t)n * D_ + t + 512] = a2;
    float pb = Wo_a[n * H_ + t] * bv_a[t];
    pb = wsum(pb);
    __syncthreads();
    if (l == 0) rd_s[w] = pb;
    __syncthreads();
    if (t == 0) bvo[n] = rd_s[0] + rd_s[1] + rd_s[2] + rd_s[3] + bo_a[n];
    Wqp[n * H_ + t] = Wq[n * H_ + t] * ln_w[t];
    float pq = Wq[n * H_ + t] * ln_b[t];
    pq = wsum(pq);
    __syncthreads();
    if (l == 0) rd_s[w] = pq;
    __syncthreads();
    if (t == 0) bqp[n] = rd_s[0] + rd_s[1] + rd_s[2] + rd_s[3];
  }
  if (n == 0) {
    float sv = 0.f;
    for (int hh = 0; hh < H_; hh++) sv = fmaf(bk_a[hh], Wq_a[hh * H_ + t], sv);
    vqbk[t] = sv;
    float pc = bq_a[t] * bk_a[t];
    pc = wsum(pc);
    __syncthreads();
    if (l == 0) rd_s[w] = pc;
    __syncthreads();
    if (t == 0) qcst[0] = rd_s[0] + rd_s[1] + rd_s[2] + rd_s[3];
  }
}

// ---------- fused gemm_cn + cross-attention ----------
// Block = 64 rows = batches {2b, 2b+1}. Computes cn (l2n'd), attn scores in-staging,
// softmax, PV (L3-served re-read), wce. 256 threads (4 waves, one per 64-col group).
__global__ __launch_bounds__(256)
void gemm_cn_attn(const float* __restrict__ A, const ushort* __restrict__ Bh,
                  const ushort* __restrict__ Bl, const float* __restrict__ qkv,
                  const float* __restrict__ qr, const float* __restrict__ vqbk,
                  const float* __restrict__ qcst, float* __restrict__ C,
                  float* __restrict__ wce)
{
  __shared__ __align__(16) ushort AhS[2][2048], AlS[2][2048];
  __shared__ __align__(16) float4 qkv_s[384];   // 2 batches x 192
  __shared__ float sc_s[64], at_s[64], qbk_s[2];
  __shared__ float rsq[64][4];
  const int t = threadIdx.x, l = t & 63, w = t >> 6;
  const int r = t >> 2, kc = t & 3;             // A staging map: 64 rows x 4 chunks
  const int tb = t >> 7;                        // staging thread's batch (0/1)
  const float* Ag = A + ((size_t)blockIdx.x * 64 + r) * 768 + kc * 8;
  const int aslot = ((r >> 4) * 64 + ((r & 15) | (kc << 4))) * 8;
  const ushort* Bhb = Bh + ((w * 4) * 64 + l) * 8;   // + ks*8192 + ni*512
  const ushort* Blb = Bl + ((w * 4) * 64 + l) * 8;

  // load qkv for both batches into LDS; compute qbk per batch (waves 0,1)
  for (int i = t; i < 384; i += 256)
    qkv_s[i] = ((const float4*)qkv)[(size_t)blockIdx.x * 384 + i];
  if (w < 2) {
    const float4 q4 = ((const float4*)qr)[((size_t)blockIdx.x * 2 + w) * 64 + l];
    const float4 v4 = ((const float4*)vqbk)[l];
    float p = wsum(dot4(q4, v4));
    if (l == 0) qbk_s[w] = p + qcst[0];
  }

  f32x4 acc[4][4];
#pragma unroll
  for (int i = 0; i < 4; i++)
#pragma unroll
    for (int j = 0; j < 4; j++) acc[i][j] = (f32x4)0.f;

  float sc = 0.f;
  // prologue: load A(0), dot with qkv, stage -> buf0, prefetch A(1)
  float4 f0 = *(const float4*)(Ag);
  float4 f1 = *(const float4*)(Ag + 4);
  __syncthreads();  // qkv_s ready
  sc += dot4(f0, qkv_s[tb * 192 + kc * 2]) + dot4(f1, qkv_s[tb * 192 + kc * 2 + 1]);
  {
    uint2 ha, la, hb, lb;
    split4(f0, ha, la); split4(f1, hb, lb);
    *(uint4*)&AhS[0][aslot] = make_uint4(ha.x, ha.y, hb.x, hb.y);
    *(uint4*)&AlS[0][aslot] = make_uint4(la.x, la.y, lb.x, lb.y);
  }
  f0 = *(const float4*)(Ag + 32);
  f1 = *(const float4*)(Ag + 36);
  __syncthreads();

#pragma unroll 2
  for (int ks = 0; ks < 24; ks++) {
    const int cur = ks & 1;
    // stage A(ks+1): score-dot + split into the other buffer; prefetch A(ks+2)
    if (ks < 23) {
      sc += dot4(f0, qkv_s[tb * 192 + (ks + 1) * 8 + kc * 2]) +
            dot4(f1, qkv_s[tb * 192 + (ks + 1) * 8 + kc * 2 + 1]);
      uint2 ha, la, hb, lb;
      split4(f0, ha, la); split4(f1, hb, lb);
      *(uint4*)&AhS[cur ^ 1][aslot] = make_uint4(ha.x, ha.y, hb.x, hb.y);
      *(uint4*)&AlS[cur ^ 1][aslot] = make_uint4(la.x, la.y, lb.x, lb.y);
      if (ks < 22) {
        f0 = *(const float4*)(Ag + (ks + 2) * 32);
        f1 = *(const float4*)(Ag + (ks + 2) * 32 + 4);
      }
    }
    // MFMA: per-ni B frags just-in-time from L2
    bf16x8 ah[4], al[4];
#pragma unroll
    for (int mi = 0; mi < 4; mi++) {
      ah[mi] = *(const bf16x8*)&AhS[cur][(mi * 64 + l) * 8];
      al[mi] = *(const bf16x8*)&AlS[cur][(mi * 64 + l) * 8];
    }
#pragma unroll
    for (int ni = 0; ni < 4; ni++) {
      const bf16x8 bhf = *(const bf16x8*)(Bhb + ks * 8192 + ni * 512);
      const bf16x8 blf = *(const bf16x8*)(Blb + ks * 8192 + ni * 512);
#pragma unroll
      for (int mi = 0; mi < 4; mi++) {
        acc[mi][ni] = __builtin_amdgcn_mfma_f32_16x16x32_bf16(ah[mi], bhf, acc[mi][ni], 0, 0, 0);
        acc[mi][ni] = __builtin_amdgcn_mfma_f32_16x16x32_bf16(al[mi], bhf, acc[mi][ni], 0, 0, 0);
        acc[mi][ni] = __builtin_amdgcn_mfma_f32_16x16x32_bf16(ah[mi], blf, acc[mi][ni], 0, 0, 0);
      }
    }
    __syncthreads();  // ds ordering only; global loads stay in flight
  }

  // ---- attention: reduce scores over kc, softmax per batch, PV ----
  sc += __shfl_xor(sc, 1);
  sc += __shfl_xor(sc, 2);
  if ((t & 3) == 0) sc_s[r] = sc;
  __syncthreads();
  if (w < 2) {  // wave w handles batch w
    float s = (l < 32) ? (sc_s[w * 32 + l] + qbk_s[w]) * (1.f / 16.f) : -1e30f;
    const float m = wmaxr(s);
    const float e = (l < 32) ? expf(s - m) : 0.f;
    const float su = wsum(e);
    if (l < 32) at_s[w * 32 + l] = e / su;
  }
  __syncthreads();
  // PV: 384 float4 slots (2 batches x 192); ce re-read is L3-served
#pragma unroll
  for (int p = 0; p < 2; p++) {
    const int slot = t + p * 256;
    if (slot < 384) {
      const int tb2 = slot >= 192;
      const int idx = slot - tb2 * 192;
      const float4* cb = (const float4*)A + ((size_t)blockIdx.x * 64 + tb2 * 32) * 192 + idx;
      float4 a = make_float4(0.f, 0.f, 0.f, 0.f);
#pragma unroll 8
      for (int c = 0; c < 32; c++) {
        const float av = at_s[tb2 * 32 + c];
        const float4 f = cb[c * 192];
        a.x = fmaf(av, f.x, a.x); a.y = fmaf(av, f.y, a.y);
        a.z = fmaf(av, f.z, a.z); a.w = fmaf(av, f.w, a.w);
      }
      ((float4*)wce)[((size_t)blockIdx.x * 2 + tb2) * 192 + idx] = a;
    }
  }

  // ---- fused epilogue: l2n + write cn ----
#pragma unroll
  for (int mi = 0; mi < 4; mi++)
#pragma unroll
    for (int rg = 0; rg < 4; rg++) {
      float p = 0.f;
#pragma unroll
      for (int ni = 0; ni < 4; ni++) { const float v = acc[mi][ni][rg]; p = fmaf(v, v, p); }
      p += __shfl_xor(p, 1); p += __shfl_xor(p, 2); p += __shfl_xor(p, 4); p += __shfl_xor(p, 8);
      if ((l & 15) == 0) rsq[mi * 16 + (l >> 4) * 4 + rg][w] = p;
    }
  __syncthreads();
  const size_t row0 = (size_t)blockIdx.x * 64;
#pragma unroll
  for (int mi = 0; mi < 4; mi++)
#pragma unroll
    for (int rg = 0; rg < 4; rg++) {
      const int rl = mi * 16 + (l >> 4) * 4 + rg;
      const float ssum = rsq[rl][0] + rsq[rl][1] + rsq[rl][2] + rsq[rl][3];
      const float inv = 1.f / fmaxf(sqrtf(ssum), 1e-12f);
#pragma unroll
      for (int ni = 0; ni < 4; ni++)
        C[(row0 + rl) * H_ + w * 64 + ni * 16 + (l & 15)] = acc[mi][ni][rg] * inv;
    }
}

// ---------- tp = softmax(cn . pro^T) over topics ----------
__global__ __launch_bounds__(256)
void tp_kernel(const float* __restrict__ cn, const float* __restrict__ pro,
               float* __restrict__ tp)
{
  __shared__ float cn_s[16][260];
  __shared__ float pro_s[16][260];
  const int t = threadIdx.x;
  const size_t row0 = (size_t)blockIdx.x * 16;
  const int sr = t >> 4;
#pragma unroll
  for (int j = 0; j < 4; j++) {
    const int c = (t & 15) * 4 + j * 64;
    *(float4*)&cn_s[sr][c] = *(const float4*)(cn + (row0 + sr) * H_ + c);
    *(float4*)&pro_s[sr][c] = *(const float4*)(pro + sr * H_ + c);
  }
  __syncthreads();
  const int r = t >> 4, tt = t & 15;
  float d = 0.f;
#pragma unroll 8
  for (int j = 0; j < 64; j++) {
    const float4 a = *(const float4*)&cn_s[r][j * 4];
    const float4 p = *(const float4*)&pro_s[tt][j * 4];
    d = fmaf(a.x, p.x, d); d = fmaf(a.y, p.y, d);
    d = fmaf(a.z, p.z, d); d = fmaf(a.w, p.w, d);
  }
  float m = d;
  m = fmaxf(m, __shfl_xor(m, 1)); m = fmaxf(m, __shfl_xor(m, 2));
  m = fmaxf(m, __shfl_xor(m, 4)); m = fmaxf(m, __shfl_xor(m, 8));
  const float e = expf(d - m);
  float su = e;
  su += __shfl_xor(su, 1); su += __shfl_xor(su, 2);
  su += __shfl_xor(su, 4); su += __shfl_xor(su, 8);
  tp[(row0 + r) * T_ + tt] = e / su;
}

// ---------- generic split-bf16 MFMA GEMM: C[M,N] = A[M,K]*B^T (+bias), B pre-tiled ----------
template<int NKS, int NB, bool BIAS>
__global__ __launch_bounds__(256)
void gemm_bf(const float* __restrict__ A, const ushort* __restrict__ Bh,
             const ushort* __restrict__ Bl, const float* __restrict__ bias,
             float* __restrict__ C)
{
  __shared__ __align__(16) ushort AhS[2][4096], AlS[2][4096];
  const int t = threadIdx.x, l = t & 63, w = t >> 6;
  const int wr = w >> 1, wc = w & 1;
  const int Kd = NKS * 32, N = NB * 16;
  const int r = t >> 1, kc0 = (t & 1) * 2;
  const float* Ag = A + ((size_t)blockIdx.x * 128 + r) * Kd + kc0 * 8;
  const int aslot0 = ((r >> 4) * 64 + ((r & 15) | (kc0 << 4))) * 8;
  const int aslot1 = aslot0 + 128;
  const int nb0 = blockIdx.y * 4 + wc * 2;
  const ushort* Bhb = Bh + (nb0 * 64 + l) * 8;
  const ushort* Blb = Bl + (nb0 * 64 + l) * 8;

  f32x4 acc[4][2];
#pragma unroll
  for (int i = 0; i < 4; i++)
#pragma unroll
    for (int j = 0; j < 2; j++) acc[i][j] = (f32x4)0.f;

  float4 f0 = *(const float4*)(Ag);
  float4 f1 = *(const float4*)(Ag + 4);
  float4 f2 = *(const float4*)(Ag + 8);
  float4 f3 = *(const float4*)(Ag + 12);
  {
    uint2 ha, la, hb, lb;
    split4(f0, ha, la); split4(f1, hb, lb);
    *(uint4*)&AhS[0][aslot0] = make_uint4(ha.x, ha.y, hb.x, hb.y);
    *(uint4*)&AlS[0][aslot0] = make_uint4(la.x, la.y, lb.x, lb.y);
    split4(f2, ha, la); split4(f3, hb, lb);
    *(uint4*)&AhS[0][aslot1] = make_uint4(ha.x, ha.y, hb.x, hb.y);
    *(uint4*)&AlS[0][aslot1] = make_uint4(la.x, la.y, lb.x, lb.y);
  }
  f0 = *(const float4*)(Ag + 32); f1 = *(const float4*)(Ag + 36);
  f2 = *(const float4*)(Ag + 40); f3 = *(const float4*)(Ag + 44);
  __syncthreads();

#pragma unroll 2
  for (int ks = 0; ks < NKS; ks++) {
    const int cur = ks & 1;
    if (ks < NKS - 1) {
      uint2 ha, la, hb, lb;
      split4(f0, ha, la); split4(f1, hb, lb);
      *(uint4*)&AhS[cur ^ 1][aslot0] = make_uint4(ha.x, ha.y, hb.x, hb.y);
      *(uint4*)&AlS[cur ^ 1][aslot0] = make_uint4(la.x, la.y, lb.x, lb.y);
      split4(f2, ha, la); split4(f3, hb, lb);
      *(uint4*)&AhS[cur ^ 1][aslot1] = make_uint4(ha.x, ha.y, hb.x, hb.y);
      *(uint4*)&AlS[cur ^ 1][aslot1] = make_uint4(la.x, la.y, lb.x, lb.y);
      if (ks < NKS - 2) {
        f0 = *(const float4*)(Ag + (ks + 2) * 32);
        f1 = *(const float4*)(Ag + (ks + 2) * 32 + 4);
        f2 = *(const float4*)(Ag + (ks + 2) * 32 + 8);
        f3 = *(const float4*)(Ag + (ks + 2) * 32 + 12);
      }
    }
#pragma unroll
    for (int mi = 0; mi < 4; mi++) {
      const bf16x8 ah = *(const bf16x8*)&AhS[cur][((wr * 4 + mi) * 64 + l) * 8];
      const bf16x8 al = *(const bf16x8*)&AlS[cur][((wr * 4 + mi) * 64 + l) * 8];
#pragma unroll
      for (int ni = 0; ni < 2; ni++) {
        const bf16x8 bhf = *(const bf16x8*)(Bhb + ks * (NB * 512) + ni * 512);
        const bf16x8 blf = *(const bf16x8*)(Blb + ks * (NB * 512) + ni * 512);
        acc[mi][ni] = __builtin_amdgcn_mfma_f32_16x16x32_bf16(ah, bhf, acc[mi][ni], 0, 0, 0);
        acc[mi][ni] = __builtin_amdgcn_mfma_f32_16x16x32_bf16(al, bhf, acc[mi][ni], 0, 0, 0);
        acc[mi][ni] = __builtin_amdgcn_mfma_f32_16x16x32_bf16(ah, blf, acc[mi][ni], 0, 0, 0);
      }
    }
    __syncthreads();
  }

  const size_t row0 = (size_t)blockIdx.x * 128 + wr * 64;
  const int col0 = blockIdx.y * 64 + wc * 32;
#pragma unroll
  for (int mi = 0; mi < 4; mi++)
#pragma unroll
    for (int ni = 0; ni < 2; ni++) {
      const int col = col0 + ni * 16 + (l & 15);
      const float bb = BIAS ? bias[col] : 0.f;
#pragma unroll
      for (int rg = 0; rg < 4; rg++) {
        const size_t row = row0 + mi * 16 + (l >> 4) * 4 + rg;
        C[row * N + col] = acc[mi][ni][rg] + bb;
      }
    }
}

// ---------- residual + LayerNorm -> xhat (scale/bias folded into Wq') ----------
__global__ __launch_bounds__(256)
void ln_kernel(const float* __restrict__ xin, const float* __restrict__ res,
               float* __restrict__ xhat)
{
  const int w = threadIdx.x >> 6, l = threadIdx.x & 63;
  const size_t r = (size_t)blockIdx.x * 4 + w;
  const float4 a = *(const float4*)(xin + r * H_ + l * 4);
  const float4 b = *(const float4*)(res + r * H_ + l * 4);
  const float x0 = a.x + b.x, x1 = a.y + b.y, x2 = a.z + b.z, x3 = a.w + b.w;
  const float mu = wsum(x0 + x1 + x2 + x3) * (1.f / H_);
  const float d0 = x0 - mu, d1 = x1 - mu, d2 = x2 - mu, d3 = x3 - mu;
  const float var = wsum(d0 * d0 + d1 * d1 + d2 * d2 + d3 * d3) * (1.f / H_);
  const float isd = 1.f / sqrtf(var + 1e-5f);
  float4 o;
  o.x = d0 * isd; o.y = d1 * isd; o.z = d2 * isd; o.w = d3 * isd;
  *(float4*)(xhat + r * H_ + l * 4) = o;
}

// ---------- h = l2n(hraw); need = softmax(h@Wqt^T + bqt) ----------
__global__ __launch_bounds__(256)
void h_post(const float* __restrict__ hraw, const float* __restrict__ Wqt,
            const float* __restrict__ bqt, float* __restrict__ h, float* __restrict__ need)
{
  __shared__ float wq_s[T_ * H_];
  for (int i = threadIdx.x; i < T_ * H_; i += 256) wq_s[i] = Wqt[i];
  const int w = threadIdx.x >> 6, l = threadIdx.x & 63;
  const size_t r = (size_t)blockIdx.x * 4 + w;
  const float4 v = *(const float4*)(hraw + r * H_ + l * 4);
  const float n = fmaxf(sqrtf(wsum(v.x * v.x + v.y * v.y + v.z * v.z + v.w * v.w)), 1e-12f);
  float4 hn; hn.x = v.x / n; hn.y = v.y / n; hn.z = v.z / n; hn.w = v.w / n;
  *(float4*)(h + r * H_ + l * 4) = hn;
  __syncthreads();
  float mine = 0.f;
  for (int tt = 0; tt < T_; tt++) {
    const float4 p4 = *(const float4*)(wq_s + tt * H_ + l * 4);
    float p = hn.x * p4.x + hn.y * p4.y + hn.z * p4.z + hn.w * p4.w;
    p = wsum(p);
    if (l == tt) mine = p + bqt[l];
  }
  float s = (l < T_) ? mine : -1e30f;
  const float m = wmaxr(s);
  const float e = (l < T_) ? expf(s - m) : 0.f;
  const float su = wsum(e);
  if (l < T_) need[r * T_ + l] = e / su;
}

// ---------- selection step ----------
template<int STEP>
__global__ __launch_bounds__(256)
void score_kernel(const float* __restrict__ h, const float* __restrict__ se,
                  const float* __restrict__ cn, const float* __restrict__ tp,
                  const float* __restrict__ need, const float* __restrict__ clam,
                  float* __restrict__ covered, int* __restrict__ sel,
                  float* __restrict__ chosen, float* __restrict__ logits,
                  float* __restrict__ preds)
{
  __shared__ __align__(16) float hs_s[H_];
  __shared__ float nu_s[T_];
  __shared__ float sc_s[K_];
  __shared__ float rd_s[4];
  __shared__ int idx_s;
  const int b = blockIdx.x, t = threadIdx.x;
  const int w = t >> 6, l = t & 63;

  const float hv = h[(size_t)b * H_ + t] + se[STEP * H_ + t];
  const float ss = wsum(hv * hv);
  if (l == 0) rd_s[w] = ss;
  if (STEP == 1 && t < T_)
    nu_s[t] = need[(size_t)b * T_ + t] * fminf(fmaxf(1.f - covered[(size_t)b * T_ + t], 0.f), 1.f);
  __syncthreads();
  const float n = fmaxf(sqrtf(rd_s[0] + rd_s[1] + rd_s[2] + rd_s[3]), 1e-12f);
  hs_s[t] = hv / n;
  __syncthreads();

  const float lam = log1pf(expf(clam[0]));
  const float4 hf = *(const float4*)(hs_s + l * 4);
#pragma unroll
  for (int cc = 0; cc < 8; cc++) {
    const int c = w * 8 + cc;
    const float4 cv = *(const float4*)(cn + ((size_t)b * K_ + c) * H_ + l * 4);
    float p = cv.x * hf.x + cv.y * hf.y + cv.z * hf.z + cv.w * hf.w;
    p = wsum(p);
    float s = p / 0.1f;
    if (STEP == 1) {
      float g = (l < T_) ? nu_s[l] * tp[((size_t)b * K_ + c) * T_ + l] : 0.f;
      g = wsum(g);
      s += lam * g;
      if (sel[(size_t)b * K_ + c]) s = -100.f;
    }
    if (l == 0) sc_s[c] = s;
  }
  __syncthreads();
  if (w == 0) {
    float s = (l < K_) ? sc_s[l] : -1e30f;
    int bi = (l < K_) ? l : K_;
#pragma unroll
    for (int o = 32; o; o >>= 1) {
      const float s2 = __shfl_xor(s, o);
      const int i2 = __shfl_xor(bi, o);
      if (s2 > s || (s2 == s && i2 < bi)) { s = s2; bi = i2; }
    }
    if (l == 0) idx_s = bi;
  }
  __syncthreads();
  const int idx = idx_s;
  if (t < K_) logits[(size_t)b * (S_ * K_) + STEP * K_ + t] = sc_s[t];
  if (t == 0) preds[(size_t)b * S_ + STEP] = (float)idx;
  if (STEP == 0) {
    if (t < K_) sel[(size_t)b * K_ + t] = (t == idx) ? 1 : 0;
    if (t < T_) covered[(size_t)b * T_ + t] = fminf(tp[((size_t)b * K_ + idx) * T_ + t], 1.f);
    chosen[(size_t)b * H_ + t] = cn[((size_t)b * K_ + idx) * H_ + t];
  }
}

// ---------- GRU gate fusion + l2n, h updated in place ----------
__global__ __launch_bounds__(256)
void gru_kernel(const float* __restrict__ gi, const float* __restrict__ gh, float* __restrict__ h)
{
  __shared__ float rd_s[4];
  const int b = blockIdx.x, t = threadIdx.x, w = t >> 6, l = t & 63;
  const size_t o = (size_t)b * (3 * H_);
  const float ir = gi[o + t], iz = gi[o + 256 + t], ig = gi[o + 512 + t];
  const float hr = gh[o + t], hz = gh[o + 256 + t], hg = gh[o + 512 + t];
  const float hv = h[(size_t)b * H_ + t];
  const float r = 1.f / (1.f + expf(-(ir + hr)));
  const float z = 1.f / (1.f + expf(-(iz + hz)));
  const float nn = tanhf(ig + r * hg);
  const float x = (1.f - z) * nn + z * hv;
  const float ss = wsum(x * x);
  if (l == 0) rd_s[w] = ss;
  __syncthreads();
  const float n = fmaxf(sqrtf(rd_s[0] + rd_s[1] + rd_s[2] + rd_s[3]), 1e-12f);
  h[(size_t)b * H_ + t] = x / n;
}

extern "C" void kernel_launch(void* const* d_in, const int* in_sizes, int n_in,
                              void* d_out, int out_size, void* d_ws, size_t ws_size,
                              hipStream_t stream)
{
  const float* query_emb = (const float*)d_in[0];
  const float* cand_emb  = (const float*)d_in[1];
  const float* W_in = (const float*)d_in[2];
  const float* Wq_a = (const float*)d_in[3];
  const float* Wk_a = (const float*)d_in[4];
  const float* Wv_a = (const float*)d_in[5];
  const float* bq_a = (const float*)d_in[6];
  const float* bk_a = (const float*)d_in[7];
  const float* bv_a = (const float*)d_in[8];
  const float* Wo_a = (const float*)d_in[9];
  const float* bo_a = (const float*)d_in[10];
  const float* ln_w = (const float*)d_in[11];
  const float* ln_b = (const float*)d_in[12];
  const float* Wq   = (const float*)d_in[13];
  const float* Wc   = (const float*)d_in[14];
  const float* W_ih = (const float*)d_in[15];
  const float* W_hh = (const float*)d_in[16];
  const float* b_ih = (const float*)d_in[17];
  const float* b_hh = (const float*)d_in[18];
  const float* step_emb = (const float*)d_in[19];
  const float* tpro = (const float*)d_in[20];
  const float* Wqt  = (const float*)d_in[21];
  const float* bqt  = (const float*)d_in[22];
  const float* clam = (const float*)d_in[23];

  float* ws = (float*)d_ws;
  size_t o = 0;
  float* WkinT = ws + o; o += (size_t)D_ * H_;
  float* Wv_in = ws + o; o += (size_t)H_ * D_;
  ushort* BhW  = (ushort*)(ws + o); o += 98304;   // 24*16*64*8 ushorts
  ushort* BlW  = (ushort*)(ws + o); o += 98304;
  float* pro   = ws + o; o += (size_t)T_ * H_;
  float* Bqk   = ws + o; o += (size_t)D_ * H_;
  float* bqk   = ws + o; o += 1024;
  float* Wvo   = ws + o; o += (size_t)H_ * D_;
  float* bvo   = ws + o; o += 256;
  float* Wqp   = ws + o; o += (size_t)H_ * H_;
  float* bqp   = ws + o; o += 256;
  float* vqbk  = ws + o; o += 256;
  float* qcst  = ws + o; o += 4;
  ushort* WintH = (ushort*)(ws + o); o += 98304;
  ushort* WintL = (ushort*)(ws + o); o += 98304;
  ushort* BqktH = (ushort*)(ws + o); o += 98304;
  ushort* BqktL = (ushort*)(ws + o); o += 98304;
  ushort* WvotH = (ushort*)(ws + o); o += 98304;
  ushort* WvotL = (ushort*)(ws + o); o += 98304;
  ushort* WqptH = (ushort*)(ws + o); o += 32768;
  ushort* WqptL = (ushort*)(ws + o); o += 32768;
  ushort* WihtH = (ushort*)(ws + o); o += 98304;
  ushort* WihtL = (ushort*)(ws + o); o += 98304;
  ushort* WhhtH = (ushort*)(ws + o); o += 98304;
  ushort* WhhtL = (ushort*)(ws + o); o += 98304;
  float* qr    = ws + o; o += (size_t)B_ * H_;
  float* qkv   = ws + o; o += (size_t)B_ * D_;   // later: gi
  float* wce   = ws + o; o += (size_t)B_ * D_;   // later: gh
  float* ctxb  = ws + o; o += (size_t)B_ * H_;   // ctx, later hraw
  float* xhat  = ws + o; o += (size_t)B_ * H_;
  float* h     = ws + o; o += (size_t)B_ * H_;
  float* need  = ws + o; o += (size_t)B_ * T_;
  float* cn    = ws + o; o += (size_t)B_ * K_ * H_;
  float* tp    = ws + o; o += (size_t)B_ * K_ * T_;
  int*   sel   = (int*)(ws + o); o += (size_t)B_ * K_;
  float* cov   = ws + o; o += (size_t)B_ * T_;
  float* chosen= ws + o; o += (size_t)B_ * H_;

  float* out_logits = (float*)d_out;
  float* out_preds  = (float*)d_out + (size_t)B_ * S_ * K_;

  // weight folding + tiling
  fold_kernel<<<dim3(H_, 3), 256, 0, stream>>>(Wk_a, Wv_a, Wc, W_in, WkinT, Wv_in, BhW, BlW);
  proto_kernel<<<1, 256, 0, stream>>>(tpro, pro);
  fold2_kernel<<<D_, 256, 0, stream>>>(Wq_a, bq_a, bk_a, Wo_a, bo_a, bv_a, Wq, ln_w, ln_b,
                                       WkinT, Wv_in, Bqk, bqk, Wvo, bvo, Wqp, bqp, vqbk, qcst);
  TileJobs jobs;
  jobs.j[0] = {W_in, WintH, WintL, 16, 768, 256};
  jobs.j[1] = {Bqk,  BqktH, BqktL, 48, 256, 768};
  jobs.j[2] = {Wvo,  WvotH, WvotL, 16, 768, 256};
  jobs.j[3] = {Wqp,  WqptH, WqptL, 16, 256, 256};
  jobs.j[4] = {W_ih, WihtH, WihtL, 48, 256, 768};
  jobs.j[5] = {W_hh, WhhtH, WhhtL, 48, 256, 768};
  tile_all<<<dim3(768, 6), 256, 0, stream>>>(jobs);

  // query path (all MFMA)
  gemm_bf<24, 16, false><<<dim3(B_ / 128, 4), 256, 0, stream>>>(query_emb, WintH, WintL, nullptr, qr);
  gemm_bf<8, 48, true><<<dim3(B_ / 128, 12), 256, 0, stream>>>(qr, BqktH, BqktL, bqk, qkv);

  // candidate path + fused attention (cn, wce)
  gemm_cn_attn<<<(B_ * K_) / 64, 256, 0, stream>>>(cand_emb, BhW, BlW, qkv, qr, vqbk, qcst, cn, wce);

  gemm_bf<24, 16, true><<<dim3(B_ / 128, 4), 256, 0, stream>>>(wce, WvotH, WvotL, bvo, ctxb);
  ln_kernel<<<B_ / 4, 256, 0, stream>>>(ctxb, qr, xhat);
  gemm_bf<8, 16, true><<<dim3(B_ / 128, 4), 256, 0, stream>>>(xhat, WqptH, WqptL, bqp, ctxb);  // ctxb := hraw
  h_post<<<B_ / 4, 256, 0, stream>>>(ctxb, Wqt, bqt, h, need);

  tp_kernel<<<(B_ * K_) / 16, 256, 0, stream>>>(cn, pro, tp);

  // step 0
  score_kernel<0><<<B_, 256, 0, stream>>>(h, step_emb, cn, tp, need, clam, cov, sel, chosen, out_logits, out_preds);
  // GRU update
  gemm_bf<8, 48, true><<<dim3(B_ / 128, 12), 256, 0, stream>>>(chosen, WihtH, WihtL, b_ih, qkv);  // qkv := gi
  gemm_bf<8, 48, true><<<dim3(B_ / 128, 12), 256, 0, stream>>>(h, WhhtH, WhhtL, b_hh, wce);       // wce := gh
  gru_kernel<<<B_, 256, 0, stream>>>(qkv, wce, h);
  // step 1
  score_kernel<1><<<B_, 256, 0, stream>>>(h, step_emb, cn, tp, need, clam, cov, sel, chosen, out_logits, out_preds);
}

// Round 7
// 892.888 us; speedup vs baseline: 2.8725x; 1.0764x over previous
//
#include <hip/hip_runtime.h>
#include <math.h>

#define B_ 8192
#define K_ 32
#define D_ 768
#define H_ 256
#define T_ 16
#define S_ 2

typedef unsigned int uint;
typedef unsigned short ushort;
typedef __attribute__((ext_vector_type(8))) short bf16x8;
typedef __attribute__((ext_vector_type(4))) float f32x4;

// ---------- wave (64-lane) reductions ----------
__device__ __forceinline__ float wsum(float v) {
  v += __shfl_xor(v, 32); v += __shfl_xor(v, 16); v += __shfl_xor(v, 8);
  v += __shfl_xor(v, 4);  v += __shfl_xor(v, 2);  v += __shfl_xor(v, 1);
  return v;
}
__device__ __forceinline__ float wmaxr(float v) {
  v = fmaxf(v, __shfl_xor(v, 32)); v = fmaxf(v, __shfl_xor(v, 16));
  v = fmaxf(v, __shfl_xor(v, 8));  v = fmaxf(v, __shfl_xor(v, 4));
  v = fmaxf(v, __shfl_xor(v, 2));  v = fmaxf(v, __shfl_xor(v, 1));
  return v;
}

// split fp32 -> (hi bf16 trunc, lo bf16 trunc of exact remainder), packed 2/uint
__device__ __forceinline__ void split4(const float4 f, uint2& h, uint2& lo) {
  const uint ux = __float_as_uint(f.x), uy = __float_as_uint(f.y);
  const uint uz = __float_as_uint(f.z), uw = __float_as_uint(f.w);
  h.x = (uy & 0xFFFF0000u) | (ux >> 16);
  h.y = (uw & 0xFFFF0000u) | (uz >> 16);
  const float rx = f.x - __uint_as_float(ux & 0xFFFF0000u);
  const float ry = f.y - __uint_as_float(uy & 0xFFFF0000u);
  const float rz = f.z - __uint_as_float(uz & 0xFFFF0000u);
  const float rw = f.w - __uint_as_float(uw & 0xFFFF0000u);
  lo.x = (__float_as_uint(ry) & 0xFFFF0000u) | (__float_as_uint(rx) >> 16);
  lo.y = (__float_as_uint(rw) & 0xFFFF0000u) | (__float_as_uint(rz) >> 16);
}

__device__ __forceinline__ float dot4(const float4 a, const float4 b) {
  float s = a.x * b.x;
  s = fmaf(a.y, b.y, s); s = fmaf(a.z, b.z, s); s = fmaf(a.w, b.w, s);
  return s;
}

// B frag tiling (NB = N/16): elem(n,k) -> ((ks*NB + nb)*64 + (nl | kc<<4))*8 + kb
// ks=k>>5, kc=(k>>3)&3, kb=k&7, nb=n>>4, nl=n&15

// ---------- fold stage 1: WkinT fp32, Wv_in fp32, Wc_in -> hi/lo bf16 frag-tiled (NB=16) ----------
__global__ __launch_bounds__(256)
void fold_kernel(const float* __restrict__ Wk_a, const float* __restrict__ Wv_a,
                 const float* __restrict__ Wc,  const float* __restrict__ W_in,
                 float* __restrict__ WkinT, float* __restrict__ Wv_in,
                 ushort* __restrict__ Bh, ushort* __restrict__ Bl)
{
  const int i = blockIdx.x;   // output row 0..255
  const int m = blockIdx.y;   // which matrix
  const float* Wx = (m == 0) ? Wk_a : ((m == 1) ? Wv_a : Wc);
  const int t = threadIdx.x;
  float a0 = 0.f, a1 = 0.f, a2 = 0.f;
  for (int k = 0; k < H_; k++) {
    const float wv = Wx[i * H_ + k];
    const float* row = W_in + (size_t)k * D_;
    a0 = fmaf(wv, row[t], a0);
    a1 = fmaf(wv, row[t + 256], a1);
    a2 = fmaf(wv, row[t + 512], a2);
  }
  if (m == 0) {
    WkinT[(size_t)t * H_ + i] = a0;
    WkinT[(size_t)(t + 256) * H_ + i] = a1;
    WkinT[(size_t)(t + 512) * H_ + i] = a2;
  } else if (m == 1) {
    float* o = Wv_in + (size_t)i * D_;
    o[t] = a0; o[t + 256] = a1; o[t + 512] = a2;
  } else {
    const float vals[3] = {a0, a1, a2};
#pragma unroll
    for (int j = 0; j < 3; j++) {
      const int k = t + j * 256;
      const float v = vals[j];
      const int idx = (((k >> 5) * 16 + (i >> 4)) * 64 + ((i & 15) | (((k >> 3) & 3) << 4))) * 8 + (k & 7);
      const uint u = __float_as_uint(v);
      Bh[idx] = (ushort)(u >> 16);
      const float rr = v - __uint_as_float(u & 0xFFFF0000u);
      Bl[idx] = (ushort)(__float_as_uint(rr) >> 16);
    }
  }
}

// ---------- all weight tilings in one launch ----------
struct TileJob { const float* W; ushort* Bh; ushort* Bl; int NB; int K; int rows; };
struct TileJobs { TileJob j[6]; };

__global__ __launch_bounds__(256)
void tile_all(TileJobs jobs)
{
  const TileJob J = jobs.j[blockIdx.y];
  const int n = blockIdx.x;
  if (n >= J.rows) return;
  const int t = threadIdx.x;
  for (int k = t; k < J.K; k += 256) {
    const float v = J.W[(size_t)n * J.K + k];
    const int idx = (((k >> 5) * J.NB + (n >> 4)) * 64 + ((n & 15) | (((k >> 3) & 3) << 4))) * 8 + (k & 7);
    const uint u = __float_as_uint(v);
    J.Bh[idx] = (ushort)(u >> 16);
    const float rr = v - __uint_as_float(u & 0xFFFF0000u);
    J.Bl[idx] = (ushort)(__float_as_uint(rr) >> 16);
  }
}

// ---------- l2-normalize topic prototypes ----------
__global__ __launch_bounds__(256)
void proto_kernel(const float* __restrict__ tpro, float* __restrict__ pro)
{
  const int w = threadIdx.x >> 6, l = threadIdx.x & 63;
  for (int r = w; r < T_; r += 4) {
    const float4 v = *(const float4*)(tpro + (size_t)r * H_ + l * 4);
    const float n = fmaxf(sqrtf(wsum(v.x * v.x + v.y * v.y + v.z * v.z + v.w * v.w)), 1e-12f);
    float4 o; o.x = v.x / n; o.y = v.y / n; o.z = v.z / n; o.w = v.w / n;
    *(float4*)(pro + (size_t)r * H_ + l * 4) = o;
  }
}

// ---------- fold stage 2: attention/query-path weight folds ----------
__global__ __launch_bounds__(256)
void fold2_kernel(const float* __restrict__ Wq_a, const float* __restrict__ bq_a,
                  const float* __restrict__ bk_a, const float* __restrict__ Wo_a,
                  const float* __restrict__ bo_a, const float* __restrict__ bv_a,
                  const float* __restrict__ Wq,   const float* __restrict__ ln_w,
                  const float* __restrict__ ln_b, const float* __restrict__ WkinT,
                  const float* __restrict__ Wv_in,
                  float* __restrict__ Bqk, float* __restrict__ bqk,
                  float* __restrict__ Wvo, float* __restrict__ bvo,
                  float* __restrict__ Wqp, float* __restrict__ bqp,
                  float* __restrict__ vqbk, float* __restrict__ qcst)
{
  __shared__ float rd_s[4];
  const int n = blockIdx.x, t = threadIdx.x, w = t >> 6, l = t & 63;
  float s = 0.f;
  for (int hh = 0; hh < H_; hh++)
    s = fmaf(Wq_a[hh * H_ + t], WkinT[(size_t)n * H_ + hh], s);
  Bqk[(size_t)n * H_ + t] = s;
  float p = bq_a[t] * WkinT[(size_t)n * H_ + t];
  p = wsum(p);
  if (l == 0) rd_s[w] = p;
  __syncthreads();
  if (t == 0) bqk[n] = rd_s[0] + rd_s[1] + rd_s[2] + rd_s[3];
  if (n < H_) {
    float a0 = 0.f, a1 = 0.f, a2 = 0.f;
    for (int hh = 0; hh < H_; hh++) {
      const float wo = Wo_a[n * H_ + hh];
      const float* rowv = Wv_in + (size_t)hh * D_;
      a0 = fmaf(wo, rowv[t], a0);
      a1 = fmaf(wo, rowv[t + 256], a1);
      a2 = fmaf(wo, rowv[t + 512], a2);
    }
    Wvo[(size_t)n * D_ + t] = a0;
    Wvo[(size_t)n * D_ + t + 256] = a1;
    Wvo[(size_t)n * D_ + t + 512] = a2;
    float pb = Wo_a[n * H_ + t] * bv_a[t];
    pb = wsum(pb);
    __syncthreads();
    if (l == 0) rd_s[w] = pb;
    __syncthreads();
    if (t == 0) bvo[n] = rd_s[0] + rd_s[1] + rd_s[2] + rd_s[3] + bo_a[n];
    Wqp[n * H_ + t] = Wq[n * H_ + t] * ln_w[t];
    float pq = Wq[n * H_ + t] * ln_b[t];
    pq = wsum(pq);
    __syncthreads();
    if (l == 0) rd_s[w] = pq;
    __syncthreads();
    if (t == 0) bqp[n] = rd_s[0] + rd_s[1] + rd_s[2] + rd_s[3];
  }
  if (n == 0) {
    float sv = 0.f;
    for (int hh = 0; hh < H_; hh++) sv = fmaf(bk_a[hh], Wq_a[hh * H_ + t], sv);
    vqbk[t] = sv;
    float pc = bq_a[t] * bk_a[t];
    pc = wsum(pc);
    __syncthreads();
    if (l == 0) rd_s[w] = pc;
    __syncthreads();
    if (t == 0) qcst[0] = rd_s[0] + rd_s[1] + rd_s[2] + rd_s[3];
  }
}

// ---------- fused gemm_cn + cross-attention (v2: low-VGPR, B-hoisted) ----------
// Block = 64 rows = batches {2b, 2b+1}. 256 threads (4 waves, one per 64-col group).
__global__ __launch_bounds__(256, 3)
void gemm_cn_attn(const float* __restrict__ A, const ushort* __restrict__ Bh,
                  const ushort* __restrict__ Bl, const float* __restrict__ qkv,
                  const float* __restrict__ qr, const float* __restrict__ vqbk,
                  const float* __restrict__ qcst, float* __restrict__ C,
                  float* __restrict__ wce)
{
  __shared__ __align__(16) ushort AhS[2][2048], AlS[2][2048];
  __shared__ __align__(16) float4 qkv_s[384];   // 2 batches x 192
  __shared__ float sc_s[64], at_s[64], qbk_s[2];
  __shared__ float rsq[64][4];
  const int t = threadIdx.x, l = t & 63, w = t >> 6;
  const int r = t >> 2, kc = t & 3;             // A staging map: 64 rows x 4 chunks
  const int tb = t >> 7;                        // staging thread's batch (0/1)
  const float* Ag = A + ((size_t)blockIdx.x * 64 + r) * 768 + kc * 8;
  const int aslot = ((r >> 4) * 64 + ((r & 15) | (kc << 4))) * 8;
  const ushort* Bhb = Bh + ((w * 4) * 64 + l) * 8;   // + ks*8192 + ni*512
  const ushort* Blb = Bl + ((w * 4) * 64 + l) * 8;

  // load qkv for both batches into LDS; compute qbk per batch (waves 0,1)
  for (int i = t; i < 384; i += 256)
    qkv_s[i] = ((const float4*)qkv)[(size_t)blockIdx.x * 384 + i];
  if (w < 2) {
    const float4 q4 = ((const float4*)qr)[((size_t)blockIdx.x * 2 + w) * 64 + l];
    const float4 v4 = ((const float4*)vqbk)[l];
    float p = wsum(dot4(q4, v4));
    if (l == 0) qbk_s[w] = p + qcst[0];
  }

  f32x4 acc[4][4];
#pragma unroll
  for (int i = 0; i < 4; i++)
#pragma unroll
    for (int j = 0; j < 4; j++) acc[i][j] = (f32x4)0.f;

  float sc = 0.f;
  // prologue: load A(0), dot with qkv, stage -> buf0, prefetch A(1)
  float4 f0 = *(const float4*)(Ag);
  float4 f1 = *(const float4*)(Ag + 4);
  __syncthreads();  // qkv_s ready
  sc += dot4(f0, qkv_s[tb * 192 + kc * 2]) + dot4(f1, qkv_s[tb * 192 + kc * 2 + 1]);
  {
    uint2 ha, la, hb, lb;
    split4(f0, ha, la); split4(f1, hb, lb);
    *(uint4*)&AhS[0][aslot] = make_uint4(ha.x, ha.y, hb.x, hb.y);
    *(uint4*)&AlS[0][aslot] = make_uint4(la.x, la.y, lb.x, lb.y);
  }
  f0 = *(const float4*)(Ag + 32);
  f1 = *(const float4*)(Ag + 36);
  __syncthreads();

#pragma unroll 2
  for (int ks = 0; ks < 24; ks++) {
    const int cur = ks & 1;
    // B(ks) loads issued first; A-stage VALU below covers their L2 latency
    uint4 bhv[4], blv[4];
#pragma unroll
    for (int ni = 0; ni < 4; ni++) {
      bhv[ni] = *(const uint4*)(Bhb + ks * 8192 + ni * 512);
      blv[ni] = *(const uint4*)(Blb + ks * 8192 + ni * 512);
    }
    // stage A(ks+1): score-dot + split into the other buffer; prefetch A(ks+2)
    if (ks < 23) {
      sc += dot4(f0, qkv_s[tb * 192 + (ks + 1) * 8 + kc * 2]) +
            dot4(f1, qkv_s[tb * 192 + (ks + 1) * 8 + kc * 2 + 1]);
      uint2 ha, la, hb, lb;
      split4(f0, ha, la); split4(f1, hb, lb);
      *(uint4*)&AhS[cur ^ 1][aslot] = make_uint4(ha.x, ha.y, hb.x, hb.y);
      *(uint4*)&AlS[cur ^ 1][aslot] = make_uint4(la.x, la.y, lb.x, lb.y);
      if (ks < 22) {
        f0 = *(const float4*)(Ag + (ks + 2) * 32);
        f1 = *(const float4*)(Ag + (ks + 2) * 32 + 4);
      }
    }
    // MFMA: A frags read per-mi (low register pressure)
#pragma unroll
    for (int mi = 0; mi < 4; mi++) {
      const bf16x8 ah = *(const bf16x8*)&AhS[cur][(mi * 64 + l) * 8];
      const bf16x8 al = *(const bf16x8*)&AlS[cur][(mi * 64 + l) * 8];
#pragma unroll
      for (int ni = 0; ni < 4; ni++) {
        const bf16x8 bhf = *(const bf16x8*)&bhv[ni];
        const bf16x8 blf = *(const bf16x8*)&blv[ni];
        acc[mi][ni] = __builtin_amdgcn_mfma_f32_16x16x32_bf16(ah, bhf, acc[mi][ni], 0, 0, 0);
        acc[mi][ni] = __builtin_amdgcn_mfma_f32_16x16x32_bf16(al, bhf, acc[mi][ni], 0, 0, 0);
        acc[mi][ni] = __builtin_amdgcn_mfma_f32_16x16x32_bf16(ah, blf, acc[mi][ni], 0, 0, 0);
      }
    }
    __syncthreads();  // ds ordering only; global loads stay in flight
  }

  // ---- attention: reduce scores over kc, softmax per batch, PV ----
  sc += __shfl_xor(sc, 1);
  sc += __shfl_xor(sc, 2);
  if ((t & 3) == 0) sc_s[r] = sc;
  __syncthreads();
  if (w < 2) {  // wave w handles batch w
    float s = (l < 32) ? (sc_s[w * 32 + l] + qbk_s[w]) * (1.f / 16.f) : -1e30f;
    const float m = wmaxr(s);
    const float e = (l < 32) ? expf(s - m) : 0.f;
    const float su = wsum(e);
    if (l < 32) at_s[w * 32 + l] = e / su;
  }
  __syncthreads();
  // PV: 384 float4 slots (2 batches x 192); ce re-read is L3-served
#pragma unroll
  for (int p = 0; p < 2; p++) {
    const int slot = t + p * 256;
    if (slot < 384) {
      const int tb2 = slot >= 192;
      const int idx = slot - tb2 * 192;
      const float4* cb = (const float4*)A + ((size_t)blockIdx.x * 64 + tb2 * 32) * 192 + idx;
      float4 a = make_float4(0.f, 0.f, 0.f, 0.f);
#pragma unroll 4
      for (int c = 0; c < 32; c++) {
        const float av = at_s[tb2 * 32 + c];
        const float4 f = cb[c * 192];
        a.x = fmaf(av, f.x, a.x); a.y = fmaf(av, f.y, a.y);
        a.z = fmaf(av, f.z, a.z); a.w = fmaf(av, f.w, a.w);
      }
      ((float4*)wce)[((size_t)blockIdx.x * 2 + tb2) * 192 + idx] = a;
    }
  }

  // ---- fused epilogue: l2n + write cn ----
#pragma unroll
  for (int mi = 0; mi < 4; mi++)
#pragma unroll
    for (int rg = 0; rg < 4; rg++) {
      float p = 0.f;
#pragma unroll
      for (int ni = 0; ni < 4; ni++) { const float v = acc[mi][ni][rg]; p = fmaf(v, v, p); }
      p += __shfl_xor(p, 1); p += __shfl_xor(p, 2); p += __shfl_xor(p, 4); p += __shfl_xor(p, 8);
      if ((l & 15) == 0) rsq[mi * 16 + (l >> 4) * 4 + rg][w] = p;
    }
  __syncthreads();
  const size_t row0 = (size_t)blockIdx.x * 64;
#pragma unroll
  for (int mi = 0; mi < 4; mi++)
#pragma unroll
    for (int rg = 0; rg < 4; rg++) {
      const int rl = mi * 16 + (l >> 4) * 4 + rg;
      const float ssum = rsq[rl][0] + rsq[rl][1] + rsq[rl][2] + rsq[rl][3];
      const float inv = 1.f / fmaxf(sqrtf(ssum), 1e-12f);
#pragma unroll
      for (int ni = 0; ni < 4; ni++)
        C[(row0 + rl) * H_ + w * 64 + ni * 16 + (l & 15)] = acc[mi][ni][rg] * inv;
    }
}

// ---------- tp = softmax(cn . pro^T) over topics ----------
__global__ __launch_bounds__(256)
void tp_kernel(const float* __restrict__ cn, const float* __restrict__ pro,
               float* __restrict__ tp)
{
  __shared__ float cn_s[16][260];
  __shared__ float pro_s[16][260];
  const int t = threadIdx.x;
  const size_t row0 = (size_t)blockIdx.x * 16;
  const int sr = t >> 4;
#pragma unroll
  for (int j = 0; j < 4; j++) {
    const int c = (t & 15) * 4 + j * 64;
    *(float4*)&cn_s[sr][c] = *(const float4*)(cn + (row0 + sr) * H_ + c);
    *(float4*)&pro_s[sr][c] = *(const float4*)(pro + sr * H_ + c);
  }
  __syncthreads();
  const int r = t >> 4, tt = t & 15;
  float d = 0.f;
#pragma unroll 8
  for (int j = 0; j < 64; j++) {
    const float4 a = *(const float4*)&cn_s[r][j * 4];
    const float4 p = *(const float4*)&pro_s[tt][j * 4];
    d = fmaf(a.x, p.x, d); d = fmaf(a.y, p.y, d);
    d = fmaf(a.z, p.z, d); d = fmaf(a.w, p.w, d);
  }
  float m = d;
  m = fmaxf(m, __shfl_xor(m, 1)); m = fmaxf(m, __shfl_xor(m, 2));
  m = fmaxf(m, __shfl_xor(m, 4)); m = fmaxf(m, __shfl_xor(m, 8));
  const float e = expf(d - m);
  float su = e;
  su += __shfl_xor(su, 1); su += __shfl_xor(su, 2);
  su += __shfl_xor(su, 4); su += __shfl_xor(su, 8);
  tp[(row0 + r) * T_ + tt] = e / su;
}

// ---------- generic split-bf16 MFMA GEMM: C[M,N] = A[M,K]*B^T (+bias), B pre-tiled ----------
template<int NKS, int NB, bool BIAS>
__global__ __launch_bounds__(256)
void gemm_bf(const float* __restrict__ A, const ushort* __restrict__ Bh,
             const ushort* __restrict__ Bl, const float* __restrict__ bias,
             float* __restrict__ C)
{
  __shared__ __align__(16) ushort AhS[2][4096], AlS[2][4096];
  const int t = threadIdx.x, l = t & 63, w = t >> 6;
  const int wr = w >> 1, wc = w & 1;
  const int Kd = NKS * 32, N = NB * 16;
  const int r = t >> 1, kc0 = (t & 1) * 2;
  const float* Ag = A + ((size_t)blockIdx.x * 128 + r) * Kd + kc0 * 8;
  const int aslot0 = ((r >> 4) * 64 + ((r & 15) | (kc0 << 4))) * 8;
  const int aslot1 = aslot0 + 128;
  const int nb0 = blockIdx.y * 4 + wc * 2;
  const ushort* Bhb = Bh + (nb0 * 64 + l) * 8;
  const ushort* Blb = Bl + (nb0 * 64 + l) * 8;

  f32x4 acc[4][2];
#pragma unroll
  for (int i = 0; i < 4; i++)
#pragma unroll
    for (int j = 0; j < 2; j++) acc[i][j] = (f32x4)0.f;

  float4 f0 = *(const float4*)(Ag);
  float4 f1 = *(const float4*)(Ag + 4);
  float4 f2 = *(const float4*)(Ag + 8);
  float4 f3 = *(const float4*)(Ag + 12);
  {
    uint2 ha, la, hb, lb;
    split4(f0, ha, la); split4(f1, hb, lb);
    *(uint4*)&AhS[0][aslot0] = make_uint4(ha.x, ha.y, hb.x, hb.y);
    *(uint4*)&AlS[0][aslot0] = make_uint4(la.x, la.y, lb.x, lb.y);
    split4(f2, ha, la); split4(f3, hb, lb);
    *(uint4*)&AhS[0][aslot1] = make_uint4(ha.x, ha.y, hb.x, hb.y);
    *(uint4*)&AlS[0][aslot1] = make_uint4(la.x, la.y, lb.x, lb.y);
  }
  f0 = *(const float4*)(Ag + 32); f1 = *(const float4*)(Ag + 36);
  f2 = *(const float4*)(Ag + 40); f3 = *(const float4*)(Ag + 44);
  __syncthreads();

#pragma unroll 2
  for (int ks = 0; ks < NKS; ks++) {
    const int cur = ks & 1;
    if (ks < NKS - 1) {
      uint2 ha, la, hb, lb;
      split4(f0, ha, la); split4(f1, hb, lb);
      *(uint4*)&AhS[cur ^ 1][aslot0] = make_uint4(ha.x, ha.y, hb.x, hb.y);
      *(uint4*)&AlS[cur ^ 1][aslot0] = make_uint4(la.x, la.y, lb.x, lb.y);
      split4(f2, ha, la); split4(f3, hb, lb);
      *(uint4*)&AhS[cur ^ 1][aslot1] = make_uint4(ha.x, ha.y, hb.x, hb.y);
      *(uint4*)&AlS[cur ^ 1][aslot1] = make_uint4(la.x, la.y, lb.x, lb.y);
      if (ks < NKS - 2) {
        f0 = *(const float4*)(Ag + (ks + 2) * 32);
        f1 = *(const float4*)(Ag + (ks + 2) * 32 + 4);
        f2 = *(const float4*)(Ag + (ks + 2) * 32 + 8);
        f3 = *(const float4*)(Ag + (ks + 2) * 32 + 12);
      }
    }
#pragma unroll
    for (int mi = 0; mi < 4; mi++) {
      const bf16x8 ah = *(const bf16x8*)&AhS[cur][((wr * 4 + mi) * 64 + l) * 8];
      const bf16x8 al = *(const bf16x8*)&AlS[cur][((wr * 4 + mi) * 64 + l) * 8];
#pragma unroll
      for (int ni = 0; ni < 2; ni++) {
        const bf16x8 bhf = *(const bf16x8*)(Bhb + ks * (NB * 512) + ni * 512);
        const bf16x8 blf = *(const bf16x8*)(Blb + ks * (NB * 512) + ni * 512);
        acc[mi][ni] = __builtin_amdgcn_mfma_f32_16x16x32_bf16(ah, bhf, acc[mi][ni], 0, 0, 0);
        acc[mi][ni] = __builtin_amdgcn_mfma_f32_16x16x32_bf16(al, bhf, acc[mi][ni], 0, 0, 0);
        acc[mi][ni] = __builtin_amdgcn_mfma_f32_16x16x32_bf16(ah, blf, acc[mi][ni], 0, 0, 0);
      }
    }
    __syncthreads();
  }

  const size_t row0 = (size_t)blockIdx.x * 128 + wr * 64;
  const int col0 = blockIdx.y * 64 + wc * 32;
#pragma unroll
  for (int mi = 0; mi < 4; mi++)
#pragma unroll
    for (int ni = 0; ni < 2; ni++) {
      const int col = col0 + ni * 16 + (l & 15);
      const float bb = BIAS ? bias[col] : 0.f;
#pragma unroll
      for (int rg = 0; rg < 4; rg++) {
        const size_t row = row0 + mi * 16 + (l >> 4) * 4 + rg;
        C[row * N + col] = acc[mi][ni][rg] + bb;
      }
    }
}

// ---------- residual + LayerNorm -> xhat (scale/bias folded into Wq') ----------
__global__ __launch_bounds__(256)
void ln_kernel(const float* __restrict__ xin, const float* __restrict__ res,
               float* __restrict__ xhat)
{
  const int w = threadIdx.x >> 6, l = threadIdx.x & 63;
  const size_t r = (size_t)blockIdx.x * 4 + w;
  const float4 a = *(const float4*)(xin + r * H_ + l * 4);
  const float4 b = *(const float4*)(res + r * H_ + l * 4);
  const float x0 = a.x + b.x, x1 = a.y + b.y, x2 = a.z + b.z, x3 = a.w + b.w;
  const float mu = wsum(x0 + x1 + x2 + x3) * (1.f / H_);
  const float d0 = x0 - mu, d1 = x1 - mu, d2 = x2 - mu, d3 = x3 - mu;
  const float var = wsum(d0 * d0 + d1 * d1 + d2 * d2 + d3 * d3) * (1.f / H_);
  const float isd = 1.f / sqrtf(var + 1e-5f);
  float4 o;
  o.x = d0 * isd; o.y = d1 * isd; o.z = d2 * isd; o.w = d3 * isd;
  *(float4*)(xhat + r * H_ + l * 4) = o;
}

// ---------- h = l2n(hraw); need = softmax(h@Wqt^T + bqt) ----------
__global__ __launch_bounds__(256)
void h_post(const float* __restrict__ hraw, const float* __restrict__ Wqt,
            const float* __restrict__ bqt, float* __restrict__ h, float* __restrict__ need)
{
  __shared__ float wq_s[T_ * H_];
  for (int i = threadIdx.x; i < T_ * H_; i += 256) wq_s[i] = Wqt[i];
  const int w = threadIdx.x >> 6, l = threadIdx.x & 63;
  const size_t r = (size_t)blockIdx.x * 4 + w;
  const float4 v = *(const float4*)(hraw + r * H_ + l * 4);
  const float n = fmaxf(sqrtf(wsum(v.x * v.x + v.y * v.y + v.z * v.z + v.w * v.w)), 1e-12f);
  float4 hn; hn.x = v.x / n; hn.y = v.y / n; hn.z = v.z / n; hn.w = v.w / n;
  *(float4*)(h + r * H_ + l * 4) = hn;
  __syncthreads();
  float mine = 0.f;
  for (int tt = 0; tt < T_; tt++) {
    const float4 p4 = *(const float4*)(wq_s + tt * H_ + l * 4);
    float p = hn.x * p4.x + hn.y * p4.y + hn.z * p4.z + hn.w * p4.w;
    p = wsum(p);
    if (l == tt) mine = p + bqt[l];
  }
  float s = (l < T_) ? mine : -1e30f;
  const float m = wmaxr(s);
  const float e = (l < T_) ? expf(s - m) : 0.f;
  const float su = wsum(e);
  if (l < T_) need[r * T_ + l] = e / su;
}

// ---------- selection step ----------
template<int STEP>
__global__ __launch_bounds__(256)
void score_kernel(const float* __restrict__ h, const float* __restrict__ se,
                  const float* __restrict__ cn, const float* __restrict__ tp,
                  const float* __restrict__ need, const float* __restrict__ clam,
                  float* __restrict__ covered, int* __restrict__ sel,
                  float* __restrict__ chosen, float* __restrict__ logits,
                  float* __restrict__ preds)
{
  __shared__ __align__(16) float hs_s[H_];
  __shared__ float nu_s[T_];
  __shared__ float sc_s[K_];
  __shared__ float rd_s[4];
  __shared__ int idx_s;
  const int b = blockIdx.x, t = threadIdx.x;
  const int w = t >> 6, l = t & 63;

  const float hv = h[(size_t)b * H_ + t] + se[STEP * H_ + t];
  const float ss = wsum(hv * hv);
  if (l == 0) rd_s[w] = ss;
  if (STEP == 1 && t < T_)
    nu_s[t] = need[(size_t)b * T_ + t] * fminf(fmaxf(1.f - covered[(size_t)b * T_ + t], 0.f), 1.f);
  __syncthreads();
  const float n = fmaxf(sqrtf(rd_s[0] + rd_s[1] + rd_s[2] + rd_s[3]), 1e-12f);
  hs_s[t] = hv / n;
  __syncthreads();

  const float lam = log1pf(expf(clam[0]));
  const float4 hf = *(const float4*)(hs_s + l * 4);
#pragma unroll
  for (int cc = 0; cc < 8; cc++) {
    const int c = w * 8 + cc;
    const float4 cv = *(const float4*)(cn + ((size_t)b * K_ + c) * H_ + l * 4);
    float p = cv.x * hf.x + cv.y * hf.y + cv.z * hf.z + cv.w * hf.w;
    p = wsum(p);
    float s = p / 0.1f;
    if (STEP == 1) {
      float g = (l < T_) ? nu_s[l] * tp[((size_t)b * K_ + c) * T_ + l] : 0.f;
      g = wsum(g);
      s += lam * g;
      if (sel[(size_t)b * K_ + c]) s = -100.f;
    }
    if (l == 0) sc_s[c] = s;
  }
  __syncthreads();
  if (w == 0) {
    float s = (l < K_) ? sc_s[l] : -1e30f;
    int bi = (l < K_) ? l : K_;
#pragma unroll
    for (int o = 32; o; o >>= 1) {
      const float s2 = __shfl_xor(s, o);
      const int i2 = __shfl_xor(bi, o);
      if (s2 > s || (s2 == s && i2 < bi)) { s = s2; bi = i2; }
    }
    if (l == 0) idx_s = bi;
  }
  __syncthreads();
  const int idx = idx_s;
  if (t < K_) logits[(size_t)b * (S_ * K_) + STEP * K_ + t] = sc_s[t];
  if (t == 0) preds[(size_t)b * S_ + STEP] = (float)idx;
  if (STEP == 0) {
    if (t < K_) sel[(size_t)b * K_ + t] = (t == idx) ? 1 : 0;
    if (t < T_) covered[(size_t)b * T_ + t] = fminf(tp[((size_t)b * K_ + idx) * T_ + t], 1.f);
    chosen[(size_t)b * H_ + t] = cn[((size_t)b * K_ + idx) * H_ + t];
  }
}

// ---------- GRU gate fusion + l2n, h updated in place ----------
__global__ __launch_bounds__(256)
void gru_kernel(const float* __restrict__ gi, const float* __restrict__ gh, float* __restrict__ h)
{
  __shared__ float rd_s[4];
  const int b = blockIdx.x, t = threadIdx.x, w = t >> 6, l = t & 63;
  const size_t o = (size_t)b * (3 * H_);
  const float ir = gi[o + t], iz = gi[o + 256 + t], ig = gi[o + 512 + t];
  const float hr = gh[o + t], hz = gh[o + 256 + t], hg = gh[o + 512 + t];
  const float hv = h[(size_t)b * H_ + t];
  const float r = 1.f / (1.f + expf(-(ir + hr)));
  const float z = 1.f / (1.f + expf(-(iz + hz)));
  const float nn = tanhf(ig + r * hg);
  const float x = (1.f - z) * nn + z * hv;
  const float ss = wsum(x * x);
  if (l == 0) rd_s[w] = ss;
  __syncthreads();
  const float n = fmaxf(sqrtf(rd_s[0] + rd_s[1] + rd_s[2] + rd_s[3]), 1e-12f);
  h[(size_t)b * H_ + t] = x / n;
}

extern "C" void kernel_launch(void* const* d_in, const int* in_sizes, int n_in,
                              void* d_out, int out_size, void* d_ws, size_t ws_size,
                              hipStream_t stream)
{
  const float* query_emb = (const float*)d_in[0];
  const float* cand_emb  = (const float*)d_in[1];
  const float* W_in = (const float*)d_in[2];
  const float* Wq_a = (const float*)d_in[3];
  const float* Wk_a = (const float*)d_in[4];
  const float* Wv_a = (const float*)d_in[5];
  const float* bq_a = (const float*)d_in[6];
  const float* bk_a = (const float*)d_in[7];
  const float* bv_a = (const float*)d_in[8];
  const float* Wo_a = (const float*)d_in[9];
  const float* bo_a = (const float*)d_in[10];
  const float* ln_w = (const float*)d_in[11];
  const float* ln_b = (const float*)d_in[12];
  const float* Wq   = (const float*)d_in[13];
  const float* Wc   = (const float*)d_in[14];
  const float* W_ih = (const float*)d_in[15];
  const float* W_hh = (const float*)d_in[16];
  const float* b_ih = (const float*)d_in[17];
  const float* b_hh = (const float*)d_in[18];
  const float* step_emb = (const float*)d_in[19];
  const float* tpro = (const float*)d_in[20];
  const float* Wqt  = (const float*)d_in[21];
  const float* bqt  = (const float*)d_in[22];
  const float* clam = (const float*)d_in[23];

  float* ws = (float*)d_ws;
  size_t o = 0;
  float* WkinT = ws + o; o += (size_t)D_ * H_;
  float* Wv_in = ws + o; o += (size_t)H_ * D_;
  ushort* BhW  = (ushort*)(ws + o); o += 98304;   // 24*16*64*8 ushorts
  ushort* BlW  = (ushort*)(ws + o); o += 98304;
  float* pro   = ws + o; o += (size_t)T_ * H_;
  float* Bqk   = ws + o; o += (size_t)D_ * H_;
  float* bqk   = ws + o; o += 1024;
  float* Wvo   = ws + o; o += (size_t)H_ * D_;
  float* bvo   = ws + o; o += 256;
  float* Wqp   = ws + o; o += (size_t)H_ * H_;
  float* bqp   = ws + o; o += 256;
  float* vqbk  = ws + o; o += 256;
  float* qcst  = ws + o; o += 4;
  ushort* WintH = (ushort*)(ws + o); o += 98304;
  ushort* WintL = (ushort*)(ws + o); o += 98304;
  ushort* BqktH = (ushort*)(ws + o); o += 98304;
  ushort* BqktL = (ushort*)(ws + o); o += 98304;
  ushort* WvotH = (ushort*)(ws + o); o += 98304;
  ushort* WvotL = (ushort*)(ws + o); o += 98304;
  ushort* WqptH = (ushort*)(ws + o); o += 32768;
  ushort* WqptL = (ushort*)(ws + o); o += 32768;
  ushort* WihtH = (ushort*)(ws + o); o += 98304;
  ushort* WihtL = (ushort*)(ws + o); o += 98304;
  ushort* WhhtH = (ushort*)(ws + o); o += 98304;
  ushort* WhhtL = (ushort*)(ws + o); o += 98304;
  float* qr    = ws + o; o += (size_t)B_ * H_;
  float* qkv   = ws + o; o += (size_t)B_ * D_;   // later: gi
  float* wce   = ws + o; o += (size_t)B_ * D_;   // later: gh
  float* ctxb  = ws + o; o += (size_t)B_ * H_;   // ctx, later hraw
  float* xhat  = ws + o; o += (size_t)B_ * H_;
  float* h     = ws + o; o += (size_t)B_ * H_;
  float* need  = ws + o; o += (size_t)B_ * T_;
  float* cn    = ws + o; o += (size_t)B_ * K_ * H_;
  float* tp    = ws + o; o += (size_t)B_ * K_ * T_;
  int*   sel   = (int*)(ws + o); o += (size_t)B_ * K_;
  float* cov   = ws + o; o += (size_t)B_ * T_;
  float* chosen= ws + o; o += (size_t)B_ * H_;

  float* out_logits = (float*)d_out;
  float* out_preds  = (float*)d_out + (size_t)B_ * S_ * K_;

  // weight folding + tiling
  fold_kernel<<<dim3(H_, 3), 256, 0, stream>>>(Wk_a, Wv_a, Wc, W_in, WkinT, Wv_in, BhW, BlW);
  proto_kernel<<<1, 256, 0, stream>>>(tpro, pro);
  fold2_kernel<<<D_, 256, 0, stream>>>(Wq_a, bq_a, bk_a, Wo_a, bo_a, bv_a, Wq, ln_w, ln_b,
                                       WkinT, Wv_in, Bqk, bqk, Wvo, bvo, Wqp, bqp, vqbk, qcst);
  TileJobs jobs;
  jobs.j[0] = {W_in, WintH, WintL, 16, 768, 256};
  jobs.j[1] = {Bqk,  BqktH, BqktL, 48, 256, 768};
  jobs.j[2] = {Wvo,  WvotH, WvotL, 16, 768, 256};
  jobs.j[3] = {Wqp,  WqptH, WqptL, 16, 256, 256};
  jobs.j[4] = {W_ih, WihtH, WihtL, 48, 256, 768};
  jobs.j[5] = {W_hh, WhhtH, WhhtL, 48, 256, 768};
  tile_all<<<dim3(768, 6), 256, 0, stream>>>(jobs);

  // query path (all MFMA)
  gemm_bf<24, 16, false><<<dim3(B_ / 128, 4), 256, 0, stream>>>(query_emb, WintH, WintL, nullptr, qr);
  gemm_bf<8, 48, true><<<dim3(B_ / 128, 12), 256, 0, stream>>>(qr, BqktH, BqktL, bqk, qkv);

  // candidate path + fused attention (cn, wce)
  gemm_cn_attn<<<(B_ * K_) / 64, 256, 0, stream>>>(cand_emb, BhW, BlW, qkv, qr, vqbk, qcst, cn, wce);

  gemm_bf<24, 16, true><<<dim3(B_ / 128, 4), 256, 0, stream>>>(wce, WvotH, WvotL, bvo, ctxb);
  ln_kernel<<<B_ / 4, 256, 0, stream>>>(ctxb, qr, xhat);
  gemm_bf<8, 16, true><<<dim3(B_ / 128, 4), 256, 0, stream>>>(xhat, WqptH, WqptL, bqp, ctxb);  // ctxb := hraw
  h_post<<<B_ / 4, 256, 0, stream>>>(ctxb, Wqt, bqt, h, need);

  tp_kernel<<<(B_ * K_) / 16, 256, 0, stream>>>(cn, pro, tp);

  // step 0
  score_kernel<0><<<B_, 256, 0, stream>>>(h, step_emb, cn, tp, need, clam, cov, sel, chosen, out_logits, out_preds);
  // GRU update
  gemm_bf<8, 48, true><<<dim3(B_ / 128, 12), 256, 0, stream>>>(chosen, WihtH, WihtL, b_ih, qkv);  // qkv := gi
  gemm_bf<8, 48, true><<<dim3(B_ / 128, 12), 256, 0, stream>>>(h, WhhtH, WhhtL, b_hh, wce);       // wce := gh
  gru_kernel<<<B_, 256, 0, stream>>>(qkv, wce, h);
  // step 1
  score_kernel<1><<<B_, 256, 0, stream>>>(h, step_emb, cn, tp, need, clam, cov, sel, chosen, out_logits, out_preds);
}

// Round 8
// 882.703 us; speedup vs baseline: 2.9056x; 1.0115x over previous
//
#include <hip/hip_runtime.h>
#include <math.h>

#define B_ 8192
#define K_ 32
#define D_ 768
#define H_ 256
#define T_ 16
#define S_ 2

typedef unsigned int uint;
typedef unsigned short ushort;
typedef __attribute__((ext_vector_type(8))) short bf16x8;
typedef __attribute__((ext_vector_type(4))) float f32x4;

// ---------- wave (64-lane) reductions ----------
__device__ __forceinline__ float wsum(float v) {
  v += __shfl_xor(v, 32); v += __shfl_xor(v, 16); v += __shfl_xor(v, 8);
  v += __shfl_xor(v, 4);  v += __shfl_xor(v, 2);  v += __shfl_xor(v, 1);
  return v;
}
__device__ __forceinline__ float wmaxr(float v) {
  v = fmaxf(v, __shfl_xor(v, 32)); v = fmaxf(v, __shfl_xor(v, 16));
  v = fmaxf(v, __shfl_xor(v, 8));  v = fmaxf(v, __shfl_xor(v, 4));
  v = fmaxf(v, __shfl_xor(v, 2));  v = fmaxf(v, __shfl_xor(v, 1));
  return v;
}

// split fp32 -> (hi bf16 trunc, lo bf16 trunc of exact remainder), packed 2/uint
__device__ __forceinline__ void split4(const float4 f, uint2& h, uint2& lo) {
  const uint ux = __float_as_uint(f.x), uy = __float_as_uint(f.y);
  const uint uz = __float_as_uint(f.z), uw = __float_as_uint(f.w);
  h.x = (uy & 0xFFFF0000u) | (ux >> 16);
  h.y = (uw & 0xFFFF0000u) | (uz >> 16);
  const float rx = f.x - __uint_as_float(ux & 0xFFFF0000u);
  const float ry = f.y - __uint_as_float(uy & 0xFFFF0000u);
  const float rz = f.z - __uint_as_float(uz & 0xFFFF0000u);
  const float rw = f.w - __uint_as_float(uw & 0xFFFF0000u);
  lo.x = (__float_as_uint(ry) & 0xFFFF0000u) | (__float_as_uint(rx) >> 16);
  lo.y = (__float_as_uint(rw) & 0xFFFF0000u) | (__float_as_uint(rz) >> 16);
}

__device__ __forceinline__ float dot4(const float4 a, const float4 b) {
  float s = a.x * b.x;
  s = fmaf(a.y, b.y, s); s = fmaf(a.z, b.z, s); s = fmaf(a.w, b.w, s);
  return s;
}

// B frag tiling (NB = N/16): elem(n,k) -> ((ks*NB + nb)*64 + (nl | kc<<4))*8 + kb

// ---------- fold stage 1: WkinT fp32, Wv_in fp32, Wc_in -> hi/lo bf16 frag-tiled (NB=16) ----------
__global__ __launch_bounds__(256)
void fold_kernel(const float* __restrict__ Wk_a, const float* __restrict__ Wv_a,
                 const float* __restrict__ Wc,  const float* __restrict__ W_in,
                 float* __restrict__ WkinT, float* __restrict__ Wv_in,
                 ushort* __restrict__ Bh, ushort* __restrict__ Bl)
{
  const int i = blockIdx.x;
  const int m = blockIdx.y;
  const float* Wx = (m == 0) ? Wk_a : ((m == 1) ? Wv_a : Wc);
  const int t = threadIdx.x;
  float a0 = 0.f, a1 = 0.f, a2 = 0.f;
  for (int k = 0; k < H_; k++) {
    const float wv = Wx[i * H_ + k];
    const float* row = W_in + (size_t)k * D_;
    a0 = fmaf(wv, row[t], a0);
    a1 = fmaf(wv, row[t + 256], a1);
    a2 = fmaf(wv, row[t + 512], a2);
  }
  if (m == 0) {
    WkinT[(size_t)t * H_ + i] = a0;
    WkinT[(size_t)(t + 256) * H_ + i] = a1;
    WkinT[(size_t)(t + 512) * H_ + i] = a2;
  } else if (m == 1) {
    float* o = Wv_in + (size_t)i * D_;
    o[t] = a0; o[t + 256] = a1; o[t + 512] = a2;
  } else {
    const float vals[3] = {a0, a1, a2};
#pragma unroll
    for (int j = 0; j < 3; j++) {
      const int k = t + j * 256;
      const float v = vals[j];
      const int idx = (((k >> 5) * 16 + (i >> 4)) * 64 + ((i & 15) | (((k >> 3) & 3) << 4))) * 8 + (k & 7);
      const uint u = __float_as_uint(v);
      Bh[idx] = (ushort)(u >> 16);
      const float rr = v - __uint_as_float(u & 0xFFFF0000u);
      Bl[idx] = (ushort)(__float_as_uint(rr) >> 16);
    }
  }
}

// ---------- all weight tilings in one launch ----------
struct TileJob { const float* W; ushort* Bh; ushort* Bl; int NB; int K; int rows; };
struct TileJobs { TileJob j[6]; };

__global__ __launch_bounds__(256)
void tile_all(TileJobs jobs)
{
  const TileJob J = jobs.j[blockIdx.y];
  const int n = blockIdx.x;
  if (n >= J.rows) return;
  const int t = threadIdx.x;
  for (int k = t; k < J.K; k += 256) {
    const float v = J.W[(size_t)n * J.K + k];
    const int idx = (((k >> 5) * J.NB + (n >> 4)) * 64 + ((n & 15) | (((k >> 3) & 3) << 4))) * 8 + (k & 7);
    const uint u = __float_as_uint(v);
    J.Bh[idx] = (ushort)(u >> 16);
    const float rr = v - __uint_as_float(u & 0xFFFF0000u);
    J.Bl[idx] = (ushort)(__float_as_uint(rr) >> 16);
  }
}

// ---------- l2-normalize topic prototypes ----------
__global__ __launch_bounds__(256)
void proto_kernel(const float* __restrict__ tpro, float* __restrict__ pro)
{
  const int w = threadIdx.x >> 6, l = threadIdx.x & 63;
  for (int r = w; r < T_; r += 4) {
    const float4 v = *(const float4*)(tpro + (size_t)r * H_ + l * 4);
    const float n = fmaxf(sqrtf(wsum(v.x * v.x + v.y * v.y + v.z * v.z + v.w * v.w)), 1e-12f);
    float4 o; o.x = v.x / n; o.y = v.y / n; o.z = v.z / n; o.w = v.w / n;
    *(float4*)(pro + (size_t)r * H_ + l * 4) = o;
  }
}

// ---------- fold stage 2: attention/query-path weight folds ----------
__global__ __launch_bounds__(256)
void fold2_kernel(const float* __restrict__ Wq_a, const float* __restrict__ bq_a,
                  const float* __restrict__ bk_a, const float* __restrict__ Wo_a,
                  const float* __restrict__ bo_a, const float* __restrict__ bv_a,
                  const float* __restrict__ Wq,   const float* __restrict__ ln_w,
                  const float* __restrict__ ln_b, const float* __restrict__ WkinT,
                  const float* __restrict__ Wv_in,
                  float* __restrict__ Bqk, float* __restrict__ bqk,
                  float* __restrict__ Wvo, float* __restrict__ bvo,
                  float* __restrict__ Wqp, float* __restrict__ bqp,
                  float* __restrict__ vqbk, float* __restrict__ qcst)
{
  __shared__ float rd_s[4];
  const int n = blockIdx.x, t = threadIdx.x, w = t >> 6, l = t & 63;
  float s = 0.f;
  for (int hh = 0; hh < H_; hh++)
    s = fmaf(Wq_a[hh * H_ + t], WkinT[(size_t)n * H_ + hh], s);
  Bqk[(size_t)n * H_ + t] = s;
  float p = bq_a[t] * WkinT[(size_t)n * H_ + t];
  p = wsum(p);
  if (l == 0) rd_s[w] = p;
  __syncthreads();
  if (t == 0) bqk[n] = rd_s[0] + rd_s[1] + rd_s[2] + rd_s[3];
  if (n < H_) {
    float a0 = 0.f, a1 = 0.f, a2 = 0.f;
    for (int hh = 0; hh < H_; hh++) {
      const float wo = Wo_a[n * H_ + hh];
      const float* rowv = Wv_in + (size_t)hh * D_;
      a0 = fmaf(wo, rowv[t], a0);
      a1 = fmaf(wo, rowv[t + 256], a1);
      a2 = fmaf(wo, rowv[t + 512], a2);
    }
    Wvo[(size_t)n * D_ + t] = a0;
    Wvo[(size_t)n * D_ + t + 256] = a1;
    Wvo[(size_t)n * D_ + t + 512] = a2;
    float pb = Wo_a[n * H_ + t] * bv_a[t];
    pb = wsum(pb);
    __syncthreads();
    if (l == 0) rd_s[w] = pb;
    __syncthreads();
    if (t == 0) bvo[n] = rd_s[0] + rd_s[1] + rd_s[2] + rd_s[3] + bo_a[n];
    Wqp[n * H_ + t] = Wq[n * H_ + t] * ln_w[t];
    float pq = Wq[n * H_ + t] * ln_b[t];
    pq = wsum(pq);
    __syncthreads();
    if (l == 0) rd_s[w] = pq;
    __syncthreads();
    if (t == 0) bqp[n] = rd_s[0] + rd_s[1] + rd_s[2] + rd_s[3];
  }
  if (n == 0) {
    float sv = 0.f;
    for (int hh = 0; hh < H_; hh++) sv = fmaf(bk_a[hh], Wq_a[hh * H_ + t], sv);
    vqbk[t] = sv;
    float pc = bq_a[t] * bk_a[t];
    pc = wsum(pc);
    __syncthreads();
    if (l == 0) rd_s[w] = pc;
    __syncthreads();
    if (t == 0) qcst[0] = rd_s[0] + rd_s[1] + rd_s[2] + rd_s[3];
  }
}

// ---------- fused gemm_cn + cross-attention (unchanged from R6) ----------
__global__ __launch_bounds__(256, 3)
void gemm_cn_attn(const float* __restrict__ A, const ushort* __restrict__ Bh,
                  const ushort* __restrict__ Bl, const float* __restrict__ qkv,
                  const float* __restrict__ qr, const float* __restrict__ vqbk,
                  const float* __restrict__ qcst, float* __restrict__ C,
                  float* __restrict__ wce)
{
  __shared__ __align__(16) ushort AhS[2][2048], AlS[2][2048];
  __shared__ __align__(16) float4 qkv_s[384];
  __shared__ float sc_s[64], at_s[64], qbk_s[2];
  __shared__ float rsq[64][4];
  const int t = threadIdx.x, l = t & 63, w = t >> 6;
  const int r = t >> 2, kc = t & 3;
  const int tb = t >> 7;
  const float* Ag = A + ((size_t)blockIdx.x * 64 + r) * 768 + kc * 8;
  const int aslot = ((r >> 4) * 64 + ((r & 15) | (kc << 4))) * 8;
  const ushort* Bhb = Bh + ((w * 4) * 64 + l) * 8;
  const ushort* Blb = Bl + ((w * 4) * 64 + l) * 8;

  for (int i = t; i < 384; i += 256)
    qkv_s[i] = ((const float4*)qkv)[(size_t)blockIdx.x * 384 + i];
  if (w < 2) {
    const float4 q4 = ((const float4*)qr)[((size_t)blockIdx.x * 2 + w) * 64 + l];
    const float4 v4 = ((const float4*)vqbk)[l];
    float p = wsum(dot4(q4, v4));
    if (l == 0) qbk_s[w] = p + qcst[0];
  }

  f32x4 acc[4][4];
#pragma unroll
  for (int i = 0; i < 4; i++)
#pragma unroll
    for (int j = 0; j < 4; j++) acc[i][j] = (f32x4)0.f;

  float sc = 0.f;
  float4 f0 = *(const float4*)(Ag);
  float4 f1 = *(const float4*)(Ag + 4);
  __syncthreads();
  sc += dot4(f0, qkv_s[tb * 192 + kc * 2]) + dot4(f1, qkv_s[tb * 192 + kc * 2 + 1]);
  {
    uint2 ha, la, hb, lb;
    split4(f0, ha, la); split4(f1, hb, lb);
    *(uint4*)&AhS[0][aslot] = make_uint4(ha.x, ha.y, hb.x, hb.y);
    *(uint4*)&AlS[0][aslot] = make_uint4(la.x, la.y, lb.x, lb.y);
  }
  f0 = *(const float4*)(Ag + 32);
  f1 = *(const float4*)(Ag + 36);
  __syncthreads();

#pragma unroll 2
  for (int ks = 0; ks < 24; ks++) {
    const int cur = ks & 1;
    uint4 bhv[4], blv[4];
#pragma unroll
    for (int ni = 0; ni < 4; ni++) {
      bhv[ni] = *(const uint4*)(Bhb + ks * 8192 + ni * 512);
      blv[ni] = *(const uint4*)(Blb + ks * 8192 + ni * 512);
    }
    if (ks < 23) {
      sc += dot4(f0, qkv_s[tb * 192 + (ks + 1) * 8 + kc * 2]) +
            dot4(f1, qkv_s[tb * 192 + (ks + 1) * 8 + kc * 2 + 1]);
      uint2 ha, la, hb, lb;
      split4(f0, ha, la); split4(f1, hb, lb);
      *(uint4*)&AhS[cur ^ 1][aslot] = make_uint4(ha.x, ha.y, hb.x, hb.y);
      *(uint4*)&AlS[cur ^ 1][aslot] = make_uint4(la.x, la.y, lb.x, lb.y);
      if (ks < 22) {
        f0 = *(const float4*)(Ag + (ks + 2) * 32);
        f1 = *(const float4*)(Ag + (ks + 2) * 32 + 4);
      }
    }
#pragma unroll
    for (int mi = 0; mi < 4; mi++) {
      const bf16x8 ah = *(const bf16x8*)&AhS[cur][(mi * 64 + l) * 8];
      const bf16x8 al = *(const bf16x8*)&AlS[cur][(mi * 64 + l) * 8];
#pragma unroll
      for (int ni = 0; ni < 4; ni++) {
        const bf16x8 bhf = *(const bf16x8*)&bhv[ni];
        const bf16x8 blf = *(const bf16x8*)&blv[ni];
        acc[mi][ni] = __builtin_amdgcn_mfma_f32_16x16x32_bf16(ah, bhf, acc[mi][ni], 0, 0, 0);
        acc[mi][ni] = __builtin_amdgcn_mfma_f32_16x16x32_bf16(al, bhf, acc[mi][ni], 0, 0, 0);
        acc[mi][ni] = __builtin_amdgcn_mfma_f32_16x16x32_bf16(ah, blf, acc[mi][ni], 0, 0, 0);
      }
    }
    __syncthreads();
  }

  sc += __shfl_xor(sc, 1);
  sc += __shfl_xor(sc, 2);
  if ((t & 3) == 0) sc_s[r] = sc;
  __syncthreads();
  if (w < 2) {
    float s = (l < 32) ? (sc_s[w * 32 + l] + qbk_s[w]) * (1.f / 16.f) : -1e30f;
    const float m = wmaxr(s);
    const float e = (l < 32) ? expf(s - m) : 0.f;
    const float su = wsum(e);
    if (l < 32) at_s[w * 32 + l] = e / su;
  }
  __syncthreads();
#pragma unroll
  for (int p = 0; p < 2; p++) {
    const int slot = t + p * 256;
    if (slot < 384) {
      const int tb2 = slot >= 192;
      const int idx = slot - tb2 * 192;
      const float4* cb = (const float4*)A + ((size_t)blockIdx.x * 64 + tb2 * 32) * 192 + idx;
      float4 a = make_float4(0.f, 0.f, 0.f, 0.f);
#pragma unroll 4
      for (int c = 0; c < 32; c++) {
        const float av = at_s[tb2 * 32 + c];
        const float4 f = cb[c * 192];
        a.x = fmaf(av, f.x, a.x); a.y = fmaf(av, f.y, a.y);
        a.z = fmaf(av, f.z, a.z); a.w = fmaf(av, f.w, a.w);
      }
      ((float4*)wce)[((size_t)blockIdx.x * 2 + tb2) * 192 + idx] = a;
    }
  }

#pragma unroll
  for (int mi = 0; mi < 4; mi++)
#pragma unroll
    for (int rg = 0; rg < 4; rg++) {
      float p = 0.f;
#pragma unroll
      for (int ni = 0; ni < 4; ni++) { const float v = acc[mi][ni][rg]; p = fmaf(v, v, p); }
      p += __shfl_xor(p, 1); p += __shfl_xor(p, 2); p += __shfl_xor(p, 4); p += __shfl_xor(p, 8);
      if ((l & 15) == 0) rsq[mi * 16 + (l >> 4) * 4 + rg][w] = p;
    }
  __syncthreads();
  const size_t row0 = (size_t)blockIdx.x * 64;
#pragma unroll
  for (int mi = 0; mi < 4; mi++)
#pragma unroll
    for (int rg = 0; rg < 4; rg++) {
      const int rl = mi * 16 + (l >> 4) * 4 + rg;
      const float ssum = rsq[rl][0] + rsq[rl][1] + rsq[rl][2] + rsq[rl][3];
      const float inv = 1.f / fmaxf(sqrtf(ssum), 1e-12f);
#pragma unroll
      for (int ni = 0; ni < 4; ni++)
        C[(row0 + rl) * H_ + w * 64 + ni * 16 + (l & 15)] = acc[mi][ni][rg] * inv;
    }
}

// ---------- gemm ctx + residual + LayerNorm fused: xhat = LN(wce@Wvo^T + bvo + qr) ----------
// BM=64, full N=256 (4 waves, one per 64-col group), K=768.
__global__ __launch_bounds__(256, 3)
void gemm_ctx_ln(const float* __restrict__ A, const ushort* __restrict__ Bh,
                 const ushort* __restrict__ Bl, const float* __restrict__ bvo,
                 const float* __restrict__ qr, float* __restrict__ xhat)
{
  __shared__ __align__(16) ushort AhS[2][2048], AlS[2][2048];
  __shared__ float red[64][4][2];
  const int t = threadIdx.x, l = t & 63, w = t >> 6;
  const int r = t >> 2, kc = t & 3;
  const float* Ag = A + ((size_t)blockIdx.x * 64 + r) * 768 + kc * 8;
  const int aslot = ((r >> 4) * 64 + ((r & 15) | (kc << 4))) * 8;
  const ushort* Bhb = Bh + ((w * 4) * 64 + l) * 8;
  const ushort* Blb = Bl + ((w * 4) * 64 + l) * 8;

  f32x4 acc[4][4];
#pragma unroll
  for (int i = 0; i < 4; i++)
#pragma unroll
    for (int j = 0; j < 4; j++) acc[i][j] = (f32x4)0.f;

  float4 f0 = *(const float4*)(Ag);
  float4 f1 = *(const float4*)(Ag + 4);
  {
    uint2 ha, la, hb, lb;
    split4(f0, ha, la); split4(f1, hb, lb);
    *(uint4*)&AhS[0][aslot] = make_uint4(ha.x, ha.y, hb.x, hb.y);
    *(uint4*)&AlS[0][aslot] = make_uint4(la.x, la.y, lb.x, lb.y);
  }
  f0 = *(const float4*)(Ag + 32);
  f1 = *(const float4*)(Ag + 36);
  __syncthreads();

#pragma unroll 2
  for (int ks = 0; ks < 24; ks++) {
    const int cur = ks & 1;
    uint4 bhv[4], blv[4];
#pragma unroll
    for (int ni = 0; ni < 4; ni++) {
      bhv[ni] = *(const uint4*)(Bhb + ks * 8192 + ni * 512);
      blv[ni] = *(const uint4*)(Blb + ks * 8192 + ni * 512);
    }
    if (ks < 23) {
      uint2 ha, la, hb, lb;
      split4(f0, ha, la); split4(f1, hb, lb);
      *(uint4*)&AhS[cur ^ 1][aslot] = make_uint4(ha.x, ha.y, hb.x, hb.y);
      *(uint4*)&AlS[cur ^ 1][aslot] = make_uint4(la.x, la.y, lb.x, lb.y);
      if (ks < 22) {
        f0 = *(const float4*)(Ag + (ks + 2) * 32);
        f1 = *(const float4*)(Ag + (ks + 2) * 32 + 4);
      }
    }
#pragma unroll
    for (int mi = 0; mi < 4; mi++) {
      const bf16x8 ah = *(const bf16x8*)&AhS[cur][(mi * 64 + l) * 8];
      const bf16x8 al = *(const bf16x8*)&AlS[cur][(mi * 64 + l) * 8];
#pragma unroll
      for (int ni = 0; ni < 4; ni++) {
        const bf16x8 bhf = *(const bf16x8*)&bhv[ni];
        const bf16x8 blf = *(const bf16x8*)&blv[ni];
        acc[mi][ni] = __builtin_amdgcn_mfma_f32_16x16x32_bf16(ah, bhf, acc[mi][ni], 0, 0, 0);
        acc[mi][ni] = __builtin_amdgcn_mfma_f32_16x16x32_bf16(al, bhf, acc[mi][ni], 0, 0, 0);
        acc[mi][ni] = __builtin_amdgcn_mfma_f32_16x16x32_bf16(ah, blf, acc[mi][ni], 0, 0, 0);
      }
    }
    __syncthreads();
  }

  // epilogue: x = acc + bvo + qr ; LN stats over rows ; write xhat
  const size_t row0 = (size_t)blockIdx.x * 64;
#pragma unroll
  for (int mi = 0; mi < 4; mi++)
#pragma unroll
    for (int rg = 0; rg < 4; rg++) {
      const int rl = mi * 16 + (l >> 4) * 4 + rg;
      float sx = 0.f, sxx = 0.f;
#pragma unroll
      for (int ni = 0; ni < 4; ni++) {
        const int col = w * 64 + ni * 16 + (l & 15);
        const float x = acc[mi][ni][rg] + bvo[col] + qr[(row0 + rl) * H_ + col];
        acc[mi][ni][rg] = x;
        sx += x; sxx = fmaf(x, x, sxx);
      }
      sx += __shfl_xor(sx, 1); sx += __shfl_xor(sx, 2); sx += __shfl_xor(sx, 4); sx += __shfl_xor(sx, 8);
      sxx += __shfl_xor(sxx, 1); sxx += __shfl_xor(sxx, 2); sxx += __shfl_xor(sxx, 4); sxx += __shfl_xor(sxx, 8);
      if ((l & 15) == 0) { red[rl][w][0] = sx; red[rl][w][1] = sxx; }
    }
  __syncthreads();
#pragma unroll
  for (int mi = 0; mi < 4; mi++)
#pragma unroll
    for (int rg = 0; rg < 4; rg++) {
      const int rl = mi * 16 + (l >> 4) * 4 + rg;
      const float SX = red[rl][0][0] + red[rl][1][0] + red[rl][2][0] + red[rl][3][0];
      const float SXX = red[rl][0][1] + red[rl][1][1] + red[rl][2][1] + red[rl][3][1];
      const float mu = SX * (1.f / H_);
      const float var = SXX * (1.f / H_) - mu * mu;
      const float isd = 1.f / sqrtf(var + 1e-5f);
#pragma unroll
      for (int ni = 0; ni < 4; ni++)
        xhat[(row0 + rl) * H_ + w * 64 + ni * 16 + (l & 15)] = (acc[mi][ni][rg] - mu) * isd;
    }
}

// ---------- generic split-bf16 MFMA GEMM: C[M,N] = A[M,K]*B^T (+bias), B pre-tiled ----------
template<int NKS, int NB, bool BIAS>
__global__ __launch_bounds__(256)
void gemm_bf(const float* __restrict__ A, const ushort* __restrict__ Bh,
             const ushort* __restrict__ Bl, const float* __restrict__ bias,
             float* __restrict__ C)
{
  __shared__ __align__(16) ushort AhS[2][4096], AlS[2][4096];
  const int t = threadIdx.x, l = t & 63, w = t >> 6;
  const int wr = w >> 1, wc = w & 1;
  const int Kd = NKS * 32, N = NB * 16;
  const int r = t >> 1, kc0 = (t & 1) * 2;
  const float* Ag = A + ((size_t)blockIdx.x * 128 + r) * Kd + kc0 * 8;
  const int aslot0 = ((r >> 4) * 64 + ((r & 15) | (kc0 << 4))) * 8;
  const int aslot1 = aslot0 + 128;
  const int nb0 = blockIdx.y * 4 + wc * 2;
  const ushort* Bhb = Bh + (nb0 * 64 + l) * 8;
  const ushort* Blb = Bl + (nb0 * 64 + l) * 8;

  f32x4 acc[4][2];
#pragma unroll
  for (int i = 0; i < 4; i++)
#pragma unroll
    for (int j = 0; j < 2; j++) acc[i][j] = (f32x4)0.f;

  float4 f0 = *(const float4*)(Ag);
  float4 f1 = *(const float4*)(Ag + 4);
  float4 f2 = *(const float4*)(Ag + 8);
  float4 f3 = *(const float4*)(Ag + 12);
  {
    uint2 ha, la, hb, lb;
    split4(f0, ha, la); split4(f1, hb, lb);
    *(uint4*)&AhS[0][aslot0] = make_uint4(ha.x, ha.y, hb.x, hb.y);
    *(uint4*)&AlS[0][aslot0] = make_uint4(la.x, la.y, lb.x, lb.y);
    split4(f2, ha, la); split4(f3, hb, lb);
    *(uint4*)&AhS[0][aslot1] = make_uint4(ha.x, ha.y, hb.x, hb.y);
    *(uint4*)&AlS[0][aslot1] = make_uint4(la.x, la.y, lb.x, lb.y);
  }
  f0 = *(const float4*)(Ag + 32); f1 = *(const float4*)(Ag + 36);
  f2 = *(const float4*)(Ag + 40); f3 = *(const float4*)(Ag + 44);
  __syncthreads();

#pragma unroll 2
  for (int ks = 0; ks < NKS; ks++) {
    const int cur = ks & 1;
    if (ks < NKS - 1) {
      uint2 ha, la, hb, lb;
      split4(f0, ha, la); split4(f1, hb, lb);
      *(uint4*)&AhS[cur ^ 1][aslot0] = make_uint4(ha.x, ha.y, hb.x, hb.y);
      *(uint4*)&AlS[cur ^ 1][aslot0] = make_uint4(la.x, la.y, lb.x, lb.y);
      split4(f2, ha, la); split4(f3, hb, lb);
      *(uint4*)&AhS[cur ^ 1][aslot1] = make_uint4(ha.x, ha.y, hb.x, hb.y);
      *(uint4*)&AlS[cur ^ 1][aslot1] = make_uint4(la.x, la.y, lb.x, lb.y);
      if (ks < NKS - 2) {
        f0 = *(const float4*)(Ag + (ks + 2) * 32);
        f1 = *(const float4*)(Ag + (ks + 2) * 32 + 4);
        f2 = *(const float4*)(Ag + (ks + 2) * 32 + 8);
        f3 = *(const float4*)(Ag + (ks + 2) * 32 + 12);
      }
    }
#pragma unroll
    for (int mi = 0; mi < 4; mi++) {
      const bf16x8 ah = *(const bf16x8*)&AhS[cur][((wr * 4 + mi) * 64 + l) * 8];
      const bf16x8 al = *(const bf16x8*)&AlS[cur][((wr * 4 + mi) * 64 + l) * 8];
#pragma unroll
      for (int ni = 0; ni < 2; ni++) {
        const bf16x8 bhf = *(const bf16x8*)(Bhb + ks * (NB * 512) + ni * 512);
        const bf16x8 blf = *(const bf16x8*)(Blb + ks * (NB * 512) + ni * 512);
        acc[mi][ni] = __builtin_amdgcn_mfma_f32_16x16x32_bf16(ah, bhf, acc[mi][ni], 0, 0, 0);
        acc[mi][ni] = __builtin_amdgcn_mfma_f32_16x16x32_bf16(al, bhf, acc[mi][ni], 0, 0, 0);
        acc[mi][ni] = __builtin_amdgcn_mfma_f32_16x16x32_bf16(ah, blf, acc[mi][ni], 0, 0, 0);
      }
    }
    __syncthreads();
  }

  const size_t row0 = (size_t)blockIdx.x * 128 + wr * 64;
  const int col0 = blockIdx.y * 64 + wc * 32;
#pragma unroll
  for (int mi = 0; mi < 4; mi++)
#pragma unroll
    for (int ni = 0; ni < 2; ni++) {
      const int col = col0 + ni * 16 + (l & 15);
      const float bb = BIAS ? bias[col] : 0.f;
#pragma unroll
      for (int rg = 0; rg < 4; rg++) {
        const size_t row = row0 + mi * 16 + (l >> 4) * 4 + rg;
        C[row * N + col] = acc[mi][ni][rg] + bb;
      }
    }
}

// ---------- h = l2n(hraw); need = softmax(h@Wqt^T + bqt) ----------
__global__ __launch_bounds__(256)
void h_post(const float* __restrict__ hraw, const float* __restrict__ Wqt,
            const float* __restrict__ bqt, float* __restrict__ h, float* __restrict__ need)
{
  __shared__ float wq_s[T_ * H_];
  for (int i = threadIdx.x; i < T_ * H_; i += 256) wq_s[i] = Wqt[i];
  const int w = threadIdx.x >> 6, l = threadIdx.x & 63;
  const size_t r = (size_t)blockIdx.x * 4 + w;
  const float4 v = *(const float4*)(hraw + r * H_ + l * 4);
  const float n = fmaxf(sqrtf(wsum(v.x * v.x + v.y * v.y + v.z * v.z + v.w * v.w)), 1e-12f);
  float4 hn; hn.x = v.x / n; hn.y = v.y / n; hn.z = v.z / n; hn.w = v.w / n;
  *(float4*)(h + r * H_ + l * 4) = hn;
  __syncthreads();
  float mine = 0.f;
  for (int tt = 0; tt < T_; tt++) {
    const float4 p4 = *(const float4*)(wq_s + tt * H_ + l * 4);
    float p = hn.x * p4.x + hn.y * p4.y + hn.z * p4.z + hn.w * p4.w;
    p = wsum(p);
    if (l == tt) mine = p + bqt[l];
  }
  float s = (l < T_) ? mine : -1e30f;
  const float m = wmaxr(s);
  const float e = (l < T_) ? expf(s - m) : 0.f;
  const float su = wsum(e);
  if (l < T_) need[r * T_ + l] = e / su;
}

// ---------- step 0: scores, argmax, covered from chosen row ----------
__global__ __launch_bounds__(256)
void score0_kernel(const float* __restrict__ h, const float* __restrict__ se,
                   const float* __restrict__ cn, const float* __restrict__ pro,
                   float* __restrict__ covered, float* __restrict__ chosen,
                   float* __restrict__ logits, float* __restrict__ preds)
{
  __shared__ __align__(16) float hs_s[H_];
  __shared__ __align__(16) float cr_s[H_];
  __shared__ float part_s[T_ * 16];
  __shared__ float sc_s[K_];
  __shared__ float rd_s[4];
  __shared__ int idx_s;
  const int b = blockIdx.x, t = threadIdx.x;
  const int w = t >> 6, l = t & 63;

  const float hv = h[(size_t)b * H_ + t] + se[t];
  const float ss = wsum(hv * hv);
  if (l == 0) rd_s[w] = ss;
  __syncthreads();
  const float n = fmaxf(sqrtf(rd_s[0] + rd_s[1] + rd_s[2] + rd_s[3]), 1e-12f);
  hs_s[t] = hv / n;
  __syncthreads();

  const float4 hf = *(const float4*)(hs_s + l * 4);
#pragma unroll
  for (int cc = 0; cc < 8; cc++) {
    const int c = w * 8 + cc;
    const float4 cv = *(const float4*)(cn + ((size_t)b * K_ + c) * H_ + l * 4);
    float p = wsum(dot4(cv, hf));
    if (l == 0) sc_s[c] = p * 10.f;
  }
  __syncthreads();
  if (w == 0) {  // argmax, first-index tie-break
    float s = (l < K_) ? sc_s[l] : -1e30f;
    int bi = (l < K_) ? l : K_;
#pragma unroll
    for (int o = 32; o; o >>= 1) {
      const float s2 = __shfl_xor(s, o);
      const int i2 = __shfl_xor(bi, o);
      if (s2 > s || (s2 == s && i2 < bi)) { s = s2; bi = i2; }
    }
    if (l == 0) idx_s = bi;
  }
  __syncthreads();
  const int idx = idx_s;
  if (t < K_) logits[(size_t)b * (S_ * K_) + t] = sc_s[t];
  if (t == 0) preds[(size_t)b * S_] = (float)idx;

  // covered = min(softmax_t(cn[b,idx].pro[t]), 1); chosen = cn[b,idx]
  const float crv = cn[((size_t)b * K_ + idx) * H_ + t];
  cr_s[t] = crv;
  chosen[(size_t)b * H_ + t] = crv;
  __syncthreads();
  {
    const int tt = t & 15, ch = t >> 4;
    float p = 0.f;
#pragma unroll
    for (int j = 0; j < 16; j++)
      p = fmaf(cr_s[ch * 16 + j], pro[tt * H_ + ch * 16 + j], p);
    part_s[tt * 16 + ch] = p;
  }
  __syncthreads();
  if (t < 16) {
    float d = 0.f;
#pragma unroll
    for (int ch = 0; ch < 16; ch++) d += part_s[t * 16 + ch];
    float mx = d;
    mx = fmaxf(mx, __shfl_xor(mx, 1)); mx = fmaxf(mx, __shfl_xor(mx, 2));
    mx = fmaxf(mx, __shfl_xor(mx, 4)); mx = fmaxf(mx, __shfl_xor(mx, 8));
    const float e = expf(d - mx);
    float su = e;
    su += __shfl_xor(su, 1); su += __shfl_xor(su, 2);
    su += __shfl_xor(su, 4); su += __shfl_xor(su, 8);
    covered[(size_t)b * T_ + t] = fminf(e / su, 1.f);
  }
}

// ---------- step 1: GRU + scores + topic gain + argmax ----------
__global__ __launch_bounds__(256)
void score1_kernel(const float* __restrict__ gi, const float* __restrict__ gh,
                   const float* __restrict__ h,  const float* __restrict__ se,
                   const float* __restrict__ cn, const float* __restrict__ pro,
                   const float* __restrict__ need, const float* __restrict__ clam,
                   const float* __restrict__ covered,
                   float* __restrict__ logits, float* __restrict__ preds)
{
  __shared__ __align__(16) float cn_s[K_ * 260];    // stride 260 (65 float4)
  __shared__ __align__(16) float pro_s[T_ * 260];
  __shared__ __align__(16) float hs_s[H_];
  __shared__ float gd_s[K_ * T_];
  __shared__ float gain_s[K_];
  __shared__ float nu_s[T_], sc_s[K_], rd_s[4], rd2_s[4];
  const int b = blockIdx.x, t = threadIdx.x;
  const int w = t >> 6, l = t & 63;

  // GRU
  const size_t o = (size_t)b * (3 * H_);
  const float ir = gi[o + t], iz = gi[o + 256 + t], ig = gi[o + 512 + t];
  const float hr = gh[o + t], hz = gh[o + 256 + t], hg = gh[o + 512 + t];
  const float hv = h[(size_t)b * H_ + t];
  const float rr = 1.f / (1.f + expf(-(ir + hr)));
  const float zz = 1.f / (1.f + expf(-(iz + hz)));
  const float nn = tanhf(ig + rr * hg);
  const float x = (1.f - zz) * nn + zz * hv;
  const float ss = wsum(x * x);
  if (l == 0) rd_s[w] = ss;

  // stage cn[b] and pro (padded stride), nu
  {
    const float4* cng = (const float4*)(cn + (size_t)b * K_ * H_);
    float4* cns4 = (float4*)cn_s;
    for (int i = t; i < 2048; i += 256) cns4[(i >> 6) * 65 + (i & 63)] = cng[i];
    const float4* prg = (const float4*)pro;
    float4* prs4 = (float4*)pro_s;
    for (int i = t; i < 1024; i += 256) prs4[(i >> 6) * 65 + (i & 63)] = prg[i];
  }
  if (t < T_)
    nu_s[t] = need[(size_t)b * T_ + t] * fminf(fmaxf(1.f - covered[(size_t)b * T_ + t], 0.f), 1.f);
  __syncthreads();
  const float n1 = fmaxf(sqrtf(rd_s[0] + rd_s[1] + rd_s[2] + rd_s[3]), 1e-12f);
  const float y = x / n1 + se[H_ + t];
  const float ss2 = wsum(y * y);
  if (l == 0) rd2_s[w] = ss2;
  __syncthreads();
  const float n2 = fmaxf(sqrtf(rd2_s[0] + rd2_s[1] + rd2_s[2] + rd2_s[3]), 1e-12f);
  hs_s[t] = y / n2;
  __syncthreads();

  // raw scores
  const float4* cn_s4 = (const float4*)cn_s;
  const float4* pro_s4 = (const float4*)pro_s;
  const float4 hf = *(const float4*)(hs_s + l * 4);
#pragma unroll
  for (int cc = 0; cc < 8; cc++) {
    const int c = w * 8 + cc;
    const float4 cv = cn_s4[c * 65 + l];
    float p = wsum(dot4(cv, hf));
    if (l == 0) sc_s[c] = p * 10.f;
  }
  // topic dots: 512 (c,tt) pairs, 2 per thread
#pragma unroll
  for (int pr = 0; pr < 2; pr++) {
    const int idx2 = t + pr * 256;
    const int c = idx2 >> 4, tt = idx2 & 15;
    float d = 0.f;
#pragma unroll 8
    for (int j = 0; j < 64; j++)
      d += dot4(cn_s4[c * 65 + j], pro_s4[tt * 65 + j]);
    gd_s[idx2] = d;
  }
  __syncthreads();
  if (t < K_) {  // per-candidate softmax over topics + gain
    float mx = -1e30f;
#pragma unroll
    for (int tt = 0; tt < T_; tt++) mx = fmaxf(mx, gd_s[t * T_ + tt]);
    float su = 0.f, ga = 0.f;
#pragma unroll
    for (int tt = 0; tt < T_; tt++) {
      const float e = expf(gd_s[t * T_ + tt] - mx);
      su += e; ga = fmaf(nu_s[tt], e, ga);
    }
    gain_s[t] = ga / su;
  }
  const int i0 = (int)preds[(size_t)b * S_];
  __syncthreads();
  if (w == 0) {
    const float lam = log1pf(expf(clam[0]));
    float s = (l < K_) ? sc_s[l] + lam * gain_s[l] : -1e30f;
    if (l < K_ && l == i0) s = -100.f;
    if (l < K_) logits[(size_t)b * (S_ * K_) + K_ + l] = s;
    int bi = (l < K_) ? l : K_;
    float sm = s;
#pragma unroll
    for (int o2 = 32; o2; o2 >>= 1) {
      const float s2 = __shfl_xor(sm, o2);
      const int i2 = __shfl_xor(bi, o2);
      if (s2 > sm || (s2 == sm && i2 < bi)) { sm = s2; bi = i2; }
    }
    if (l == 0) preds[(size_t)b * S_ + 1] = (float)bi;
  }
}

extern "C" void kernel_launch(void* const* d_in, const int* in_sizes, int n_in,
                              void* d_out, int out_size, void* d_ws, size_t ws_size,
                              hipStream_t stream)
{
  const float* query_emb = (const float*)d_in[0];
  const float* cand_emb  = (const float*)d_in[1];
  const float* W_in = (const float*)d_in[2];
  const float* Wq_a = (const float*)d_in[3];
  const float* Wk_a = (const float*)d_in[4];
  const float* Wv_a = (const float*)d_in[5];
  const float* bq_a = (const float*)d_in[6];
  const float* bk_a = (const float*)d_in[7];
  const float* bv_a = (const float*)d_in[8];
  const float* Wo_a = (const float*)d_in[9];
  const float* bo_a = (const float*)d_in[10];
  const float* ln_w = (const float*)d_in[11];
  const float* ln_b = (const float*)d_in[12];
  const float* Wq   = (const float*)d_in[13];
  const float* Wc   = (const float*)d_in[14];
  const float* W_ih = (const float*)d_in[15];
  const float* W_hh = (const float*)d_in[16];
  const float* b_ih = (const float*)d_in[17];
  const float* b_hh = (const float*)d_in[18];
  const float* step_emb = (const float*)d_in[19];
  const float* tpro = (const float*)d_in[20];
  const float* Wqt  = (const float*)d_in[21];
  const float* bqt  = (const float*)d_in[22];
  const float* clam = (const float*)d_in[23];

  float* ws = (float*)d_ws;
  size_t o = 0;
  float* WkinT = ws + o; o += (size_t)D_ * H_;
  float* Wv_in = ws + o; o += (size_t)H_ * D_;
  ushort* BhW  = (ushort*)(ws + o); o += 98304;
  ushort* BlW  = (ushort*)(ws + o); o += 98304;
  float* pro   = ws + o; o += (size_t)T_ * H_;
  float* Bqk   = ws + o; o += (size_t)D_ * H_;
  float* bqk   = ws + o; o += 1024;
  float* Wvo   = ws + o; o += (size_t)H_ * D_;
  float* bvo   = ws + o; o += 256;
  float* Wqp   = ws + o; o += (size_t)H_ * H_;
  float* bqp   = ws + o; o += 256;
  float* vqbk  = ws + o; o += 256;
  float* qcst  = ws + o; o += 4;
  ushort* WintH = (ushort*)(ws + o); o += 98304;
  ushort* WintL = (ushort*)(ws + o); o += 98304;
  ushort* BqktH = (ushort*)(ws + o); o += 98304;
  ushort* BqktL = (ushort*)(ws + o); o += 98304;
  ushort* WvotH = (ushort*)(ws + o); o += 98304;
  ushort* WvotL = (ushort*)(ws + o); o += 98304;
  ushort* WqptH = (ushort*)(ws + o); o += 32768;
  ushort* WqptL = (ushort*)(ws + o); o += 32768;
  ushort* WihtH = (ushort*)(ws + o); o += 98304;
  ushort* WihtL = (ushort*)(ws + o); o += 98304;
  ushort* WhhtH = (ushort*)(ws + o); o += 98304;
  ushort* WhhtL = (ushort*)(ws + o); o += 98304;
  float* qr    = ws + o; o += (size_t)B_ * H_;
  float* qkv   = ws + o; o += (size_t)B_ * D_;   // later: gi
  float* wce   = ws + o; o += (size_t)B_ * D_;   // later: gh
  float* ctxb  = ws + o; o += (size_t)B_ * H_;   // hraw
  float* xhat  = ws + o; o += (size_t)B_ * H_;
  float* h     = ws + o; o += (size_t)B_ * H_;
  float* need  = ws + o; o += (size_t)B_ * T_;
  float* cn    = ws + o; o += (size_t)B_ * K_ * H_;
  float* cov   = ws + o; o += (size_t)B_ * T_;
  float* chosen= ws + o; o += (size_t)B_ * H_;

  float* out_logits = (float*)d_out;
  float* out_preds  = (float*)d_out + (size_t)B_ * S_ * K_;

  // weight folding + tiling
  fold_kernel<<<dim3(H_, 3), 256, 0, stream>>>(Wk_a, Wv_a, Wc, W_in, WkinT, Wv_in, BhW, BlW);
  proto_kernel<<<1, 256, 0, stream>>>(tpro, pro);
  fold2_kernel<<<D_, 256, 0, stream>>>(Wq_a, bq_a, bk_a, Wo_a, bo_a, bv_a, Wq, ln_w, ln_b,
                                       WkinT, Wv_in, Bqk, bqk, Wvo, bvo, Wqp, bqp, vqbk, qcst);
  TileJobs jobs;
  jobs.j[0] = {W_in, WintH, WintL, 16, 768, 256};
  jobs.j[1] = {Bqk,  BqktH, BqktL, 48, 256, 768};
  jobs.j[2] = {Wvo,  WvotH, WvotL, 16, 768, 256};
  jobs.j[3] = {Wqp,  WqptH, WqptL, 16, 256, 256};
  jobs.j[4] = {W_ih, WihtH, WihtL, 48, 256, 768};
  jobs.j[5] = {W_hh, WhhtH, WhhtL, 48, 256, 768};
  tile_all<<<dim3(768, 6), 256, 0, stream>>>(jobs);

  // query path
  gemm_bf<24, 16, false><<<dim3(B_ / 128, 4), 256, 0, stream>>>(query_emb, WintH, WintL, nullptr, qr);
  gemm_bf<8, 48, true><<<dim3(B_ / 128, 12), 256, 0, stream>>>(qr, BqktH, BqktL, bqk, qkv);

  // candidate path + fused attention
  gemm_cn_attn<<<(B_ * K_) / 64, 256, 0, stream>>>(cand_emb, BhW, BlW, qkv, qr, vqbk, qcst, cn, wce);

  // ctx gemm + residual + LN fused
  gemm_ctx_ln<<<B_ / 64, 256, 0, stream>>>(wce, WvotH, WvotL, bvo, qr, xhat);
  gemm_bf<8, 16, true><<<dim3(B_ / 128, 4), 256, 0, stream>>>(xhat, WqptH, WqptL, bqp, ctxb);  // hraw
  h_post<<<B_ / 4, 256, 0, stream>>>(ctxb, Wqt, bqt, h, need);

  // step 0 (scores + covered + chosen)
  score0_kernel<<<B_, 256, 0, stream>>>(h, step_emb, cn, pro, cov, chosen, out_logits, out_preds);
  // GRU gates
  gemm_bf<8, 48, true><<<dim3(B_ / 128, 12), 256, 0, stream>>>(chosen, WihtH, WihtL, b_ih, qkv);  // gi
  gemm_bf<8, 48, true><<<dim3(B_ / 128, 12), 256, 0, stream>>>(h, WhhtH, WhhtL, b_hh, wce);       // gh
  // step 1 (GRU + scores + topic gain)
  score1_kernel<<<B_, 256, 0, stream>>>(qkv, wce, h, step_emb, cn, pro, need, clam, cov,
                                        out_logits, out_preds);
}